// Round 4
// 1098.359 us; speedup vs baseline: 1.4056x; 1.4056x over previous
//
#include <hip/hip_runtime.h>
#include <math.h>

#define HID 128
#define NRAYS 4096
#define TP 64   // points per MLP tile (one per lane)

typedef __bf16 bf16x8 __attribute__((ext_vector_type(8)));
typedef float f32x4 __attribute__((ext_vector_type(4)));
typedef unsigned int uint32x4 __attribute__((ext_vector_type(4)));

union frag_u { bf16x8 v; uint32x4 q; };

__device__ __forceinline__ unsigned f2bf(float f){   // fp32 -> bf16 bits, RNE
  unsigned u = __float_as_uint(f);
  u += 0x7FFFu + ((u >> 16) & 1u);
  return u >> 16;
}
__device__ __forceinline__ float bf2f(unsigned h){
  return __uint_as_float(h << 16);
}
__device__ __forceinline__ float sp_f(float x){      // softplus, libm-precision
  return fmaxf(x, 0.0f) + log1pf(expf(-fabsf(x)));
}
__device__ __forceinline__ float sp_fast(float x){   // softplus, fast (MFMA fwd staging)
  float e = __expf(-fabsf(x));
  return fmaxf(x, 0.0f) + __logf(1.0f + e);
}
__device__ __forceinline__ float sg_f(float x){      // sigmoid, libm-precision
  return 1.0f / (1.0f + expf(-x));
}
__device__ __forceinline__ f32x4 splat4(float x){
  f32x4 v = {x, x, x, x};
  return v;
}

// Swizzled LDS index (ushort units) for a [64][128] bf16 plane.
// byte ^= ((row&7)<<4)  ->  ushort idx ^= ((row&7)<<3). Keeps 16B alignment.
#define SW(p,k) ((((p)*HID) + (k)) ^ (((p)&7)<<3))

// ---------------------------------------------------------------- transpose W2 (fp32, for VALU bwd)
__global__ void k_transpose(const float* __restrict__ W2, float* __restrict__ W2T){
  int idx = blockIdx.x*256 + threadIdx.x;
  if (idx < HID*HID){
    int k = idx >> 7, n = idx & 127;
    W2T[n*HID + k] = W2[k*HID + n];
  }
}

// ---------------------------------------------------------------- W2 fwd-fragment prep
// Split W2 into bf16 hi/lo MFMA B-fragment order (fwd GEMM only):
// frag f = kc*8 + tg; element: contraction a = 32*kc + 8*(lane>>4)+e,
// output b = 16*tg + (lane&15). Stored at [(f*64+lane)*8 + e].
// NOTE: launched AFTER the upsample loop — its destination aliases sdf_buf,
// which is dead by then. Keeps total workspace within the proven footprint.
__global__ void k_make_frags(const float* __restrict__ W2,
    unsigned short* __restrict__ w2fh, unsigned short* __restrict__ w2fl){
  int idx = blockIdx.x*256 + threadIdx.x;
  if (idx >= 2048) return;
  int f    = idx >> 6;             // 0..31
  int lane = idx & 63;
  int kc = f >> 3, tg = f & 7;
  int lg = lane >> 4, lr = lane & 15;
  int base = (f*64 + lane)*8;
  #pragma unroll
  for (int e = 0; e < 8; e++){
    int a = 32*kc + 8*lg + e;      // contraction index k
    int b = 16*tg + lr;            // output index n
    float v = W2[a*HID + b];
    unsigned hi = f2bf(v);
    w2fh[base+e] = (unsigned short)hi;
    w2fl[base+e] = (unsigned short)f2bf(v - bf2f(hi));
  }
}

// ---------------------------------------------------------------- initial z + pts
__global__ void k_init(const float* __restrict__ rays_o, const float* __restrict__ rays_d,
                       const float* __restrict__ nearv, const float* __restrict__ farv,
                       float* __restrict__ z_buf, float* __restrict__ pts){
  int idx = blockIdx.x*256 + threadIdx.x;
  if (idx >= NRAYS*64) return;
  int ray = idx >> 6, j = idx & 63;
  float nr = nearv[ray];
  float z = nr + (farv[ray] - nr) * ((float)j / 63.0f);
  z_buf[ray*128 + j] = z;
  pts[idx*3+0] = rays_o[ray*3+0] + rays_d[ray*3+0]*z;
  pts[idx*3+1] = rays_o[ray*3+1] + rays_d[ray*3+1]*z;
  pts[idx*3+2] = rays_o[ray*3+2] + rays_d[ray*3+2]*z;
}

// ---------------------------------------------------------------- MLP forward (fp32 VALU)
// Precision-critical: feeds the upsample cdf (inv_s amplification + searchsorted).
// Wave w owns neurons [32w,32w+32); lane owns one point. Weights wave-uniform.
__global__ __launch_bounds__(256, 4) void k_mlp_fwd(
    const float* __restrict__ pts,
    const float* __restrict__ W1, const float* __restrict__ b1,
    const float* __restrict__ W2, const float* __restrict__ b2,
    const float* __restrict__ W3, const float* __restrict__ b3,
    float* __restrict__ sdf_out){
  __shared__ float sH[HID*TP];    // h1 [k][p]  (32 KB)
  __shared__ float sRed[4*TP];
  const int tid = threadIdx.x;
  const int p   = tid & 63;
  const int wv  = __builtin_amdgcn_readfirstlane(tid >> 6);
  const int k0  = wv * 32;
  const int q0  = blockIdx.x * TP;
  const float x0 = pts[(q0+p)*3+0];
  const float x1 = pts[(q0+p)*3+1];
  const float x2 = pts[(q0+p)*3+2];
  #pragma unroll
  for (int kk = 0; kk < 32; kk++){
    int k = k0 + kk;
    float pre = b1[k];
    pre = fmaf(x0, W1[k],       pre);
    pre = fmaf(x1, W1[HID+k],   pre);
    pre = fmaf(x2, W1[2*HID+k], pre);
    sH[k*TP + p] = sp_f(pre);
  }
  __syncthreads();
  float acc[32];
  #pragma unroll
  for (int j = 0; j < 32; j++) acc[j] = b2[k0+j];
  #pragma unroll 2
  for (int k = 0; k < HID; k++){
    const float hv = sH[k*TP + p];
    const float* __restrict__ wr = &W2[k*HID + k0];
    #pragma unroll
    for (int j = 0; j < 32; j++) acc[j] = fmaf(hv, wr[j], acc[j]);
  }
  float part = 0.0f;
  #pragma unroll
  for (int j = 0; j < 32; j++) part += sp_f(acc[j]) * W3[k0+j];
  sRed[wv*TP + p] = part;
  __syncthreads();
  if (tid < TP)
    sdf_out[q0+tid] = b3[0] + sRed[tid] + sRed[TP+tid] + sRed[2*TP+tid] + sRed[3*TP+tid];
}

// ---------------------------------------------------------------- MLP fwd(MFMA) + bwd(VALU)
// Fwd layer-2 GEMM on mfma_f32_16x16x32_bf16, 3-term hi/lo emulation —
// DEPTH-VALIDATED in rounds 1-2 (sdf feeds k_render through inv_s=20; both
// D-readout coordinates validated via sRed/W3 agreement). Bwd dh1 GEMM is the
// round-0-verified VALU path with fp32 g2 staged in LDS ([n][p] layout,
// conflict-free reads). The g2 fp32 plane aliases the h1 bf16 hi/lo planes
// (disjoint lifetimes, separated by the post-fwd-GEMM barrier).
// A-frag: row p = 16*mt + (lane&15), k = 32*kc + 8*(lane>>4) + e
// B-frag: col   = 16*tg + (lane&15), same k-map (self-consistent pairing)
// C/D   : col = lane&15, row = 4*(lane>>4) + reg   [HW-verified]
__global__ __launch_bounds__(256, 4) void k_mlp_bwd(
    const float* __restrict__ pts,
    const float* __restrict__ W1, const float* __restrict__ b1,
    const float* __restrict__ b2,
    const float* __restrict__ W3, const float* __restrict__ b3,
    const unsigned short* __restrict__ w2fh, const unsigned short* __restrict__ w2fl,
    const float* __restrict__ W2T,
    float* __restrict__ sdf_out, float* __restrict__ grad_out)
{
  __shared__ __align__(16) unsigned char sBuf[32768];  // 32 KB shared block
  unsigned short* sHi = (unsigned short*)sBuf;         // h1 hi plane (16 KB)
  unsigned short* sLo = sHi + 64*HID;                  // h1 lo plane (16 KB)
  float*          sG  = (float*)sBuf;                  // g2 [n][p] fp32 (32 KB), after fwd
  __shared__ float sRed[4][64];                        // sdf partials per wave
  __shared__ float sGx[4*64], sGy[4*64], sGz[4*64];    // grad partials per wave

  const int tid = threadIdx.x;
  const int l   = tid & 63;
  const int wv  = __builtin_amdgcn_readfirstlane(tid >> 6);
  const int lg  = l >> 4;
  const int lr  = l & 15;
  const int q0  = blockIdx.x * 64;
  const int kb  = 32*wv;

  const float x0 = pts[(q0+l)*3+0];
  const float x1 = pts[(q0+l)*3+1];
  const float x2 = pts[(q0+l)*3+2];

  // ---- layer 1: point l, k in [32wv, 32wv+32); bf16 hi/lo staged for MFMA
  #pragma unroll
  for (int g = 0; g < 4; g++){
    unsigned hw[4], lw[4];
    #pragma unroll
    for (int e2 = 0; e2 < 4; e2++){
      unsigned hpk[2], lpk[2];
      #pragma unroll
      for (int t = 0; t < 2; t++){
        int k = kb + 8*g + 2*e2 + t;
        float pre = b1[k];
        pre = fmaf(x0, W1[k],       pre);
        pre = fmaf(x1, W1[HID+k],   pre);
        pre = fmaf(x2, W1[2*HID+k], pre);
        float h = sp_fast(pre);
        unsigned hi = f2bf(h);
        hpk[t] = hi;
        lpk[t] = f2bf(h - bf2f(hi));
      }
      hw[e2] = hpk[0] | (hpk[1] << 16);
      lw[e2] = lpk[0] | (lpk[1] << 16);
    }
    uint32x4 hq = {hw[0], hw[1], hw[2], hw[3]};
    uint32x4 lq = {lw[0], lw[1], lw[2], lw[3]};
    *(uint32x4*)&sHi[SW(l, kb + 8*g)] = hq;
    *(uint32x4*)&sLo[SW(l, kb + 8*g)] = lq;
  }
  __syncthreads();

  // ---- layer 2 forward (MFMA): pre2[p][n], n in wave's 32-slice
  f32x4 acc[4][2];
  {
    const float b2a = b2[kb + lr];
    const float b2b = b2[kb + 16 + lr];
    #pragma unroll
    for (int mt = 0; mt < 4; mt++){
      acc[mt][0] = splat4(b2a);
      acc[mt][1] = splat4(b2b);
    }
  }
  #pragma unroll
  for (int kc = 0; kc < 4; kc++){
    frag_u bh0, bl0, bh1, bl1;
    const int f0 = ((kc*8 + 2*wv + 0)*64 + l)*8;
    const int f1 = ((kc*8 + 2*wv + 1)*64 + l)*8;
    bh0.q = *(const uint32x4*)(w2fh + f0);
    bl0.q = *(const uint32x4*)(w2fl + f0);
    bh1.q = *(const uint32x4*)(w2fh + f1);
    bl1.q = *(const uint32x4*)(w2fl + f1);
    const int kk = 32*kc + 8*lg;
    #pragma unroll
    for (int mt = 0; mt < 4; mt++){
      frag_u ah, al;
      ah.q = *(const uint32x4*)&sHi[SW(16*mt + lr, kk)];
      al.q = *(const uint32x4*)&sLo[SW(16*mt + lr, kk)];
      acc[mt][0] = __builtin_amdgcn_mfma_f32_16x16x32_bf16(ah.v, bh0.v, acc[mt][0], 0,0,0);
      acc[mt][0] = __builtin_amdgcn_mfma_f32_16x16x32_bf16(ah.v, bl0.v, acc[mt][0], 0,0,0);
      acc[mt][0] = __builtin_amdgcn_mfma_f32_16x16x32_bf16(al.v, bh0.v, acc[mt][0], 0,0,0);
      acc[mt][1] = __builtin_amdgcn_mfma_f32_16x16x32_bf16(ah.v, bh1.v, acc[mt][1], 0,0,0);
      acc[mt][1] = __builtin_amdgcn_mfma_f32_16x16x32_bf16(ah.v, bl1.v, acc[mt][1], 0,0,0);
      acc[mt][1] = __builtin_amdgcn_mfma_f32_16x16x32_bf16(al.v, bh1.v, acc[mt][1], 0,0,0);
    }
  }
  __syncthreads();   // all waves done reading h planes; sG may now be written

  // ---- fwd epilogue: sdf partials (validated) + g2 fp32 into sG[n][p]
  {
    const float w3a = W3[kb + lr];
    const float w3b = W3[kb + 16 + lr];
    #pragma unroll
    for (int mt = 0; mt < 4; mt++){
      float svr[4];
      #pragma unroll
      for (int r = 0; r < 4; r++){
        float pa = acc[mt][0][r], pb = acc[mt][1][r];
        svr[r] = sp_fast(pa)*w3a + sp_fast(pb)*w3b;
        int pr = 16*mt + 4*lg + r;                    // point (D-row, validated)
        sG[(kb + lr)*64      + pr] = sg_f(pa) * w3a;  // n = kb+lr
        sG[(kb + 16 + lr)*64 + pr] = sg_f(pb) * w3b;  // n = kb+16+lr
      }
      #pragma unroll
      for (int m = 1; m < 16; m <<= 1){
        svr[0] += __shfl_xor(svr[0], m);
        svr[1] += __shfl_xor(svr[1], m);
        svr[2] += __shfl_xor(svr[2], m);
        svr[3] += __shfl_xor(svr[3], m);
      }
      if (lr == 0){
        sRed[wv][16*mt + 4*lg + 0] = svr[0];
        sRed[wv][16*mt + 4*lg + 1] = svr[1];
        sRed[wv][16*mt + 4*lg + 2] = svr[2];
        sRed[wv][16*mt + 4*lg + 3] = svr[3];
      }
    }
  }
  __syncthreads();
  if (tid < 64)
    sdf_out[q0+tid] = b3[0] + sRed[0][tid] + sRed[1][tid] + sRed[2][tid] + sRed[3][tid];

  // ---- backward (round-0-verified VALU): dh1[p][k] = sum_n g2[p][n]*W2T[n][k]
  // lane owns point p = l; wave owns k-slice [kb, kb+32)
  float accD[32];
  #pragma unroll
  for (int j = 0; j < 32; j++) accD[j] = 0.0f;
  #pragma unroll 2
  for (int n = 0; n < HID; n++){
    const float gv = sG[n*64 + l];                   // stride-1 lanes: conflict-free
    const float* __restrict__ wr = &W2T[n*HID + kb]; // wave-uniform scalar row
    #pragma unroll
    for (int j = 0; j < 32; j++) accD[j] = fmaf(gv, wr[j], accD[j]);
  }

  // ---- bwd epilogue (round-0): dp1 = dh1*sg(pre1); grad = W1 @ dp1
  {
    float gxa = 0.f, gya = 0.f, gza = 0.f;
    #pragma unroll
    for (int j = 0; j < 32; j++){
      int k = kb + j;
      float w1a = W1[k], w1b = W1[HID+k], w1c = W1[2*HID+k];
      float pre1 = b1[k];
      pre1 = fmaf(x0, w1a, pre1);
      pre1 = fmaf(x1, w1b, pre1);
      pre1 = fmaf(x2, w1c, pre1);
      float d = accD[j] * sg_f(pre1);
      gxa = fmaf(w1a, d, gxa); gya = fmaf(w1b, d, gya); gza = fmaf(w1c, d, gza);
    }
    sGx[wv*64 + l] = gxa; sGy[wv*64 + l] = gya; sGz[wv*64 + l] = gza;
  }
  __syncthreads();
  if (tid < 64){
    float gx = sGx[tid] + sGx[64+tid] + sGx[128+tid] + sGx[192+tid];
    float gy = sGy[tid] + sGy[64+tid] + sGy[128+tid] + sGy[192+tid];
    float gz = sGz[tid] + sGz[64+tid] + sGz[128+tid] + sGz[192+tid];
    grad_out[(q0+tid)*3+0] = gx;
    grad_out[(q0+tid)*3+1] = gy;
    grad_out[(q0+tid)*3+2] = gz;
  }
}

// ---------------------------------------------------------------- scatters
__global__ void k_scatter_init(const float* __restrict__ sdf_tmp, float* __restrict__ sdf_buf){
  int idx = blockIdx.x*256 + threadIdx.x;
  if (idx >= NRAYS*64) return;
  sdf_buf[(idx >> 6)*128 + (idx & 63)] = sdf_tmp[idx];
}
__global__ void k_scatter_new(const float* __restrict__ sdf_tmp, const int* __restrict__ slots,
                              float* __restrict__ sdf_buf){
  int idx = blockIdx.x*256 + threadIdx.x;
  if (idx >= NRAYS*16) return;
  sdf_buf[(idx >> 4)*128 + slots[idx]] = sdf_tmp[idx];
}

// ---------------------------------------------------------------- upsample (one wave per ray)
__global__ __launch_bounds__(64) void k_upsample(
      const float* __restrict__ rays_o, const float* __restrict__ rays_d,
      float* __restrict__ z_buf, float* __restrict__ sdf_buf,
      float* __restrict__ pts_new, int* __restrict__ slots,
      int S, float inv_s, int last){
  __shared__ float z[128], sd[128], rad[128], cosv[128], alf[128], wv[128], cdf[129], nz[16];
  __shared__ int slt[16];
  const int ray = blockIdx.x;
  const int l   = threadIdx.x;
  const float ox = rays_o[ray*3], oy = rays_o[ray*3+1], oz = rays_o[ray*3+2];
  const float dx = rays_d[ray*3], dy = rays_d[ray*3+1], dz = rays_d[ray*3+2];
  for (int j = l; j < S; j += 64){
    float zz = z_buf[ray*128+j];
    z[j]  = zz;
    sd[j] = sdf_buf[ray*128+j];
    float px = ox+dx*zz, py = oy+dy*zz, pz = oz+dz*zz;
    rad[j] = sqrtf(px*px + py*py + pz*pz);
  }
  __syncthreads();
  for (int j = l; j < S-1; j += 64)
    cosv[j] = (sd[j+1]-sd[j]) / (z[j+1]-z[j] + 1e-5f);
  __syncthreads();
  for (int j = l; j < S-1; j += 64){
    float cv = fminf((j > 0) ? cosv[j-1] : 0.0f, cosv[j]);
    cv = fminf(fmaxf(cv, -1000.0f), 0.0f);
    float inside = (rad[j] < 1.0f || rad[j+1] < 1.0f) ? 1.0f : 0.0f;
    cv *= inside;
    float mid  = 0.5f*(sd[j]+sd[j+1]);
    float dist = z[j+1]-z[j];
    float e = sg_f((mid - cv*dist*0.5f)*inv_s);
    float f = sg_f((mid + cv*dist*0.5f)*inv_s);
    alf[j] = (e - f + 1e-5f) / (e + 1e-5f);
  }
  __syncthreads();
  if (l == 0){
    float T = 1.0f, wsum = 0.0f;
    for (int j = 0; j < S-1; j++){
      float w = alf[j]*T + 1e-5f;   // weights = alpha*trans + 1e-5
      wv[j] = w; wsum += w;
      T *= (1.0f - alf[j] + 1e-7f);
    }
    cdf[0] = 0.0f;
    float c = 0.0f;
    for (int j = 0; j < S-1; j++){ c += wv[j]/wsum; cdf[j+1] = c; }
  }
  __syncthreads();
  if (l < 16){
    float u = 0.03125f + 0.0625f*(float)l;   // linspace(1/32, 31/32, 16)
    int idx = 0;
    while (idx < S && cdf[idx] <= u) idx++;  // searchsorted side='right'
    int below = idx - 1; if (below < 0) below = 0;
    int above = (idx < S-1) ? idx : (S-1);
    float cb = cdf[below], ca = cdf[above];
    float den = ca - cb; if (den < 1e-5f) den = 1.0f;
    float t = (u - cb) / den;
    nz[l] = z[below] + t*(z[above] - z[below]);
  }
  __syncthreads();
  if (l == 0){
    // stable in-place merge from the back (old-before-new on ties)
    int i = S-1, j = 15;
    for (int dst = S+15; dst >= 0; --dst){
      bool takeOld = (j < 0) || (i >= 0 && z[i] > nz[j]);
      if (takeOld){ z[dst] = z[i]; sd[dst] = sd[i]; i--; }
      else        { z[dst] = nz[j]; slt[j] = dst; j--; }
    }
  }
  __syncthreads();
  for (int j = l; j < S+16; j += 64){
    z_buf[ray*128+j]  = z[j];
    sdf_buf[ray*128+j] = sd[j];
  }
  if (!last && l < 16){
    slots[ray*16+l] = slt[l];
    float zz = nz[l];
    pts_new[(ray*16+l)*3+0] = ox + dx*zz;
    pts_new[(ray*16+l)*3+1] = oy + dy*zz;
    pts_new[(ray*16+l)*3+2] = oz + dz*zz;
  }
}

// ---------------------------------------------------------------- final mid-point pts
__global__ void k_prep(const float* __restrict__ rays_o, const float* __restrict__ rays_d,
                       const float* __restrict__ z_buf, float* __restrict__ pts){
  int idx = blockIdx.x*256 + threadIdx.x;
  if (idx >= NRAYS*128) return;
  int ray = idx >> 7, s = idx & 127;
  float z = z_buf[idx];
  float d = (s < 127) ? (z_buf[idx+1] - z) : 0.03125f;   // SAMPLE_DIST = 2/64
  float mid = z + 0.5f*d;
  pts[idx*3+0] = rays_o[ray*3+0] + rays_d[ray*3+0]*mid;
  pts[idx*3+1] = rays_o[ray*3+1] + rays_d[ray*3+1]*mid;
  pts[idx*3+2] = rays_o[ray*3+2] + rays_d[ray*3+2]*mid;
}

// ---------------------------------------------------------------- render (one thread per ray)
__global__ void k_render(const float* __restrict__ z_buf, const float* __restrict__ sdf_mid,
                         const float* __restrict__ rays_d, const float* __restrict__ grad,
                         const float* __restrict__ variance, float* __restrict__ depth_out){
  int ray = blockIdx.x*64 + threadIdx.x;
  if (ray >= NRAYS) return;
  float inv_s = expf(10.0f * variance[0]);
  inv_s = fminf(fmaxf(inv_s, 1e-6f), 1e6f);
  const float dx = rays_d[ray*3], dy = rays_d[ray*3+1], dz = rays_d[ray*3+2];
  float T = 1.0f, depth = 0.0f;
  float zc = z_buf[ray*128];
  for (int s = 0; s < 128; s++){
    int idx = ray*128 + s;
    float zn = (s < 127) ? z_buf[idx+1] : zc;
    float d  = (s < 127) ? (zn - zc) : 0.03125f;
    float sdf = sdf_mid[idx];
    float gx = grad[idx*3], gy = grad[idx*3+1], gz = grad[idx*3+2];
    float tc = dx*gx + dy*gy + dz*gz;
    float ic = -fmaxf(0.5f - 0.5f*tc, 0.0f);     // COS_ANNEAL_RATIO = 0
    float e = sg_f((sdf - ic*d*0.5f)*inv_s);
    float f = sg_f((sdf + ic*d*0.5f)*inv_s);
    float a = (e - f + 1e-5f) / (e + 1e-5f);
    a = fminf(fmaxf(a, 0.0f), 1.0f);
    depth += a*T*zc;
    T *= (1.0f - a + 1e-7f);
    zc = zn;
  }
  depth_out[ray] = depth;
}

// ---------------------------------------------------------------- launcher
extern "C" void kernel_launch(void* const* d_in, const int* in_sizes, int n_in,
                              void* d_out, int out_size, void* d_ws, size_t ws_size,
                              hipStream_t stream){
  (void)in_sizes; (void)n_in; (void)out_size; (void)ws_size;
  const float* rays_o = (const float*)d_in[0];
  const float* rays_d = (const float*)d_in[1];
  const float* nearv  = (const float*)d_in[2];
  const float* farv   = (const float*)d_in[3];
  const float* W1 = (const float*)d_in[4];
  const float* b1 = (const float*)d_in[5];
  const float* W2 = (const float*)d_in[6];
  const float* b2 = (const float*)d_in[7];
  const float* W3 = (const float*)d_in[8];
  const float* b3 = (const float*)d_in[9];
  const float* variance = (const float*)d_in[10];

  // Workspace layout: EXACTLY round-0's proven footprint (6,619,136 B).
  float* ws      = (float*)d_ws;
  float* z_buf   = ws;                    // [0,       524288)
  float* sdf_buf = ws + 524288;           // [524288,  1048576)
  float* sdf_tmp = ws + 1048576;          // [1048576, 1572864)
  float* W2T     = ws + 1572864;          // [1572864, 1589248)
  int*   slots   = (int*)(ws + 1589248);  // [1589248, 1654784) as ints
  // Fwd MFMA fragments alias sdf_buf — created AFTER the upsample loop,
  // when sdf_buf is dead (nothing reads it after the last k_upsample).
  unsigned short* w2fh = (unsigned short*)(ws + 524288);  // 16384 ushorts
  unsigned short* w2fl = w2fh + 16384;                    // 16384 ushorts

  float* out       = (float*)d_out;
  float* depth_out = out;
  float* grad_out  = out + NRAYS;         // 524288*3 floats
  float* pts       = grad_out;            // pts staging aliases grad region

  k_transpose<<<dim3(64), dim3(256), 0, stream>>>(W2, W2T);
  k_init<<<dim3(1024), dim3(256), 0, stream>>>(rays_o, rays_d, nearv, farv, z_buf, pts);
  k_mlp_fwd<<<dim3(4096), dim3(256), 0, stream>>>(pts, W1,b1,W2,b2,W3,b3, sdf_tmp);
  k_scatter_init<<<dim3(1024), dim3(256), 0, stream>>>(sdf_tmp, sdf_buf);

  for (int i = 0; i < 4; i++){
    int S = 64 + 16*i;
    float inv_s = (float)(64 << i);
    int last = (i == 3) ? 1 : 0;
    k_upsample<<<dim3(4096), dim3(64), 0, stream>>>(rays_o, rays_d, z_buf, sdf_buf,
                                                    pts, slots, S, inv_s, last);
    if (!last){
      k_mlp_fwd<<<dim3(1024), dim3(256), 0, stream>>>(pts, W1,b1,W2,b2,W3,b3, sdf_tmp);
      k_scatter_new<<<dim3(256), dim3(256), 0, stream>>>(sdf_tmp, slots, sdf_buf);
    }
  }

  // sdf_buf is dead from here on — safe to overwrite with fragments.
  k_make_frags<<<dim3(8), dim3(256), 0, stream>>>(W2, w2fh, w2fl);
  k_prep<<<dim3(2048), dim3(256), 0, stream>>>(rays_o, rays_d, z_buf, pts);
  k_mlp_bwd<<<dim3(8192), dim3(256), 0, stream>>>(pts, W1,b1,b2,W3,b3,
                                                  w2fh,w2fl, W2T, sdf_tmp, grad_out);
  k_render<<<dim3(64), dim3(64), 0, stream>>>(z_buf, sdf_tmp, rays_d, grad_out,
                                              variance, depth_out);
}

// Round 6
// 1032.151 us; speedup vs baseline: 1.4957x; 1.0641x over previous
//
#include <hip/hip_runtime.h>
#include <math.h>

#define HID 128
#define NRAYS 4096
#define TP 64   // points per MLP tile (one per lane)

typedef __bf16 bf16x8 __attribute__((ext_vector_type(8)));
typedef float f32x4 __attribute__((ext_vector_type(4)));
typedef unsigned int uint32x4 __attribute__((ext_vector_type(4)));

union frag_u { bf16x8 v; uint32x4 q; };

__device__ __forceinline__ unsigned f2bf(float f){   // fp32 -> bf16 bits, RNE
  unsigned u = __float_as_uint(f);
  u += 0x7FFFu + ((u >> 16) & 1u);
  return u >> 16;
}
__device__ __forceinline__ float bf2f(unsigned h){
  return __uint_as_float(h << 16);
}
__device__ __forceinline__ float sp_f(float x){      // softplus, libm-precision
  return fmaxf(x, 0.0f) + log1pf(expf(-fabsf(x)));
}
__device__ __forceinline__ float sp_fast(float x){   // softplus, fast (final kernel)
  float e = __expf(-fabsf(x));
  return fmaxf(x, 0.0f) + __logf(1.0f + e);
}
__device__ __forceinline__ float sg_f(float x){      // sigmoid, libm-precision
  return 1.0f / (1.0f + expf(-x));
}
__device__ __forceinline__ f32x4 splat4(float x){
  f32x4 v = {x, x, x, x};
  return v;
}

// Swizzled LDS index (ushort units) for a [64][128] bf16 plane.
// byte ^= ((row&7)<<4)  ->  ushort idx ^= ((row&7)<<3). Keeps 16B alignment.
#define SW(p,k) ((((p)*HID) + (k)) ^ (((p)&7)<<3))

// ---------------------------------------------------------------- transpose W2 (fp32, for VALU bwd)
__global__ void k_transpose(const float* __restrict__ W2, float* __restrict__ W2T){
  int idx = blockIdx.x*256 + threadIdx.x;
  if (idx < HID*HID){
    int k = idx >> 7, n = idx & 127;
    W2T[n*HID + k] = W2[k*HID + n];
  }
}

// ---------------------------------------------------------------- W2 fwd-fragment prep (2-way, final kernel)
// Validated in round 4. frag f = kc*8 + tg; contraction a = 32*kc + 8*(lane>>4)+e,
// output b = 16*tg + (lane&15). Stored at [(f*64+lane)*8 + e].
__global__ void k_make_frags(const float* __restrict__ W2,
    unsigned short* __restrict__ w2fh, unsigned short* __restrict__ w2fl){
  int idx = blockIdx.x*256 + threadIdx.x;
  if (idx >= 2048) return;
  int f    = idx >> 6;             // 0..31
  int lane = idx & 63;
  int kc = f >> 3, tg = f & 7;
  int lg = lane >> 4, lr = lane & 15;
  int base = (f*64 + lane)*8;
  #pragma unroll
  for (int e = 0; e < 8; e++){
    int a = 32*kc + 8*lg + e;      // contraction index k
    int b = 16*tg + lr;            // output index n
    float v = W2[a*HID + b];
    unsigned hi = f2bf(v);
    w2fh[base+e] = (unsigned short)hi;
    w2fl[base+e] = (unsigned short)f2bf(v - bf2f(hi));
  }
}

// ---------------------------------------------------------------- W2 fwd-fragment prep (3-way, precision fwd)
// Triple-bf16 split: v = hi + mid + lo to ~2^-27 relative. Same fragment order.
__global__ void k_make_frags3(const float* __restrict__ W2,
    unsigned short* __restrict__ dh, unsigned short* __restrict__ dm,
    unsigned short* __restrict__ dl){
  int idx = blockIdx.x*256 + threadIdx.x;
  if (idx >= 2048) return;
  int f    = idx >> 6;             // 0..31
  int lane = idx & 63;
  int kc = f >> 3, tg = f & 7;
  int lg = lane >> 4, lr = lane & 15;
  int base = (f*64 + lane)*8;
  #pragma unroll
  for (int e = 0; e < 8; e++){
    int a = 32*kc + 8*lg + e;      // contraction index k
    int b = 16*tg + lr;            // output index n
    float v = W2[a*HID + b];
    unsigned hi = f2bf(v);
    float rm = v - bf2f(hi);
    unsigned md = f2bf(rm);
    dh[base+e] = (unsigned short)hi;
    dm[base+e] = (unsigned short)md;
    dl[base+e] = (unsigned short)f2bf(rm - bf2f(md));
  }
}

// ---------------------------------------------------------------- initial z + pts
__global__ void k_init(const float* __restrict__ rays_o, const float* __restrict__ rays_d,
                       const float* __restrict__ nearv, const float* __restrict__ farv,
                       float* __restrict__ z_buf, float* __restrict__ pts){
  int idx = blockIdx.x*256 + threadIdx.x;
  if (idx >= NRAYS*64) return;
  int ray = idx >> 6, j = idx & 63;
  float nr = nearv[ray];
  float z = nr + (farv[ray] - nr) * ((float)j / 63.0f);
  z_buf[ray*128 + j] = z;
  pts[idx*3+0] = rays_o[ray*3+0] + rays_d[ray*3+0]*z;
  pts[idx*3+1] = rays_o[ray*3+1] + rays_d[ray*3+1]*z;
  pts[idx*3+2] = rays_o[ray*3+2] + rays_d[ray*3+2]*z;
}

// ---------------------------------------------------------------- MLP forward, MFMA 6-term
// Feeds the upsample cdf. Triple-bf16 split of h and W2; split accumulators:
// acc (b2 + hh terms, fp32) + accC (hm+mh+hl+mm+lh). Residual ~1e-6 on pre2 —
// same order as the r0-proven fp32 reassociation error. Structure is a verbatim
// copy of the round-4 pass-validated MFMA forward (staging, SW swizzle,
// fragment maps, D-readout, epilogue).
// A-frag: row p = 16*mt + (lane&15), k = 32*kc + 8*(lane>>4) + e
// B-frag: col   = 16*tg + (lane&15), same k-map
// C/D   : col = lane&15, row = 4*(lane>>4) + reg   [pass-validated]
__global__ __launch_bounds__(256, 3) void k_mlp_fwd_t(
    const float* __restrict__ pts,
    const float* __restrict__ W1, const float* __restrict__ b1,
    const float* __restrict__ b2,
    const float* __restrict__ W3, const float* __restrict__ b3,
    const unsigned short* __restrict__ w2h, const unsigned short* __restrict__ w2m,
    const unsigned short* __restrict__ w2l,
    float* __restrict__ sdf_out)
{
  __shared__ unsigned short sHi[64*HID];   // 16 KB each
  __shared__ unsigned short sMi[64*HID];
  __shared__ unsigned short sLo[64*HID];
  __shared__ float sRed[4][64];

  const int tid = threadIdx.x;
  const int l   = tid & 63;
  const int wv  = __builtin_amdgcn_readfirstlane(tid >> 6);
  const int lg  = l >> 4;
  const int lr  = l & 15;
  const int q0  = blockIdx.x * 64;
  const int kb  = 32*wv;

  const float x0 = pts[(q0+l)*3+0];
  const float x1 = pts[(q0+l)*3+1];
  const float x2 = pts[(q0+l)*3+2];

  // ---- layer 1: point l, k in wave's 32-slice; libm softplus, 3-way split
  #pragma unroll
  for (int g = 0; g < 4; g++){
    unsigned hw[4], mw[4], lw[4];
    #pragma unroll
    for (int e2 = 0; e2 < 4; e2++){
      unsigned hpk[2], mpk[2], lpk[2];
      #pragma unroll
      for (int t = 0; t < 2; t++){
        int k = kb + 8*g + 2*e2 + t;
        float pre = b1[k];
        pre = fmaf(x0, W1[k],       pre);
        pre = fmaf(x1, W1[HID+k],   pre);
        pre = fmaf(x2, W1[2*HID+k], pre);
        float h = sp_f(pre);
        unsigned hi = f2bf(h);
        float rm = h - bf2f(hi);
        unsigned md = f2bf(rm);
        hpk[t] = hi; mpk[t] = md;
        lpk[t] = f2bf(rm - bf2f(md));
      }
      hw[e2] = hpk[0] | (hpk[1] << 16);
      mw[e2] = mpk[0] | (mpk[1] << 16);
      lw[e2] = lpk[0] | (lpk[1] << 16);
    }
    uint32x4 hq = {hw[0], hw[1], hw[2], hw[3]};
    uint32x4 mq = {mw[0], mw[1], mw[2], mw[3]};
    uint32x4 lq = {lw[0], lw[1], lw[2], lw[3]};
    *(uint32x4*)&sHi[SW(l, kb + 8*g)] = hq;
    *(uint32x4*)&sMi[SW(l, kb + 8*g)] = mq;
    *(uint32x4*)&sLo[SW(l, kb + 8*g)] = lq;
  }
  __syncthreads();

  // ---- layer 2: pre2[p][n] via 6-term MFMA, split accumulators
  f32x4 acc[4][2], accC[4][2];
  {
    const float b2a = b2[kb + lr];
    const float b2b = b2[kb + 16 + lr];
    #pragma unroll
    for (int mt = 0; mt < 4; mt++){
      acc[mt][0]  = splat4(b2a);
      acc[mt][1]  = splat4(b2b);
      accC[mt][0] = splat4(0.0f);
      accC[mt][1] = splat4(0.0f);
    }
  }
  #pragma unroll
  for (int kc = 0; kc < 4; kc++){
    frag_u bh0, bm0, bl0, bh1, bm1, bl1;
    const int f0 = ((kc*8 + 2*wv + 0)*64 + l)*8;
    const int f1 = ((kc*8 + 2*wv + 1)*64 + l)*8;
    bh0.q = *(const uint32x4*)(w2h + f0);
    bm0.q = *(const uint32x4*)(w2m + f0);
    bl0.q = *(const uint32x4*)(w2l + f0);
    bh1.q = *(const uint32x4*)(w2h + f1);
    bm1.q = *(const uint32x4*)(w2m + f1);
    bl1.q = *(const uint32x4*)(w2l + f1);
    const int kk = 32*kc + 8*lg;
    #pragma unroll
    for (int mt = 0; mt < 4; mt++){
      frag_u ah, am, al;
      ah.q = *(const uint32x4*)&sHi[SW(16*mt + lr, kk)];
      am.q = *(const uint32x4*)&sMi[SW(16*mt + lr, kk)];
      al.q = *(const uint32x4*)&sLo[SW(16*mt + lr, kk)];
      // corrections small->large, hh into the main accumulator
      accC[mt][0] = __builtin_amdgcn_mfma_f32_16x16x32_bf16(ah.v, bl0.v, accC[mt][0], 0,0,0);
      accC[mt][0] = __builtin_amdgcn_mfma_f32_16x16x32_bf16(am.v, bm0.v, accC[mt][0], 0,0,0);
      accC[mt][0] = __builtin_amdgcn_mfma_f32_16x16x32_bf16(al.v, bh0.v, accC[mt][0], 0,0,0);
      accC[mt][0] = __builtin_amdgcn_mfma_f32_16x16x32_bf16(ah.v, bm0.v, accC[mt][0], 0,0,0);
      accC[mt][0] = __builtin_amdgcn_mfma_f32_16x16x32_bf16(am.v, bh0.v, accC[mt][0], 0,0,0);
      acc[mt][0]  = __builtin_amdgcn_mfma_f32_16x16x32_bf16(ah.v, bh0.v, acc[mt][0],  0,0,0);
      accC[mt][1] = __builtin_amdgcn_mfma_f32_16x16x32_bf16(ah.v, bl1.v, accC[mt][1], 0,0,0);
      accC[mt][1] = __builtin_amdgcn_mfma_f32_16x16x32_bf16(am.v, bm1.v, accC[mt][1], 0,0,0);
      accC[mt][1] = __builtin_amdgcn_mfma_f32_16x16x32_bf16(al.v, bh1.v, accC[mt][1], 0,0,0);
      accC[mt][1] = __builtin_amdgcn_mfma_f32_16x16x32_bf16(ah.v, bm1.v, accC[mt][1], 0,0,0);
      accC[mt][1] = __builtin_amdgcn_mfma_f32_16x16x32_bf16(am.v, bh1.v, accC[mt][1], 0,0,0);
      acc[mt][1]  = __builtin_amdgcn_mfma_f32_16x16x32_bf16(ah.v, bh1.v, acc[mt][1],  0,0,0);
    }
  }

  // ---- epilogue: sdf = b3 + sum sp(pre2)*W3 (validated reduce structure)
  {
    const float w3a = W3[kb + lr];
    const float w3b = W3[kb + 16 + lr];
    #pragma unroll
    for (int mt = 0; mt < 4; mt++){
      float svr[4];
      #pragma unroll
      for (int r = 0; r < 4; r++){
        float pa = acc[mt][0][r] + accC[mt][0][r];
        float pb = acc[mt][1][r] + accC[mt][1][r];
        svr[r] = sp_f(pa)*w3a + sp_f(pb)*w3b;
      }
      #pragma unroll
      for (int m = 1; m < 16; m <<= 1){
        svr[0] += __shfl_xor(svr[0], m);
        svr[1] += __shfl_xor(svr[1], m);
        svr[2] += __shfl_xor(svr[2], m);
        svr[3] += __shfl_xor(svr[3], m);
      }
      if (lr == 0){
        sRed[wv][16*mt + 4*lg + 0] = svr[0];
        sRed[wv][16*mt + 4*lg + 1] = svr[1];
        sRed[wv][16*mt + 4*lg + 2] = svr[2];
        sRed[wv][16*mt + 4*lg + 3] = svr[3];
      }
    }
  }
  __syncthreads();
  if (tid < 64)
    sdf_out[q0+tid] = b3[0] + sRed[0][tid] + sRed[1][tid] + sRed[2][tid] + sRed[3][tid];
}

// ---------------------------------------------------------------- MLP fwd(MFMA) + bwd(VALU)
// PASS-VALIDATED in round 4 (1098 us). Only change this round: sG stride
// 64 -> 65 to break the 16-way bank conflict on the g2 staging writes
// (1.9e7 SQ_LDS_BANK_CONFLICT). Write and read sides changed consistently.
__global__ __launch_bounds__(256, 4) void k_mlp_bwd(
    const float* __restrict__ pts,
    const float* __restrict__ W1, const float* __restrict__ b1,
    const float* __restrict__ b2,
    const float* __restrict__ W3, const float* __restrict__ b3,
    const unsigned short* __restrict__ w2fh, const unsigned short* __restrict__ w2fl,
    const float* __restrict__ W2T,
    float* __restrict__ sdf_out, float* __restrict__ grad_out)
{
  __shared__ __align__(16) unsigned char sBuf[33280];  // planes (32 KB) / padded sG (33280 B)
  unsigned short* sHi = (unsigned short*)sBuf;         // h1 hi plane (16 KB)
  unsigned short* sLo = sHi + 64*HID;                  // h1 lo plane (16 KB)
  float*          sG  = (float*)sBuf;                  // g2 [n][p] fp32, stride 65
  __shared__ float sRed[4][64];                        // sdf partials per wave
  __shared__ float sGx[4*64], sGy[4*64], sGz[4*64];    // grad partials per wave

  const int tid = threadIdx.x;
  const int l   = tid & 63;
  const int wv  = __builtin_amdgcn_readfirstlane(tid >> 6);
  const int lg  = l >> 4;
  const int lr  = l & 15;
  const int q0  = blockIdx.x * 64;
  const int kb  = 32*wv;

  const float x0 = pts[(q0+l)*3+0];
  const float x1 = pts[(q0+l)*3+1];
  const float x2 = pts[(q0+l)*3+2];

  // ---- layer 1: point l, k in [32wv, 32wv+32); bf16 hi/lo staged for MFMA
  #pragma unroll
  for (int g = 0; g < 4; g++){
    unsigned hw[4], lw[4];
    #pragma unroll
    for (int e2 = 0; e2 < 4; e2++){
      unsigned hpk[2], lpk[2];
      #pragma unroll
      for (int t = 0; t < 2; t++){
        int k = kb + 8*g + 2*e2 + t;
        float pre = b1[k];
        pre = fmaf(x0, W1[k],       pre);
        pre = fmaf(x1, W1[HID+k],   pre);
        pre = fmaf(x2, W1[2*HID+k], pre);
        float h = sp_fast(pre);
        unsigned hi = f2bf(h);
        hpk[t] = hi;
        lpk[t] = f2bf(h - bf2f(hi));
      }
      hw[e2] = hpk[0] | (hpk[1] << 16);
      lw[e2] = lpk[0] | (lpk[1] << 16);
    }
    uint32x4 hq = {hw[0], hw[1], hw[2], hw[3]};
    uint32x4 lq = {lw[0], lw[1], lw[2], lw[3]};
    *(uint32x4*)&sHi[SW(l, kb + 8*g)] = hq;
    *(uint32x4*)&sLo[SW(l, kb + 8*g)] = lq;
  }
  __syncthreads();

  // ---- layer 2 forward (MFMA): pre2[p][n], n in wave's 32-slice
  f32x4 acc[4][2];
  {
    const float b2a = b2[kb + lr];
    const float b2b = b2[kb + 16 + lr];
    #pragma unroll
    for (int mt = 0; mt < 4; mt++){
      acc[mt][0] = splat4(b2a);
      acc[mt][1] = splat4(b2b);
    }
  }
  #pragma unroll
  for (int kc = 0; kc < 4; kc++){
    frag_u bh0, bl0, bh1, bl1;
    const int f0 = ((kc*8 + 2*wv + 0)*64 + l)*8;
    const int f1 = ((kc*8 + 2*wv + 1)*64 + l)*8;
    bh0.q = *(const uint32x4*)(w2fh + f0);
    bl0.q = *(const uint32x4*)(w2fl + f0);
    bh1.q = *(const uint32x4*)(w2fh + f1);
    bl1.q = *(const uint32x4*)(w2fl + f1);
    const int kk = 32*kc + 8*lg;
    #pragma unroll
    for (int mt = 0; mt < 4; mt++){
      frag_u ah, al;
      ah.q = *(const uint32x4*)&sHi[SW(16*mt + lr, kk)];
      al.q = *(const uint32x4*)&sLo[SW(16*mt + lr, kk)];
      acc[mt][0] = __builtin_amdgcn_mfma_f32_16x16x32_bf16(ah.v, bh0.v, acc[mt][0], 0,0,0);
      acc[mt][0] = __builtin_amdgcn_mfma_f32_16x16x32_bf16(ah.v, bl0.v, acc[mt][0], 0,0,0);
      acc[mt][0] = __builtin_amdgcn_mfma_f32_16x16x32_bf16(al.v, bh0.v, acc[mt][0], 0,0,0);
      acc[mt][1] = __builtin_amdgcn_mfma_f32_16x16x32_bf16(ah.v, bh1.v, acc[mt][1], 0,0,0);
      acc[mt][1] = __builtin_amdgcn_mfma_f32_16x16x32_bf16(ah.v, bl1.v, acc[mt][1], 0,0,0);
      acc[mt][1] = __builtin_amdgcn_mfma_f32_16x16x32_bf16(al.v, bh1.v, acc[mt][1], 0,0,0);
    }
  }
  __syncthreads();   // all waves done reading h planes; sG may now be written

  // ---- fwd epilogue: sdf partials + g2 fp32 into sG[n][p] (stride 65)
  {
    const float w3a = W3[kb + lr];
    const float w3b = W3[kb + 16 + lr];
    #pragma unroll
    for (int mt = 0; mt < 4; mt++){
      float svr[4];
      #pragma unroll
      for (int r = 0; r < 4; r++){
        float pa = acc[mt][0][r], pb = acc[mt][1][r];
        svr[r] = sp_fast(pa)*w3a + sp_fast(pb)*w3b;
        int pr = 16*mt + 4*lg + r;                    // point (D-row, validated)
        sG[(kb + lr)*65      + pr] = sg_f(pa) * w3a;  // n = kb+lr
        sG[(kb + 16 + lr)*65 + pr] = sg_f(pb) * w3b;  // n = kb+16+lr
      }
      #pragma unroll
      for (int m = 1; m < 16; m <<= 1){
        svr[0] += __shfl_xor(svr[0], m);
        svr[1] += __shfl_xor(svr[1], m);
        svr[2] += __shfl_xor(svr[2], m);
        svr[3] += __shfl_xor(svr[3], m);
      }
      if (lr == 0){
        sRed[wv][16*mt + 4*lg + 0] = svr[0];
        sRed[wv][16*mt + 4*lg + 1] = svr[1];
        sRed[wv][16*mt + 4*lg + 2] = svr[2];
        sRed[wv][16*mt + 4*lg + 3] = svr[3];
      }
    }
  }
  __syncthreads();
  if (tid < 64)
    sdf_out[q0+tid] = b3[0] + sRed[0][tid] + sRed[1][tid] + sRed[2][tid] + sRed[3][tid];

  // ---- backward (round-0-verified VALU): dh1[p][k] = sum_n g2[p][n]*W2T[n][k]
  float accD[32];
  #pragma unroll
  for (int j = 0; j < 32; j++) accD[j] = 0.0f;
  #pragma unroll 2
  for (int n = 0; n < HID; n++){
    const float gv = sG[n*65 + l];                   // stride-1 lanes: conflict-free
    const float* __restrict__ wr = &W2T[n*HID + kb]; // wave-uniform scalar row
    #pragma unroll
    for (int j = 0; j < 32; j++) accD[j] = fmaf(gv, wr[j], accD[j]);
  }

  // ---- bwd epilogue (round-0): dp1 = dh1*sg(pre1); grad = W1 @ dp1
  {
    float gxa = 0.f, gya = 0.f, gza = 0.f;
    #pragma unroll
    for (int j = 0; j < 32; j++){
      int k = kb + j;
      float w1a = W1[k], w1b = W1[HID+k], w1c = W1[2*HID+k];
      float pre1 = b1[k];
      pre1 = fmaf(x0, w1a, pre1);
      pre1 = fmaf(x1, w1b, pre1);
      pre1 = fmaf(x2, w1c, pre1);
      float d = accD[j] * sg_f(pre1);
      gxa = fmaf(w1a, d, gxa); gya = fmaf(w1b, d, gya); gza = fmaf(w1c, d, gza);
    }
    sGx[wv*64 + l] = gxa; sGy[wv*64 + l] = gya; sGz[wv*64 + l] = gza;
  }
  __syncthreads();
  if (tid < 64){
    float gx = sGx[tid] + sGx[64+tid] + sGx[128+tid] + sGx[192+tid];
    float gy = sGy[tid] + sGy[64+tid] + sGy[128+tid] + sGy[192+tid];
    float gz = sGz[tid] + sGz[64+tid] + sGz[128+tid] + sGz[192+tid];
    grad_out[(q0+tid)*3+0] = gx;
    grad_out[(q0+tid)*3+1] = gy;
    grad_out[(q0+tid)*3+2] = gz;
  }
}

// ---------------------------------------------------------------- scatters
__global__ void k_scatter_init(const float* __restrict__ sdf_tmp, float* __restrict__ sdf_buf){
  int idx = blockIdx.x*256 + threadIdx.x;
  if (idx >= NRAYS*64) return;
  sdf_buf[(idx >> 6)*128 + (idx & 63)] = sdf_tmp[idx];
}
__global__ void k_scatter_new(const float* __restrict__ sdf_tmp, const int* __restrict__ slots,
                              float* __restrict__ sdf_buf){
  int idx = blockIdx.x*256 + threadIdx.x;
  if (idx >= NRAYS*16) return;
  sdf_buf[(idx >> 4)*128 + slots[idx]] = sdf_tmp[idx];
}

// ---------------------------------------------------------------- upsample (one wave per ray)
__global__ __launch_bounds__(64) void k_upsample(
      const float* __restrict__ rays_o, const float* __restrict__ rays_d,
      float* __restrict__ z_buf, float* __restrict__ sdf_buf,
      float* __restrict__ pts_new, int* __restrict__ slots,
      int S, float inv_s, int last){
  __shared__ float z[128], sd[128], rad[128], cosv[128], alf[128], wv[128], cdf[129], nz[16];
  __shared__ int slt[16];
  const int ray = blockIdx.x;
  const int l   = threadIdx.x;
  const float ox = rays_o[ray*3], oy = rays_o[ray*3+1], oz = rays_o[ray*3+2];
  const float dx = rays_d[ray*3], dy = rays_d[ray*3+1], dz = rays_d[ray*3+2];
  for (int j = l; j < S; j += 64){
    float zz = z_buf[ray*128+j];
    z[j]  = zz;
    sd[j] = sdf_buf[ray*128+j];
    float px = ox+dx*zz, py = oy+dy*zz, pz = oz+dz*zz;
    rad[j] = sqrtf(px*px + py*py + pz*pz);
  }
  __syncthreads();
  for (int j = l; j < S-1; j += 64)
    cosv[j] = (sd[j+1]-sd[j]) / (z[j+1]-z[j] + 1e-5f);
  __syncthreads();
  for (int j = l; j < S-1; j += 64){
    float cv = fminf((j > 0) ? cosv[j-1] : 0.0f, cosv[j]);
    cv = fminf(fmaxf(cv, -1000.0f), 0.0f);
    float inside = (rad[j] < 1.0f || rad[j+1] < 1.0f) ? 1.0f : 0.0f;
    cv *= inside;
    float mid  = 0.5f*(sd[j]+sd[j+1]);
    float dist = z[j+1]-z[j];
    float e = sg_f((mid - cv*dist*0.5f)*inv_s);
    float f = sg_f((mid + cv*dist*0.5f)*inv_s);
    alf[j] = (e - f + 1e-5f) / (e + 1e-5f);
  }
  __syncthreads();
  if (l == 0){
    float T = 1.0f, wsum = 0.0f;
    for (int j = 0; j < S-1; j++){
      float w = alf[j]*T + 1e-5f;   // weights = alpha*trans + 1e-5
      wv[j] = w; wsum += w;
      T *= (1.0f - alf[j] + 1e-7f);
    }
    cdf[0] = 0.0f;
    float c = 0.0f;
    for (int j = 0; j < S-1; j++){ c += wv[j]/wsum; cdf[j+1] = c; }
  }
  __syncthreads();
  if (l < 16){
    float u = 0.03125f + 0.0625f*(float)l;   // linspace(1/32, 31/32, 16)
    int idx = 0;
    while (idx < S && cdf[idx] <= u) idx++;  // searchsorted side='right'
    int below = idx - 1; if (below < 0) below = 0;
    int above = (idx < S-1) ? idx : (S-1);
    float cb = cdf[below], ca = cdf[above];
    float den = ca - cb; if (den < 1e-5f) den = 1.0f;
    float t = (u - cb) / den;
    nz[l] = z[below] + t*(z[above] - z[below]);
  }
  __syncthreads();
  if (l == 0){
    // stable in-place merge from the back (old-before-new on ties)
    int i = S-1, j = 15;
    for (int dst = S+15; dst >= 0; --dst){
      bool takeOld = (j < 0) || (i >= 0 && z[i] > nz[j]);
      if (takeOld){ z[dst] = z[i]; sd[dst] = sd[i]; i--; }
      else        { z[dst] = nz[j]; slt[j] = dst; j--; }
    }
  }
  __syncthreads();
  for (int j = l; j < S+16; j += 64){
    z_buf[ray*128+j]  = z[j];
    sdf_buf[ray*128+j] = sd[j];
  }
  if (!last && l < 16){
    slots[ray*16+l] = slt[l];
    float zz = nz[l];
    pts_new[(ray*16+l)*3+0] = ox + dx*zz;
    pts_new[(ray*16+l)*3+1] = oy + dy*zz;
    pts_new[(ray*16+l)*3+2] = oz + dz*zz;
  }
}

// ---------------------------------------------------------------- final mid-point pts
__global__ void k_prep(const float* __restrict__ rays_o, const float* __restrict__ rays_d,
                       const float* __restrict__ z_buf, float* __restrict__ pts){
  int idx = blockIdx.x*256 + threadIdx.x;
  if (idx >= NRAYS*128) return;
  int ray = idx >> 7, s = idx & 127;
  float z = z_buf[idx];
  float d = (s < 127) ? (z_buf[idx+1] - z) : 0.03125f;   // SAMPLE_DIST = 2/64
  float mid = z + 0.5f*d;
  pts[idx*3+0] = rays_o[ray*3+0] + rays_d[ray*3+0]*mid;
  pts[idx*3+1] = rays_o[ray*3+1] + rays_d[ray*3+1]*mid;
  pts[idx*3+2] = rays_o[ray*3+2] + rays_d[ray*3+2]*mid;
}

// ---------------------------------------------------------------- render (one thread per ray)
__global__ void k_render(const float* __restrict__ z_buf, const float* __restrict__ sdf_mid,
                         const float* __restrict__ rays_d, const float* __restrict__ grad,
                         const float* __restrict__ variance, float* __restrict__ depth_out){
  int ray = blockIdx.x*64 + threadIdx.x;
  if (ray >= NRAYS) return;
  float inv_s = expf(10.0f * variance[0]);
  inv_s = fminf(fmaxf(inv_s, 1e-6f), 1e6f);
  const float dx = rays_d[ray*3], dy = rays_d[ray*3+1], dz = rays_d[ray*3+2];
  float T = 1.0f, depth = 0.0f;
  float zc = z_buf[ray*128];
  for (int s = 0; s < 128; s++){
    int idx = ray*128 + s;
    float zn = (s < 127) ? z_buf[idx+1] : zc;
    float d  = (s < 127) ? (zn - zc) : 0.03125f;
    float sdf = sdf_mid[idx];
    float gx = grad[idx*3], gy = grad[idx*3+1], gz = grad[idx*3+2];
    float tc = dx*gx + dy*gy + dz*gz;
    float ic = -fmaxf(0.5f - 0.5f*tc, 0.0f);     // COS_ANNEAL_RATIO = 0
    float e = sg_f((sdf - ic*d*0.5f)*inv_s);
    float f = sg_f((sdf + ic*d*0.5f)*inv_s);
    float a = (e - f + 1e-5f) / (e + 1e-5f);
    a = fminf(fmaxf(a, 0.0f), 1.0f);
    depth += a*T*zc;
    T *= (1.0f - a + 1e-7f);
    zc = zn;
  }
  depth_out[ray] = depth;
}

// ---------------------------------------------------------------- launcher
extern "C" void kernel_launch(void* const* d_in, const int* in_sizes, int n_in,
                              void* d_out, int out_size, void* d_ws, size_t ws_size,
                              hipStream_t stream){
  (void)in_sizes; (void)n_in; (void)out_size; (void)ws_size;
  const float* rays_o = (const float*)d_in[0];
  const float* rays_d = (const float*)d_in[1];
  const float* nearv  = (const float*)d_in[2];
  const float* farv   = (const float*)d_in[3];
  const float* W1 = (const float*)d_in[4];
  const float* b1 = (const float*)d_in[5];
  const float* W2 = (const float*)d_in[6];
  const float* b2 = (const float*)d_in[7];
  const float* W3 = (const float*)d_in[8];
  const float* b3 = (const float*)d_in[9];
  const float* variance = (const float*)d_in[10];

  // Workspace layout: within round-0's proven footprint (6,619,136 B).
  float* ws      = (float*)d_ws;
  float* z_buf   = ws;                    // [0,       524288)
  float* sdf_buf = ws + 524288;           // [524288,  1048576)
  float* sdf_tmp = ws + 1048576;          // [1048576, 1572864)
  float* W2T     = ws + 1572864;          // [1572864, 1589248)
  int*   slots   = (int*)(ws + 1589248);  // [1589248, 1654784) as ints
  // 2-way fwd fragments alias sdf_buf — created AFTER the upsample loop,
  // when sdf_buf is dead (round-4 validated placement).
  unsigned short* w2fh = (unsigned short*)(ws + 524288);  // [524288, 532480)
  unsigned short* w2fl = w2fh + 16384;                    // [532480, 540672)
  // 3-way fwd fragments live in the upper (unused) half of sdf_tmp:
  // sdf_tmp is only written [0, 262144) before the final pass. The final
  // k_mlp_bwd overwrites this region, by which point the tables are dead.
  unsigned short* w2h3 = (unsigned short*)(ws + 1310720); // [1310720, 1318912)
  unsigned short* w2m3 = w2h3 + 16384;                    // [1318912, 1327104)
  unsigned short* w2l3 = w2h3 + 32768;                    // [1327104, 1335296)

  float* out       = (float*)d_out;
  float* depth_out = out;
  float* grad_out  = out + NRAYS;         // 524288*3 floats
  float* pts       = grad_out;            // pts staging aliases grad region

  k_transpose<<<dim3(64), dim3(256), 0, stream>>>(W2, W2T);
  k_make_frags3<<<dim3(8), dim3(256), 0, stream>>>(W2, w2h3, w2m3, w2l3);
  k_init<<<dim3(1024), dim3(256), 0, stream>>>(rays_o, rays_d, nearv, farv, z_buf, pts);
  k_mlp_fwd_t<<<dim3(4096), dim3(256), 0, stream>>>(pts, W1,b1,b2,W3,b3,
                                                    w2h3,w2m3,w2l3, sdf_tmp);
  k_scatter_init<<<dim3(1024), dim3(256), 0, stream>>>(sdf_tmp, sdf_buf);

  for (int i = 0; i < 4; i++){
    int S = 64 + 16*i;
    float inv_s = (float)(64 << i);
    int last = (i == 3) ? 1 : 0;
    k_upsample<<<dim3(4096), dim3(64), 0, stream>>>(rays_o, rays_d, z_buf, sdf_buf,
                                                    pts, slots, S, inv_s, last);
    if (!last){
      k_mlp_fwd_t<<<dim3(1024), dim3(256), 0, stream>>>(pts, W1,b1,b2,W3,b3,
                                                        w2h3,w2m3,w2l3, sdf_tmp);
      k_scatter_new<<<dim3(256), dim3(256), 0, stream>>>(sdf_tmp, slots, sdf_buf);
    }
  }

  // sdf_buf is dead from here on — safe to overwrite with fragments.
  k_make_frags<<<dim3(8), dim3(256), 0, stream>>>(W2, w2fh, w2fl);
  k_prep<<<dim3(2048), dim3(256), 0, stream>>>(rays_o, rays_d, z_buf, pts);
  k_mlp_bwd<<<dim3(8192), dim3(256), 0, stream>>>(pts, W1,b1,b2,W3,b3,
                                                  w2fh,w2fl, W2T, sdf_tmp, grad_out);
  k_render<<<dim3(64), dim3(64), 0, stream>>>(z_buf, sdf_tmp, rays_d, grad_out,
                                              variance, depth_out);
}

// Round 7
// 863.032 us; speedup vs baseline: 1.7888x; 1.1960x over previous
//
#include <hip/hip_runtime.h>
#include <math.h>

#define HID 128
#define NRAYS 4096
#define TP 64   // points per MLP tile (one per lane)

typedef __bf16 bf16x8 __attribute__((ext_vector_type(8)));
typedef float f32x4 __attribute__((ext_vector_type(4)));
typedef unsigned int uint32x4 __attribute__((ext_vector_type(4)));

union frag_u { bf16x8 v; uint32x4 q; };

__device__ __forceinline__ unsigned f2bf(float f){   // fp32 -> bf16 bits, RNE
  unsigned u = __float_as_uint(f);
  u += 0x7FFFu + ((u >> 16) & 1u);
  return u >> 16;
}
__device__ __forceinline__ float bf2f(unsigned h){
  return __uint_as_float(h << 16);
}
__device__ __forceinline__ float sp_f(float x){      // softplus, libm-precision
  return fmaxf(x, 0.0f) + log1pf(expf(-fabsf(x)));
}
__device__ __forceinline__ float sp_fast(float x){   // softplus, fast (final kernel)
  float e = __expf(-fabsf(x));
  return fmaxf(x, 0.0f) + __logf(1.0f + e);
}
__device__ __forceinline__ float sg_fast(float x){   // sigmoid, fast (final kernel)
  float e = __expf(-fabsf(x));
  float r = __builtin_amdgcn_rcpf(1.0f + e);
  return (x >= 0.0f ? 1.0f : e) * r;
}
__device__ __forceinline__ float sg_f(float x){      // sigmoid, libm-precision
  return 1.0f / (1.0f + expf(-x));
}
__device__ __forceinline__ f32x4 splat4(float x){
  f32x4 v = {x, x, x, x};
  return v;
}

// Swizzled LDS index (ushort units) for a [64][128] bf16 plane.
// byte ^= ((row&7)<<4)  ->  ushort idx ^= ((row&7)<<3). Keeps 16B alignment.
#define SW(p,k) ((((p)*HID) + (k)) ^ (((p)&7)<<3))

// ---------------------------------------------------------------- W2 fragment prep (2-way x 2 layouts)
// frag f = kc*8 + tg; element: contraction a = 32*kc + 8*(lane>>4)+e,
// output b = 16*tg + (lane&15). Stored at [(f*64+lane)*8 + e].
// which=0: v = W2[a*HID+b] -> B-operand for fwd (B[k][n], col=n).
// which=1: v = W2[b*HID+a] -> A-operand for swapped bwd (A[k][n]=W2[k][n], row=k).
__global__ void k_make_frags(const float* __restrict__ W2,
    unsigned short* __restrict__ w2fh,  unsigned short* __restrict__ w2fl,
    unsigned short* __restrict__ w2tfh, unsigned short* __restrict__ w2tfl){
  int idx = blockIdx.x*256 + threadIdx.x;
  if (idx >= 4096) return;
  int which = idx >> 11;
  int f    = (idx >> 6) & 31;
  int lane = idx & 63;
  int kc = f >> 3, tg = f & 7;
  int lg = lane >> 4, lr = lane & 15;
  unsigned short* dh = which ? w2tfh : w2fh;
  unsigned short* dl = which ? w2tfl : w2fl;
  int base = (f*64 + lane)*8;
  #pragma unroll
  for (int e = 0; e < 8; e++){
    int a = 32*kc + 8*lg + e;      // contraction index
    int b = 16*tg + lr;            // output index (fwd: n / bwd: k row)
    float v = which ? W2[b*HID + a] : W2[a*HID + b];
    unsigned hi = f2bf(v);
    dh[base+e] = (unsigned short)hi;
    dl[base+e] = (unsigned short)f2bf(v - bf2f(hi));
  }
}

// ---------------------------------------------------------------- W2 fwd-fragment prep (3-way, precision fwd)
// Triple-bf16 split: v = hi + mid + lo to ~2^-27 relative. Same fragment order.
__global__ void k_make_frags3(const float* __restrict__ W2,
    unsigned short* __restrict__ dh, unsigned short* __restrict__ dm,
    unsigned short* __restrict__ dl){
  int idx = blockIdx.x*256 + threadIdx.x;
  if (idx >= 2048) return;
  int f    = idx >> 6;             // 0..31
  int lane = idx & 63;
  int kc = f >> 3, tg = f & 7;
  int lg = lane >> 4, lr = lane & 15;
  int base = (f*64 + lane)*8;
  #pragma unroll
  for (int e = 0; e < 8; e++){
    int a = 32*kc + 8*lg + e;      // contraction index k
    int b = 16*tg + lr;            // output index n
    float v = W2[a*HID + b];
    unsigned hi = f2bf(v);
    float rm = v - bf2f(hi);
    unsigned md = f2bf(rm);
    dh[base+e] = (unsigned short)hi;
    dm[base+e] = (unsigned short)md;
    dl[base+e] = (unsigned short)f2bf(rm - bf2f(md));
  }
}

// ---------------------------------------------------------------- initial z + pts
__global__ void k_init(const float* __restrict__ rays_o, const float* __restrict__ rays_d,
                       const float* __restrict__ nearv, const float* __restrict__ farv,
                       float* __restrict__ z_buf, float* __restrict__ pts){
  int idx = blockIdx.x*256 + threadIdx.x;
  if (idx >= NRAYS*64) return;
  int ray = idx >> 6, j = idx & 63;
  float nr = nearv[ray];
  float z = nr + (farv[ray] - nr) * ((float)j / 63.0f);
  z_buf[ray*128 + j] = z;
  pts[idx*3+0] = rays_o[ray*3+0] + rays_d[ray*3+0]*z;
  pts[idx*3+1] = rays_o[ray*3+1] + rays_d[ray*3+1]*z;
  pts[idx*3+2] = rays_o[ray*3+2] + rays_d[ray*3+2]*z;
}

// ---------------------------------------------------------------- MLP forward, MFMA 6-term
// PASS-VALIDATED in round 6. Feeds the upsample cdf; triple-bf16 split keeps
// pre2 error ~1e-6 (3-term's ~1e-4 would blow the threshold via cdf bin flips).
__global__ __launch_bounds__(256, 3) void k_mlp_fwd_t(
    const float* __restrict__ pts,
    const float* __restrict__ W1, const float* __restrict__ b1,
    const float* __restrict__ b2,
    const float* __restrict__ W3, const float* __restrict__ b3,
    const unsigned short* __restrict__ w2h, const unsigned short* __restrict__ w2m,
    const unsigned short* __restrict__ w2l,
    float* __restrict__ sdf_out)
{
  __shared__ unsigned short sHi[64*HID];   // 16 KB each
  __shared__ unsigned short sMi[64*HID];
  __shared__ unsigned short sLo[64*HID];
  __shared__ float sRed[4][64];

  const int tid = threadIdx.x;
  const int l   = tid & 63;
  const int wv  = __builtin_amdgcn_readfirstlane(tid >> 6);
  const int lg  = l >> 4;
  const int lr  = l & 15;
  const int q0  = blockIdx.x * 64;
  const int kb  = 32*wv;

  const float x0 = pts[(q0+l)*3+0];
  const float x1 = pts[(q0+l)*3+1];
  const float x2 = pts[(q0+l)*3+2];

  // ---- layer 1: point l, k in wave's 32-slice; libm softplus, 3-way split
  #pragma unroll
  for (int g = 0; g < 4; g++){
    unsigned hw[4], mw[4], lw[4];
    #pragma unroll
    for (int e2 = 0; e2 < 4; e2++){
      unsigned hpk[2], mpk[2], lpk[2];
      #pragma unroll
      for (int t = 0; t < 2; t++){
        int k = kb + 8*g + 2*e2 + t;
        float pre = b1[k];
        pre = fmaf(x0, W1[k],       pre);
        pre = fmaf(x1, W1[HID+k],   pre);
        pre = fmaf(x2, W1[2*HID+k], pre);
        float h = sp_f(pre);
        unsigned hi = f2bf(h);
        float rm = h - bf2f(hi);
        unsigned md = f2bf(rm);
        hpk[t] = hi; mpk[t] = md;
        lpk[t] = f2bf(rm - bf2f(md));
      }
      hw[e2] = hpk[0] | (hpk[1] << 16);
      mw[e2] = mpk[0] | (mpk[1] << 16);
      lw[e2] = lpk[0] | (lpk[1] << 16);
    }
    uint32x4 hq = {hw[0], hw[1], hw[2], hw[3]};
    uint32x4 mq = {mw[0], mw[1], mw[2], mw[3]};
    uint32x4 lq = {lw[0], lw[1], lw[2], lw[3]};
    *(uint32x4*)&sHi[SW(l, kb + 8*g)] = hq;
    *(uint32x4*)&sMi[SW(l, kb + 8*g)] = mq;
    *(uint32x4*)&sLo[SW(l, kb + 8*g)] = lq;
  }
  __syncthreads();

  // ---- layer 2: pre2[p][n] via 6-term MFMA, split accumulators
  f32x4 acc[4][2], accC[4][2];
  {
    const float b2a = b2[kb + lr];
    const float b2b = b2[kb + 16 + lr];
    #pragma unroll
    for (int mt = 0; mt < 4; mt++){
      acc[mt][0]  = splat4(b2a);
      acc[mt][1]  = splat4(b2b);
      accC[mt][0] = splat4(0.0f);
      accC[mt][1] = splat4(0.0f);
    }
  }
  #pragma unroll
  for (int kc = 0; kc < 4; kc++){
    frag_u bh0, bm0, bl0, bh1, bm1, bl1;
    const int f0 = ((kc*8 + 2*wv + 0)*64 + l)*8;
    const int f1 = ((kc*8 + 2*wv + 1)*64 + l)*8;
    bh0.q = *(const uint32x4*)(w2h + f0);
    bm0.q = *(const uint32x4*)(w2m + f0);
    bl0.q = *(const uint32x4*)(w2l + f0);
    bh1.q = *(const uint32x4*)(w2h + f1);
    bm1.q = *(const uint32x4*)(w2m + f1);
    bl1.q = *(const uint32x4*)(w2l + f1);
    const int kk = 32*kc + 8*lg;
    #pragma unroll
    for (int mt = 0; mt < 4; mt++){
      frag_u ah, am, al;
      ah.q = *(const uint32x4*)&sHi[SW(16*mt + lr, kk)];
      am.q = *(const uint32x4*)&sMi[SW(16*mt + lr, kk)];
      al.q = *(const uint32x4*)&sLo[SW(16*mt + lr, kk)];
      accC[mt][0] = __builtin_amdgcn_mfma_f32_16x16x32_bf16(ah.v, bl0.v, accC[mt][0], 0,0,0);
      accC[mt][0] = __builtin_amdgcn_mfma_f32_16x16x32_bf16(am.v, bm0.v, accC[mt][0], 0,0,0);
      accC[mt][0] = __builtin_amdgcn_mfma_f32_16x16x32_bf16(al.v, bh0.v, accC[mt][0], 0,0,0);
      accC[mt][0] = __builtin_amdgcn_mfma_f32_16x16x32_bf16(ah.v, bm0.v, accC[mt][0], 0,0,0);
      accC[mt][0] = __builtin_amdgcn_mfma_f32_16x16x32_bf16(am.v, bh0.v, accC[mt][0], 0,0,0);
      acc[mt][0]  = __builtin_amdgcn_mfma_f32_16x16x32_bf16(ah.v, bh0.v, acc[mt][0],  0,0,0);
      accC[mt][1] = __builtin_amdgcn_mfma_f32_16x16x32_bf16(ah.v, bl1.v, accC[mt][1], 0,0,0);
      accC[mt][1] = __builtin_amdgcn_mfma_f32_16x16x32_bf16(am.v, bm1.v, accC[mt][1], 0,0,0);
      accC[mt][1] = __builtin_amdgcn_mfma_f32_16x16x32_bf16(al.v, bh1.v, accC[mt][1], 0,0,0);
      accC[mt][1] = __builtin_amdgcn_mfma_f32_16x16x32_bf16(ah.v, bm1.v, accC[mt][1], 0,0,0);
      accC[mt][1] = __builtin_amdgcn_mfma_f32_16x16x32_bf16(am.v, bh1.v, accC[mt][1], 0,0,0);
      acc[mt][1]  = __builtin_amdgcn_mfma_f32_16x16x32_bf16(ah.v, bh1.v, acc[mt][1],  0,0,0);
    }
  }

  // ---- epilogue: sdf = b3 + sum sp(pre2)*W3 (validated reduce structure)
  {
    const float w3a = W3[kb + lr];
    const float w3b = W3[kb + 16 + lr];
    #pragma unroll
    for (int mt = 0; mt < 4; mt++){
      float svr[4];
      #pragma unroll
      for (int r = 0; r < 4; r++){
        float pa = acc[mt][0][r] + accC[mt][0][r];
        float pb = acc[mt][1][r] + accC[mt][1][r];
        svr[r] = sp_f(pa)*w3a + sp_f(pb)*w3b;
      }
      #pragma unroll
      for (int m = 1; m < 16; m <<= 1){
        svr[0] += __shfl_xor(svr[0], m);
        svr[1] += __shfl_xor(svr[1], m);
        svr[2] += __shfl_xor(svr[2], m);
        svr[3] += __shfl_xor(svr[3], m);
      }
      if (lr == 0){
        sRed[wv][16*mt + 4*lg + 0] = svr[0];
        sRed[wv][16*mt + 4*lg + 1] = svr[1];
        sRed[wv][16*mt + 4*lg + 2] = svr[2];
        sRed[wv][16*mt + 4*lg + 3] = svr[3];
      }
    }
  }
  __syncthreads();
  if (tid < 64)
    sdf_out[q0+tid] = b3[0] + sRed[0][tid] + sRed[1][tid] + sRed[2][tid] + sRed[3][tid];
}

// ---------------------------------------------------------------- MLP fwd+bwd, both MFMA
// Fwd half pass-validated (rounds 4/6). Bwd is a NEW swapped-operand GEMM:
//   D[k][p] = sum_n W2[k][n] * g2[p][n]
// A = w2tf table (element (row=b,a)=W2[b][a] == A[k][n]); B = g2 planes read
// with the SAME LDS expression the validated fwd uses for its A-reads. All
// lane<->element maps in this formulation are individually pass-validated:
//   A row = lane&15 (+16*tile), B col = lane&15 (+16*tile),
//   contraction = 8*(lane>>4)+e (+32*chunk), D row = 4*(lane>>4)+reg, col = lane&15.
// D readout here: k = kb + 16*t + 4*lg + r (row), p = 16*pt + lr (col);
// per-point reduce over lg via shfl_xor(16|32).
__global__ __launch_bounds__(256, 4) void k_mlp_bwd(
    const float* __restrict__ pts,
    const float* __restrict__ W1, const float* __restrict__ b1,
    const float* __restrict__ b2,
    const float* __restrict__ W3, const float* __restrict__ b3,
    const unsigned short* __restrict__ w2fh,  const unsigned short* __restrict__ w2fl,
    const unsigned short* __restrict__ w2tfh, const unsigned short* __restrict__ w2tfl,
    float* __restrict__ sdf_out, float* __restrict__ grad_out)
{
  __shared__ unsigned short sHi[64*HID];   // 16 KB: h1 hi, then g2 hi
  __shared__ unsigned short sLo[64*HID];   // 16 KB: h1 lo, then g2 lo
  __shared__ float sRed[4][64];            // sdf partials per wave
  __shared__ float sPts[64][4];            // x per point (for bwd recompute)
  __shared__ float sGrad[4][64][3];        // grad partials per wave

  const int tid = threadIdx.x;
  const int l   = tid & 63;
  const int wv  = __builtin_amdgcn_readfirstlane(tid >> 6);
  const int lg  = l >> 4;
  const int lr  = l & 15;
  const int q0  = blockIdx.x * 64;
  const int kb  = 32*wv;

  const float x0 = pts[(q0+l)*3+0];
  const float x1 = pts[(q0+l)*3+1];
  const float x2 = pts[(q0+l)*3+2];
  if (wv == 0){ sPts[l][0] = x0; sPts[l][1] = x1; sPts[l][2] = x2; }

  // ---- layer 1: point l, k in [32wv, 32wv+32); bf16 hi/lo staged for MFMA
  #pragma unroll
  for (int g = 0; g < 4; g++){
    unsigned hw[4], lw[4];
    #pragma unroll
    for (int e2 = 0; e2 < 4; e2++){
      unsigned hpk[2], lpk[2];
      #pragma unroll
      for (int t = 0; t < 2; t++){
        int k = kb + 8*g + 2*e2 + t;
        float pre = b1[k];
        pre = fmaf(x0, W1[k],       pre);
        pre = fmaf(x1, W1[HID+k],   pre);
        pre = fmaf(x2, W1[2*HID+k], pre);
        float h = sp_fast(pre);
        unsigned hi = f2bf(h);
        hpk[t] = hi;
        lpk[t] = f2bf(h - bf2f(hi));
      }
      hw[e2] = hpk[0] | (hpk[1] << 16);
      lw[e2] = lpk[0] | (lpk[1] << 16);
    }
    uint32x4 hq = {hw[0], hw[1], hw[2], hw[3]};
    uint32x4 lq = {lw[0], lw[1], lw[2], lw[3]};
    *(uint32x4*)&sHi[SW(l, kb + 8*g)] = hq;
    *(uint32x4*)&sLo[SW(l, kb + 8*g)] = lq;
  }
  __syncthreads();

  // ---- layer 2 forward (MFMA, validated): pre2[p][n], n in wave's 32-slice
  f32x4 acc[4][2];
  {
    const float b2a = b2[kb + lr];
    const float b2b = b2[kb + 16 + lr];
    #pragma unroll
    for (int mt = 0; mt < 4; mt++){
      acc[mt][0] = splat4(b2a);
      acc[mt][1] = splat4(b2b);
    }
  }
  #pragma unroll
  for (int kc = 0; kc < 4; kc++){
    frag_u bh0, bl0, bh1, bl1;
    const int f0 = ((kc*8 + 2*wv + 0)*64 + l)*8;
    const int f1 = ((kc*8 + 2*wv + 1)*64 + l)*8;
    bh0.q = *(const uint32x4*)(w2fh + f0);
    bl0.q = *(const uint32x4*)(w2fl + f0);
    bh1.q = *(const uint32x4*)(w2fh + f1);
    bl1.q = *(const uint32x4*)(w2fl + f1);
    const int kk = 32*kc + 8*lg;
    #pragma unroll
    for (int mt = 0; mt < 4; mt++){
      frag_u ah, al;
      ah.q = *(const uint32x4*)&sHi[SW(16*mt + lr, kk)];
      al.q = *(const uint32x4*)&sLo[SW(16*mt + lr, kk)];
      acc[mt][0] = __builtin_amdgcn_mfma_f32_16x16x32_bf16(ah.v, bh0.v, acc[mt][0], 0,0,0);
      acc[mt][0] = __builtin_amdgcn_mfma_f32_16x16x32_bf16(ah.v, bl0.v, acc[mt][0], 0,0,0);
      acc[mt][0] = __builtin_amdgcn_mfma_f32_16x16x32_bf16(al.v, bh0.v, acc[mt][0], 0,0,0);
      acc[mt][1] = __builtin_amdgcn_mfma_f32_16x16x32_bf16(ah.v, bh1.v, acc[mt][1], 0,0,0);
      acc[mt][1] = __builtin_amdgcn_mfma_f32_16x16x32_bf16(ah.v, bl1.v, acc[mt][1], 0,0,0);
      acc[mt][1] = __builtin_amdgcn_mfma_f32_16x16x32_bf16(al.v, bh1.v, acc[mt][1], 0,0,0);
    }
  }
  __syncthreads();   // all waves done reading h planes; g2 may now overwrite

  // ---- fwd epilogue: sdf partials + g2 = sg(pre2)*W3 as bf16 hi/lo planes
  {
    const float w3a = W3[kb + lr];
    const float w3b = W3[kb + 16 + lr];
    #pragma unroll
    for (int mt = 0; mt < 4; mt++){
      float svr[4];
      #pragma unroll
      for (int r = 0; r < 4; r++){
        float pa = acc[mt][0][r], pb = acc[mt][1][r];
        svr[r] = sp_fast(pa)*w3a + sp_fast(pb)*w3b;
        int pr = 16*mt + 4*lg + r;                    // point (D-row, validated)
        float ga = sg_fast(pa) * w3a;
        float gb = sg_fast(pb) * w3b;
        unsigned ha = f2bf(ga);
        sHi[SW(pr, kb + lr)]      = (unsigned short)ha;
        sLo[SW(pr, kb + lr)]      = (unsigned short)f2bf(ga - bf2f(ha));
        unsigned hb = f2bf(gb);
        sHi[SW(pr, kb + 16 + lr)] = (unsigned short)hb;
        sLo[SW(pr, kb + 16 + lr)] = (unsigned short)f2bf(gb - bf2f(hb));
      }
      #pragma unroll
      for (int m = 1; m < 16; m <<= 1){
        svr[0] += __shfl_xor(svr[0], m);
        svr[1] += __shfl_xor(svr[1], m);
        svr[2] += __shfl_xor(svr[2], m);
        svr[3] += __shfl_xor(svr[3], m);
      }
      if (lr == 0){
        sRed[wv][16*mt + 4*lg + 0] = svr[0];
        sRed[wv][16*mt + 4*lg + 1] = svr[1];
        sRed[wv][16*mt + 4*lg + 2] = svr[2];
        sRed[wv][16*mt + 4*lg + 3] = svr[3];
      }
    }
  }
  __syncthreads();   // g2 planes complete before bwd reads them
  if (tid < 64)
    sdf_out[q0+tid] = b3[0] + sRed[0][tid] + sRed[1][tid] + sRed[2][tid] + sRed[3][tid];

  // ---- backward (MFMA, swapped): D[k][p] = sum_n W2[k][n] * g2[p][n]
  // A = w2tf fragments (row k), B = g2 planes (col p), 3-term emulation.
  f32x4 acc2[4][2];   // [pt][t]: k = kb + 16*t + 4*lg + r, p = 16*pt + lr
  #pragma unroll
  for (int pt = 0; pt < 4; pt++){
    acc2[pt][0] = splat4(0.0f);
    acc2[pt][1] = splat4(0.0f);
  }
  #pragma unroll
  for (int kcn = 0; kcn < 4; kcn++){
    frag_u ah0, al0, ah1, al1;
    const int f0 = ((kcn*8 + 2*wv + 0)*64 + l)*8;
    const int f1 = ((kcn*8 + 2*wv + 1)*64 + l)*8;
    ah0.q = *(const uint32x4*)(w2tfh + f0);
    al0.q = *(const uint32x4*)(w2tfl + f0);
    ah1.q = *(const uint32x4*)(w2tfh + f1);
    al1.q = *(const uint32x4*)(w2tfl + f1);
    const int nn = 32*kcn + 8*lg;
    #pragma unroll
    for (int pt = 0; pt < 4; pt++){
      frag_u bh, bl;
      bh.q = *(const uint32x4*)&sHi[SW(16*pt + lr, nn)];
      bl.q = *(const uint32x4*)&sLo[SW(16*pt + lr, nn)];
      acc2[pt][0] = __builtin_amdgcn_mfma_f32_16x16x32_bf16(ah0.v, bh.v, acc2[pt][0], 0,0,0);
      acc2[pt][0] = __builtin_amdgcn_mfma_f32_16x16x32_bf16(ah0.v, bl.v, acc2[pt][0], 0,0,0);
      acc2[pt][0] = __builtin_amdgcn_mfma_f32_16x16x32_bf16(al0.v, bh.v, acc2[pt][0], 0,0,0);
      acc2[pt][1] = __builtin_amdgcn_mfma_f32_16x16x32_bf16(ah1.v, bh.v, acc2[pt][1], 0,0,0);
      acc2[pt][1] = __builtin_amdgcn_mfma_f32_16x16x32_bf16(ah1.v, bl.v, acc2[pt][1], 0,0,0);
      acc2[pt][1] = __builtin_amdgcn_mfma_f32_16x16x32_bf16(al1.v, bh.v, acc2[pt][1], 0,0,0);
    }
  }

  // ---- bwd epilogue: dp1 = dh1*sg(pre1); grad = W1 @ dp1, reduce over lg
  {
    // hoist the wave's W1/b1 values: k = kb + 16*t + 4*lg + r (lane-dependent via lg)
    float w1a[2][4], w1b[2][4], w1c[2][4], b1v[2][4];
    #pragma unroll
    for (int t = 0; t < 2; t++)
      #pragma unroll
      for (int r = 0; r < 4; r++){
        int k = kb + 16*t + 4*lg + r;
        w1a[t][r] = W1[k]; w1b[t][r] = W1[HID+k]; w1c[t][r] = W1[2*HID+k];
        b1v[t][r] = b1[k];
      }
    #pragma unroll
    for (int pt = 0; pt < 4; pt++){
      const int p = 16*pt + lr;
      const float xx = sPts[p][0], xy = sPts[p][1], xz = sPts[p][2];
      float gx = 0.f, gy = 0.f, gz = 0.f;
      #pragma unroll
      for (int t = 0; t < 2; t++){
        #pragma unroll
        for (int r = 0; r < 4; r++){
          float pre1 = fmaf(xx, w1a[t][r], fmaf(xy, w1b[t][r], fmaf(xz, w1c[t][r], b1v[t][r])));
          float dp = acc2[pt][t][r] * sg_fast(pre1);
          gx = fmaf(w1a[t][r], dp, gx);
          gy = fmaf(w1b[t][r], dp, gy);
          gz = fmaf(w1c[t][r], dp, gz);
        }
      }
      gx += __shfl_xor(gx, 16); gx += __shfl_xor(gx, 32);
      gy += __shfl_xor(gy, 16); gy += __shfl_xor(gy, 32);
      gz += __shfl_xor(gz, 16); gz += __shfl_xor(gz, 32);
      if (lg == 0){
        sGrad[wv][p][0] = gx; sGrad[wv][p][1] = gy; sGrad[wv][p][2] = gz;
      }
    }
  }
  __syncthreads();
  if (tid < 64){
    #pragma unroll
    for (int c = 0; c < 3; c++)
      grad_out[(q0+tid)*3+c] =
        sGrad[0][tid][c] + sGrad[1][tid][c] + sGrad[2][tid][c] + sGrad[3][tid][c];
  }
}

// ---------------------------------------------------------------- scatters
__global__ void k_scatter_init(const float* __restrict__ sdf_tmp, float* __restrict__ sdf_buf){
  int idx = blockIdx.x*256 + threadIdx.x;
  if (idx >= NRAYS*64) return;
  sdf_buf[(idx >> 6)*128 + (idx & 63)] = sdf_tmp[idx];
}
__global__ void k_scatter_new(const float* __restrict__ sdf_tmp, const int* __restrict__ slots,
                              float* __restrict__ sdf_buf){
  int idx = blockIdx.x*256 + threadIdx.x;
  if (idx >= NRAYS*16) return;
  sdf_buf[(idx >> 4)*128 + slots[idx]] = sdf_tmp[idx];
}

// ---------------------------------------------------------------- upsample (one wave per ray)
__global__ __launch_bounds__(64) void k_upsample(
      const float* __restrict__ rays_o, const float* __restrict__ rays_d,
      float* __restrict__ z_buf, float* __restrict__ sdf_buf,
      float* __restrict__ pts_new, int* __restrict__ slots,
      int S, float inv_s, int last){
  __shared__ float z[128], sd[128], rad[128], cosv[128], alf[128], wv[128], cdf[129], nz[16];
  __shared__ int slt[16];
  const int ray = blockIdx.x;
  const int l   = threadIdx.x;
  const float ox = rays_o[ray*3], oy = rays_o[ray*3+1], oz = rays_o[ray*3+2];
  const float dx = rays_d[ray*3], dy = rays_d[ray*3+1], dz = rays_d[ray*3+2];
  for (int j = l; j < S; j += 64){
    float zz = z_buf[ray*128+j];
    z[j]  = zz;
    sd[j] = sdf_buf[ray*128+j];
    float px = ox+dx*zz, py = oy+dy*zz, pz = oz+dz*zz;
    rad[j] = sqrtf(px*px + py*py + pz*pz);
  }
  __syncthreads();
  for (int j = l; j < S-1; j += 64)
    cosv[j] = (sd[j+1]-sd[j]) / (z[j+1]-z[j] + 1e-5f);
  __syncthreads();
  for (int j = l; j < S-1; j += 64){
    float cv = fminf((j > 0) ? cosv[j-1] : 0.0f, cosv[j]);
    cv = fminf(fmaxf(cv, -1000.0f), 0.0f);
    float inside = (rad[j] < 1.0f || rad[j+1] < 1.0f) ? 1.0f : 0.0f;
    cv *= inside;
    float mid  = 0.5f*(sd[j]+sd[j+1]);
    float dist = z[j+1]-z[j];
    float e = sg_f((mid - cv*dist*0.5f)*inv_s);
    float f = sg_f((mid + cv*dist*0.5f)*inv_s);
    alf[j] = (e - f + 1e-5f) / (e + 1e-5f);
  }
  __syncthreads();
  if (l == 0){
    float T = 1.0f, wsum = 0.0f;
    for (int j = 0; j < S-1; j++){
      float w = alf[j]*T + 1e-5f;   // weights = alpha*trans + 1e-5
      wv[j] = w; wsum += w;
      T *= (1.0f - alf[j] + 1e-7f);
    }
    cdf[0] = 0.0f;
    float c = 0.0f;
    for (int j = 0; j < S-1; j++){ c += wv[j]/wsum; cdf[j+1] = c; }
  }
  __syncthreads();
  if (l < 16){
    float u = 0.03125f + 0.0625f*(float)l;   // linspace(1/32, 31/32, 16)
    int idx = 0;
    while (idx < S && cdf[idx] <= u) idx++;  // searchsorted side='right'
    int below = idx - 1; if (below < 0) below = 0;
    int above = (idx < S-1) ? idx : (S-1);
    float cb = cdf[below], ca = cdf[above];
    float den = ca - cb; if (den < 1e-5f) den = 1.0f;
    float t = (u - cb) / den;
    nz[l] = z[below] + t*(z[above] - z[below]);
  }
  __syncthreads();
  if (l == 0){
    // stable in-place merge from the back (old-before-new on ties)
    int i = S-1, j = 15;
    for (int dst = S+15; dst >= 0; --dst){
      bool takeOld = (j < 0) || (i >= 0 && z[i] > nz[j]);
      if (takeOld){ z[dst] = z[i]; sd[dst] = sd[i]; i--; }
      else        { z[dst] = nz[j]; slt[j] = dst; j--; }
    }
  }
  __syncthreads();
  for (int j = l; j < S+16; j += 64){
    z_buf[ray*128+j]  = z[j];
    sdf_buf[ray*128+j] = sd[j];
  }
  if (!last && l < 16){
    slots[ray*16+l] = slt[l];
    float zz = nz[l];
    pts_new[(ray*16+l)*3+0] = ox + dx*zz;
    pts_new[(ray*16+l)*3+1] = oy + dy*zz;
    pts_new[(ray*16+l)*3+2] = oz + dz*zz;
  }
}

// ---------------------------------------------------------------- final mid-point pts
__global__ void k_prep(const float* __restrict__ rays_o, const float* __restrict__ rays_d,
                       const float* __restrict__ z_buf, float* __restrict__ pts){
  int idx = blockIdx.x*256 + threadIdx.x;
  if (idx >= NRAYS*128) return;
  int ray = idx >> 7, s = idx & 127;
  float z = z_buf[idx];
  float d = (s < 127) ? (z_buf[idx+1] - z) : 0.03125f;   // SAMPLE_DIST = 2/64
  float mid = z + 0.5f*d;
  pts[idx*3+0] = rays_o[ray*3+0] + rays_d[ray*3+0]*mid;
  pts[idx*3+1] = rays_o[ray*3+1] + rays_d[ray*3+1]*mid;
  pts[idx*3+2] = rays_o[ray*3+2] + rays_d[ray*3+2]*mid;
}

// ---------------------------------------------------------------- render (one thread per ray)
__global__ void k_render(const float* __restrict__ z_buf, const float* __restrict__ sdf_mid,
                         const float* __restrict__ rays_d, const float* __restrict__ grad,
                         const float* __restrict__ variance, float* __restrict__ depth_out){
  int ray = blockIdx.x*64 + threadIdx.x;
  if (ray >= NRAYS) return;
  float inv_s = expf(10.0f * variance[0]);
  inv_s = fminf(fmaxf(inv_s, 1e-6f), 1e6f);
  const float dx = rays_d[ray*3], dy = rays_d[ray*3+1], dz = rays_d[ray*3+2];
  float T = 1.0f, depth = 0.0f;
  float zc = z_buf[ray*128];
  for (int s = 0; s < 128; s++){
    int idx = ray*128 + s;
    float zn = (s < 127) ? z_buf[idx+1] : zc;
    float d  = (s < 127) ? (zn - zc) : 0.03125f;
    float sdf = sdf_mid[idx];
    float gx = grad[idx*3], gy = grad[idx*3+1], gz = grad[idx*3+2];
    float tc = dx*gx + dy*gy + dz*gz;
    float ic = -fmaxf(0.5f - 0.5f*tc, 0.0f);     // COS_ANNEAL_RATIO = 0
    float e = sg_f((sdf - ic*d*0.5f)*inv_s);
    float f = sg_f((sdf + ic*d*0.5f)*inv_s);
    float a = (e - f + 1e-5f) / (e + 1e-5f);
    a = fminf(fmaxf(a, 0.0f), 1.0f);
    depth += a*T*zc;
    T *= (1.0f - a + 1e-7f);
    zc = zn;
  }
  depth_out[ray] = depth;
}

// ---------------------------------------------------------------- launcher
extern "C" void kernel_launch(void* const* d_in, const int* in_sizes, int n_in,
                              void* d_out, int out_size, void* d_ws, size_t ws_size,
                              hipStream_t stream){
  (void)in_sizes; (void)n_in; (void)out_size; (void)ws_size;
  const float* rays_o = (const float*)d_in[0];
  const float* rays_d = (const float*)d_in[1];
  const float* nearv  = (const float*)d_in[2];
  const float* farv   = (const float*)d_in[3];
  const float* W1 = (const float*)d_in[4];
  const float* b1 = (const float*)d_in[5];
  const float* W2 = (const float*)d_in[6];
  const float* b2 = (const float*)d_in[7];
  const float* W3 = (const float*)d_in[8];
  const float* b3 = (const float*)d_in[9];
  const float* variance = (const float*)d_in[10];

  // Workspace layout: within round-0's proven footprint (6,619,136 B).
  float* ws      = (float*)d_ws;
  float* z_buf   = ws;                    // [0,       524288)
  float* sdf_buf = ws + 524288;           // [524288,  1048576)
  float* sdf_tmp = ws + 1048576;          // [1048576, 1572864)
  int*   slots   = (int*)(ws + 1589248);  // [1589248, 1654784) as ints
  // 2-way fwd + bwd(A-side) fragment tables alias sdf_buf — created AFTER the
  // upsample loop, when sdf_buf is dead (round-4/6 validated placement).
  unsigned short* w2fh  = (unsigned short*)(ws + 524288);  // [524288, 532480)
  unsigned short* w2fl  = w2fh + 16384;                    // [532480, 540672)
  unsigned short* w2tfh = w2fh + 32768;                    // [540672, 548864)
  unsigned short* w2tfl = w2fh + 49152;                    // [548864, 557056)
  // 3-way fwd fragments live in the upper (unused) half of sdf_tmp.
  unsigned short* w2h3 = (unsigned short*)(ws + 1310720); // [1310720, 1318912)
  unsigned short* w2m3 = w2h3 + 16384;                    // [1318912, 1327104)
  unsigned short* w2l3 = w2h3 + 32768;                    // [1327104, 1335296)

  float* out       = (float*)d_out;
  float* depth_out = out;
  float* grad_out  = out + NRAYS;         // 524288*3 floats
  float* pts       = grad_out;            // pts staging aliases grad region

  k_make_frags3<<<dim3(8), dim3(256), 0, stream>>>(W2, w2h3, w2m3, w2l3);
  k_init<<<dim3(1024), dim3(256), 0, stream>>>(rays_o, rays_d, nearv, farv, z_buf, pts);
  k_mlp_fwd_t<<<dim3(4096), dim3(256), 0, stream>>>(pts, W1,b1,b2,W3,b3,
                                                    w2h3,w2m3,w2l3, sdf_tmp);
  k_scatter_init<<<dim3(1024), dim3(256), 0, stream>>>(sdf_tmp, sdf_buf);

  for (int i = 0; i < 4; i++){
    int S = 64 + 16*i;
    float inv_s = (float)(64 << i);
    int last = (i == 3) ? 1 : 0;
    k_upsample<<<dim3(4096), dim3(64), 0, stream>>>(rays_o, rays_d, z_buf, sdf_buf,
                                                    pts, slots, S, inv_s, last);
    if (!last){
      k_mlp_fwd_t<<<dim3(1024), dim3(256), 0, stream>>>(pts, W1,b1,b2,W3,b3,
                                                        w2h3,w2m3,w2l3, sdf_tmp);
      k_scatter_new<<<dim3(256), dim3(256), 0, stream>>>(sdf_tmp, slots, sdf_buf);
    }
  }

  // sdf_buf is dead from here on — safe to overwrite with fragments.
  k_make_frags<<<dim3(16), dim3(256), 0, stream>>>(W2, w2fh, w2fl, w2tfh, w2tfl);
  k_prep<<<dim3(2048), dim3(256), 0, stream>>>(rays_o, rays_d, z_buf, pts);
  k_mlp_bwd<<<dim3(8192), dim3(256), 0, stream>>>(pts, W1,b1,b2,W3,b3,
                                                  w2fh,w2fl,w2tfh,w2tfl, sdf_tmp, grad_out);
  k_render<<<dim3(64), dim3(64), 0, stream>>>(z_buf, sdf_tmp, rays_d, grad_out,
                                              variance, depth_out);
}

// Round 8
// 590.968 us; speedup vs baseline: 2.6123x; 1.4604x over previous
//
#include <hip/hip_runtime.h>
#include <math.h>

#define HID 128
#define NRAYS 4096
#define TP 64   // points per MLP tile (one per lane)

typedef __bf16 bf16x8 __attribute__((ext_vector_type(8)));
typedef float f32x4 __attribute__((ext_vector_type(4)));
typedef unsigned int uint32x4 __attribute__((ext_vector_type(4)));

union frag_u { bf16x8 v; uint32x4 q; };

__device__ __forceinline__ unsigned f2bf(float f){   // fp32 -> bf16 bits, RNE
  unsigned u = __float_as_uint(f);
  u += 0x7FFFu + ((u >> 16) & 1u);
  return u >> 16;
}
__device__ __forceinline__ float bf2f(unsigned h){
  return __uint_as_float(h << 16);
}
__device__ __forceinline__ float sp_f(float x){      // softplus, libm-precision
  return fmaxf(x, 0.0f) + log1pf(expf(-fabsf(x)));
}
__device__ __forceinline__ float sp_fast(float x){   // softplus, v_exp/v_log (~4e-7 abs)
  float e = __expf(-fabsf(x));
  return fmaxf(x, 0.0f) + __logf(1.0f + e);
}
__device__ __forceinline__ float sg_fast(float x){   // sigmoid, fast
  float e = __expf(-fabsf(x));
  float r = __builtin_amdgcn_rcpf(1.0f + e);
  return (x >= 0.0f ? 1.0f : e) * r;
}
__device__ __forceinline__ float sg_f(float x){      // sigmoid, libm-precision
  return 1.0f / (1.0f + expf(-x));
}
__device__ __forceinline__ f32x4 splat4(float x){
  f32x4 v = {x, x, x, x};
  return v;
}

// Swizzled LDS index (ushort units) for a [64][128] bf16 plane.
// byte ^= ((row&7)<<4)  ->  ushort idx ^= ((row&7)<<3). Keeps 16B alignment.
#define SW(p,k) ((((p)*HID) + (k)) ^ (((p)&7)<<3))

// ---------------------------------------------------------------- W2 fragment prep (2-way x 2 layouts)
// frag f = kc*8 + tg; element: contraction a = 32*kc + 8*(lane>>4)+e,
// output b = 16*tg + (lane&15). Stored at [(f*64+lane)*8 + e].
// which=0: v = W2[a*HID+b] -> B-operand for fwd (B[k][n], col=n).
// which=1: v = W2[b*HID+a] -> A-operand for swapped bwd (A[k][n]=W2[k][n], row=k).
__global__ void k_make_frags(const float* __restrict__ W2,
    unsigned short* __restrict__ w2fh,  unsigned short* __restrict__ w2fl,
    unsigned short* __restrict__ w2tfh, unsigned short* __restrict__ w2tfl){
  int idx = blockIdx.x*256 + threadIdx.x;
  if (idx >= 4096) return;
  int which = idx >> 11;
  int f    = (idx >> 6) & 31;
  int lane = idx & 63;
  int kc = f >> 3, tg = f & 7;
  int lg = lane >> 4, lr = lane & 15;
  unsigned short* dh = which ? w2tfh : w2fh;
  unsigned short* dl = which ? w2tfl : w2fl;
  int base = (f*64 + lane)*8;
  #pragma unroll
  for (int e = 0; e < 8; e++){
    int a = 32*kc + 8*lg + e;      // contraction index
    int b = 16*tg + lr;            // output index (fwd: n / bwd: k row)
    float v = which ? W2[b*HID + a] : W2[a*HID + b];
    unsigned hi = f2bf(v);
    dh[base+e] = (unsigned short)hi;
    dl[base+e] = (unsigned short)f2bf(v - bf2f(hi));
  }
}

// ---------------------------------------------------------------- W2 fwd-fragment prep (3-way, precision fwd)
// Triple-bf16 split: v = hi + mid + lo to ~2^-27 relative. Same fragment order.
__global__ void k_make_frags3(const float* __restrict__ W2,
    unsigned short* __restrict__ dh, unsigned short* __restrict__ dm,
    unsigned short* __restrict__ dl){
  int idx = blockIdx.x*256 + threadIdx.x;
  if (idx >= 2048) return;
  int f    = idx >> 6;             // 0..31
  int lane = idx & 63;
  int kc = f >> 3, tg = f & 7;
  int lg = lane >> 4, lr = lane & 15;
  int base = (f*64 + lane)*8;
  #pragma unroll
  for (int e = 0; e < 8; e++){
    int a = 32*kc + 8*lg + e;      // contraction index k
    int b = 16*tg + lr;            // output index n
    float v = W2[a*HID + b];
    unsigned hi = f2bf(v);
    float rm = v - bf2f(hi);
    unsigned md = f2bf(rm);
    dh[base+e] = (unsigned short)hi;
    dm[base+e] = (unsigned short)md;
    dl[base+e] = (unsigned short)f2bf(rm - bf2f(md));
  }
}

// ---------------------------------------------------------------- initial z + pts
__global__ void k_init(const float* __restrict__ rays_o, const float* __restrict__ rays_d,
                       const float* __restrict__ nearv, const float* __restrict__ farv,
                       float* __restrict__ z_buf, float* __restrict__ pts){
  int idx = blockIdx.x*256 + threadIdx.x;
  if (idx >= NRAYS*64) return;
  int ray = idx >> 6, j = idx & 63;
  float nr = nearv[ray];
  float z = nr + (farv[ray] - nr) * ((float)j / 63.0f);
  z_buf[ray*128 + j] = z;
  pts[idx*3+0] = rays_o[ray*3+0] + rays_d[ray*3+0]*z;
  pts[idx*3+1] = rays_o[ray*3+1] + rays_d[ray*3+1]*z;
  pts[idx*3+2] = rays_o[ray*3+2] + rays_d[ray*3+2]*z;
}

// ---------------------------------------------------------------- MLP forward, MFMA 6-term
// PASS-VALIDATED structure (round 6/7). Feeds the upsample cdf; triple-bf16
// split keeps pre2 error ~1e-6. This round: libm sp_f -> sp_fast (v_exp/v_log,
// <=4e-7 abs) — sp_f was ~half the kernel's VALU instructions (64 calls/lane).
__global__ __launch_bounds__(256, 3) void k_mlp_fwd_t(
    const float* __restrict__ pts,
    const float* __restrict__ W1, const float* __restrict__ b1,
    const float* __restrict__ b2,
    const float* __restrict__ W3, const float* __restrict__ b3,
    const unsigned short* __restrict__ w2h, const unsigned short* __restrict__ w2m,
    const unsigned short* __restrict__ w2l,
    float* __restrict__ sdf_out)
{
  __shared__ unsigned short sHi[64*HID];   // 16 KB each
  __shared__ unsigned short sMi[64*HID];
  __shared__ unsigned short sLo[64*HID];
  __shared__ float sRed[4][64];

  const int tid = threadIdx.x;
  const int l   = tid & 63;
  const int wv  = __builtin_amdgcn_readfirstlane(tid >> 6);
  const int lg  = l >> 4;
  const int lr  = l & 15;
  const int q0  = blockIdx.x * 64;
  const int kb  = 32*wv;

  const float x0 = pts[(q0+l)*3+0];
  const float x1 = pts[(q0+l)*3+1];
  const float x2 = pts[(q0+l)*3+2];

  // ---- layer 1: point l, k in wave's 32-slice; fast softplus, 3-way split
  #pragma unroll
  for (int g = 0; g < 4; g++){
    unsigned hw[4], mw[4], lw[4];
    #pragma unroll
    for (int e2 = 0; e2 < 4; e2++){
      unsigned hpk[2], mpk[2], lpk[2];
      #pragma unroll
      for (int t = 0; t < 2; t++){
        int k = kb + 8*g + 2*e2 + t;
        float pre = b1[k];
        pre = fmaf(x0, W1[k],       pre);
        pre = fmaf(x1, W1[HID+k],   pre);
        pre = fmaf(x2, W1[2*HID+k], pre);
        float h = sp_fast(pre);
        unsigned hi = f2bf(h);
        float rm = h - bf2f(hi);
        unsigned md = f2bf(rm);
        hpk[t] = hi; mpk[t] = md;
        lpk[t] = f2bf(rm - bf2f(md));
      }
      hw[e2] = hpk[0] | (hpk[1] << 16);
      mw[e2] = mpk[0] | (mpk[1] << 16);
      lw[e2] = lpk[0] | (lpk[1] << 16);
    }
    uint32x4 hq = {hw[0], hw[1], hw[2], hw[3]};
    uint32x4 mq = {mw[0], mw[1], mw[2], mw[3]};
    uint32x4 lq = {lw[0], lw[1], lw[2], lw[3]};
    *(uint32x4*)&sHi[SW(l, kb + 8*g)] = hq;
    *(uint32x4*)&sMi[SW(l, kb + 8*g)] = mq;
    *(uint32x4*)&sLo[SW(l, kb + 8*g)] = lq;
  }
  __syncthreads();

  // ---- layer 2: pre2[p][n] via 6-term MFMA, split accumulators
  f32x4 acc[4][2], accC[4][2];
  {
    const float b2a = b2[kb + lr];
    const float b2b = b2[kb + 16 + lr];
    #pragma unroll
    for (int mt = 0; mt < 4; mt++){
      acc[mt][0]  = splat4(b2a);
      acc[mt][1]  = splat4(b2b);
      accC[mt][0] = splat4(0.0f);
      accC[mt][1] = splat4(0.0f);
    }
  }
  #pragma unroll
  for (int kc = 0; kc < 4; kc++){
    frag_u bh0, bm0, bl0, bh1, bm1, bl1;
    const int f0 = ((kc*8 + 2*wv + 0)*64 + l)*8;
    const int f1 = ((kc*8 + 2*wv + 1)*64 + l)*8;
    bh0.q = *(const uint32x4*)(w2h + f0);
    bm0.q = *(const uint32x4*)(w2m + f0);
    bl0.q = *(const uint32x4*)(w2l + f0);
    bh1.q = *(const uint32x4*)(w2h + f1);
    bm1.q = *(const uint32x4*)(w2m + f1);
    bl1.q = *(const uint32x4*)(w2l + f1);
    const int kk = 32*kc + 8*lg;
    #pragma unroll
    for (int mt = 0; mt < 4; mt++){
      frag_u ah, am, al;
      ah.q = *(const uint32x4*)&sHi[SW(16*mt + lr, kk)];
      am.q = *(const uint32x4*)&sMi[SW(16*mt + lr, kk)];
      al.q = *(const uint32x4*)&sLo[SW(16*mt + lr, kk)];
      accC[mt][0] = __builtin_amdgcn_mfma_f32_16x16x32_bf16(ah.v, bl0.v, accC[mt][0], 0,0,0);
      accC[mt][0] = __builtin_amdgcn_mfma_f32_16x16x32_bf16(am.v, bm0.v, accC[mt][0], 0,0,0);
      accC[mt][0] = __builtin_amdgcn_mfma_f32_16x16x32_bf16(al.v, bh0.v, accC[mt][0], 0,0,0);
      accC[mt][0] = __builtin_amdgcn_mfma_f32_16x16x32_bf16(ah.v, bm0.v, accC[mt][0], 0,0,0);
      accC[mt][0] = __builtin_amdgcn_mfma_f32_16x16x32_bf16(am.v, bh0.v, accC[mt][0], 0,0,0);
      acc[mt][0]  = __builtin_amdgcn_mfma_f32_16x16x32_bf16(ah.v, bh0.v, acc[mt][0],  0,0,0);
      accC[mt][1] = __builtin_amdgcn_mfma_f32_16x16x32_bf16(ah.v, bl1.v, accC[mt][1], 0,0,0);
      accC[mt][1] = __builtin_amdgcn_mfma_f32_16x16x32_bf16(am.v, bm1.v, accC[mt][1], 0,0,0);
      accC[mt][1] = __builtin_amdgcn_mfma_f32_16x16x32_bf16(al.v, bh1.v, accC[mt][1], 0,0,0);
      accC[mt][1] = __builtin_amdgcn_mfma_f32_16x16x32_bf16(ah.v, bm1.v, accC[mt][1], 0,0,0);
      accC[mt][1] = __builtin_amdgcn_mfma_f32_16x16x32_bf16(am.v, bh1.v, accC[mt][1], 0,0,0);
      acc[mt][1]  = __builtin_amdgcn_mfma_f32_16x16x32_bf16(ah.v, bh1.v, acc[mt][1],  0,0,0);
    }
  }

  // ---- epilogue: sdf = b3 + sum sp(pre2)*W3 (validated reduce structure)
  {
    const float w3a = W3[kb + lr];
    const float w3b = W3[kb + 16 + lr];
    #pragma unroll
    for (int mt = 0; mt < 4; mt++){
      float svr[4];
      #pragma unroll
      for (int r = 0; r < 4; r++){
        float pa = acc[mt][0][r] + accC[mt][0][r];
        float pb = acc[mt][1][r] + accC[mt][1][r];
        svr[r] = sp_fast(pa)*w3a + sp_fast(pb)*w3b;
      }
      #pragma unroll
      for (int m = 1; m < 16; m <<= 1){
        svr[0] += __shfl_xor(svr[0], m);
        svr[1] += __shfl_xor(svr[1], m);
        svr[2] += __shfl_xor(svr[2], m);
        svr[3] += __shfl_xor(svr[3], m);
      }
      if (lr == 0){
        sRed[wv][16*mt + 4*lg + 0] = svr[0];
        sRed[wv][16*mt + 4*lg + 1] = svr[1];
        sRed[wv][16*mt + 4*lg + 2] = svr[2];
        sRed[wv][16*mt + 4*lg + 3] = svr[3];
      }
    }
  }
  __syncthreads();
  if (tid < 64)
    sdf_out[q0+tid] = b3[0] + sRed[0][tid] + sRed[1][tid] + sRed[2][tid] + sRed[3][tid];
}

// ---------------------------------------------------------------- MLP fwd+bwd, both MFMA
// PASS-VALIDATED in round 7 (863 us). Unchanged this round.
__global__ __launch_bounds__(256, 4) void k_mlp_bwd(
    const float* __restrict__ pts,
    const float* __restrict__ W1, const float* __restrict__ b1,
    const float* __restrict__ b2,
    const float* __restrict__ W3, const float* __restrict__ b3,
    const unsigned short* __restrict__ w2fh,  const unsigned short* __restrict__ w2fl,
    const unsigned short* __restrict__ w2tfh, const unsigned short* __restrict__ w2tfl,
    float* __restrict__ sdf_out, float* __restrict__ grad_out)
{
  __shared__ unsigned short sHi[64*HID];   // 16 KB: h1 hi, then g2 hi
  __shared__ unsigned short sLo[64*HID];   // 16 KB: h1 lo, then g2 lo
  __shared__ float sRed[4][64];            // sdf partials per wave
  __shared__ float sPts[64][4];            // x per point (for bwd recompute)
  __shared__ float sGrad[4][64][3];        // grad partials per wave

  const int tid = threadIdx.x;
  const int l   = tid & 63;
  const int wv  = __builtin_amdgcn_readfirstlane(tid >> 6);
  const int lg  = l >> 4;
  const int lr  = l & 15;
  const int q0  = blockIdx.x * 64;
  const int kb  = 32*wv;

  const float x0 = pts[(q0+l)*3+0];
  const float x1 = pts[(q0+l)*3+1];
  const float x2 = pts[(q0+l)*3+2];
  if (wv == 0){ sPts[l][0] = x0; sPts[l][1] = x1; sPts[l][2] = x2; }

  // ---- layer 1: point l, k in [32wv, 32wv+32); bf16 hi/lo staged for MFMA
  #pragma unroll
  for (int g = 0; g < 4; g++){
    unsigned hw[4], lw[4];
    #pragma unroll
    for (int e2 = 0; e2 < 4; e2++){
      unsigned hpk[2], lpk[2];
      #pragma unroll
      for (int t = 0; t < 2; t++){
        int k = kb + 8*g + 2*e2 + t;
        float pre = b1[k];
        pre = fmaf(x0, W1[k],       pre);
        pre = fmaf(x1, W1[HID+k],   pre);
        pre = fmaf(x2, W1[2*HID+k], pre);
        float h = sp_fast(pre);
        unsigned hi = f2bf(h);
        hpk[t] = hi;
        lpk[t] = f2bf(h - bf2f(hi));
      }
      hw[e2] = hpk[0] | (hpk[1] << 16);
      lw[e2] = lpk[0] | (lpk[1] << 16);
    }
    uint32x4 hq = {hw[0], hw[1], hw[2], hw[3]};
    uint32x4 lq = {lw[0], lw[1], lw[2], lw[3]};
    *(uint32x4*)&sHi[SW(l, kb + 8*g)] = hq;
    *(uint32x4*)&sLo[SW(l, kb + 8*g)] = lq;
  }
  __syncthreads();

  // ---- layer 2 forward (MFMA, validated): pre2[p][n], n in wave's 32-slice
  f32x4 acc[4][2];
  {
    const float b2a = b2[kb + lr];
    const float b2b = b2[kb + 16 + lr];
    #pragma unroll
    for (int mt = 0; mt < 4; mt++){
      acc[mt][0] = splat4(b2a);
      acc[mt][1] = splat4(b2b);
    }
  }
  #pragma unroll
  for (int kc = 0; kc < 4; kc++){
    frag_u bh0, bl0, bh1, bl1;
    const int f0 = ((kc*8 + 2*wv + 0)*64 + l)*8;
    const int f1 = ((kc*8 + 2*wv + 1)*64 + l)*8;
    bh0.q = *(const uint32x4*)(w2fh + f0);
    bl0.q = *(const uint32x4*)(w2fl + f0);
    bh1.q = *(const uint32x4*)(w2fh + f1);
    bl1.q = *(const uint32x4*)(w2fl + f1);
    const int kk = 32*kc + 8*lg;
    #pragma unroll
    for (int mt = 0; mt < 4; mt++){
      frag_u ah, al;
      ah.q = *(const uint32x4*)&sHi[SW(16*mt + lr, kk)];
      al.q = *(const uint32x4*)&sLo[SW(16*mt + lr, kk)];
      acc[mt][0] = __builtin_amdgcn_mfma_f32_16x16x32_bf16(ah.v, bh0.v, acc[mt][0], 0,0,0);
      acc[mt][0] = __builtin_amdgcn_mfma_f32_16x16x32_bf16(ah.v, bl0.v, acc[mt][0], 0,0,0);
      acc[mt][0] = __builtin_amdgcn_mfma_f32_16x16x32_bf16(al.v, bh0.v, acc[mt][0], 0,0,0);
      acc[mt][1] = __builtin_amdgcn_mfma_f32_16x16x32_bf16(ah.v, bh1.v, acc[mt][1], 0,0,0);
      acc[mt][1] = __builtin_amdgcn_mfma_f32_16x16x32_bf16(ah.v, bl1.v, acc[mt][1], 0,0,0);
      acc[mt][1] = __builtin_amdgcn_mfma_f32_16x16x32_bf16(al.v, bh1.v, acc[mt][1], 0,0,0);
    }
  }
  __syncthreads();   // all waves done reading h planes; g2 may now overwrite

  // ---- fwd epilogue: sdf partials + g2 = sg(pre2)*W3 as bf16 hi/lo planes
  {
    const float w3a = W3[kb + lr];
    const float w3b = W3[kb + 16 + lr];
    #pragma unroll
    for (int mt = 0; mt < 4; mt++){
      float svr[4];
      #pragma unroll
      for (int r = 0; r < 4; r++){
        float pa = acc[mt][0][r], pb = acc[mt][1][r];
        svr[r] = sp_fast(pa)*w3a + sp_fast(pb)*w3b;
        int pr = 16*mt + 4*lg + r;                    // point (D-row, validated)
        float ga = sg_fast(pa) * w3a;
        float gb = sg_fast(pb) * w3b;
        unsigned ha = f2bf(ga);
        sHi[SW(pr, kb + lr)]      = (unsigned short)ha;
        sLo[SW(pr, kb + lr)]      = (unsigned short)f2bf(ga - bf2f(ha));
        unsigned hb = f2bf(gb);
        sHi[SW(pr, kb + 16 + lr)] = (unsigned short)hb;
        sLo[SW(pr, kb + 16 + lr)] = (unsigned short)f2bf(gb - bf2f(hb));
      }
      #pragma unroll
      for (int m = 1; m < 16; m <<= 1){
        svr[0] += __shfl_xor(svr[0], m);
        svr[1] += __shfl_xor(svr[1], m);
        svr[2] += __shfl_xor(svr[2], m);
        svr[3] += __shfl_xor(svr[3], m);
      }
      if (lr == 0){
        sRed[wv][16*mt + 4*lg + 0] = svr[0];
        sRed[wv][16*mt + 4*lg + 1] = svr[1];
        sRed[wv][16*mt + 4*lg + 2] = svr[2];
        sRed[wv][16*mt + 4*lg + 3] = svr[3];
      }
    }
  }
  __syncthreads();   // g2 planes complete before bwd reads them
  if (tid < 64)
    sdf_out[q0+tid] = b3[0] + sRed[0][tid] + sRed[1][tid] + sRed[2][tid] + sRed[3][tid];

  // ---- backward (MFMA, swapped): D[k][p] = sum_n W2[k][n] * g2[p][n]
  f32x4 acc2[4][2];   // [pt][t]: k = kb + 16*t + 4*lg + r, p = 16*pt + lr
  #pragma unroll
  for (int pt = 0; pt < 4; pt++){
    acc2[pt][0] = splat4(0.0f);
    acc2[pt][1] = splat4(0.0f);
  }
  #pragma unroll
  for (int kcn = 0; kcn < 4; kcn++){
    frag_u ah0, al0, ah1, al1;
    const int f0 = ((kcn*8 + 2*wv + 0)*64 + l)*8;
    const int f1 = ((kcn*8 + 2*wv + 1)*64 + l)*8;
    ah0.q = *(const uint32x4*)(w2tfh + f0);
    al0.q = *(const uint32x4*)(w2tfl + f0);
    ah1.q = *(const uint32x4*)(w2tfh + f1);
    al1.q = *(const uint32x4*)(w2tfl + f1);
    const int nn = 32*kcn + 8*lg;
    #pragma unroll
    for (int pt = 0; pt < 4; pt++){
      frag_u bh, bl;
      bh.q = *(const uint32x4*)&sHi[SW(16*pt + lr, nn)];
      bl.q = *(const uint32x4*)&sLo[SW(16*pt + lr, nn)];
      acc2[pt][0] = __builtin_amdgcn_mfma_f32_16x16x32_bf16(ah0.v, bh.v, acc2[pt][0], 0,0,0);
      acc2[pt][0] = __builtin_amdgcn_mfma_f32_16x16x32_bf16(ah0.v, bl.v, acc2[pt][0], 0,0,0);
      acc2[pt][0] = __builtin_amdgcn_mfma_f32_16x16x32_bf16(al0.v, bh.v, acc2[pt][0], 0,0,0);
      acc2[pt][1] = __builtin_amdgcn_mfma_f32_16x16x32_bf16(ah1.v, bh.v, acc2[pt][1], 0,0,0);
      acc2[pt][1] = __builtin_amdgcn_mfma_f32_16x16x32_bf16(ah1.v, bl.v, acc2[pt][1], 0,0,0);
      acc2[pt][1] = __builtin_amdgcn_mfma_f32_16x16x32_bf16(al1.v, bh.v, acc2[pt][1], 0,0,0);
    }
  }

  // ---- bwd epilogue: dp1 = dh1*sg(pre1); grad = W1 @ dp1, reduce over lg
  {
    float w1a[2][4], w1b[2][4], w1c[2][4], b1v[2][4];
    #pragma unroll
    for (int t = 0; t < 2; t++)
      #pragma unroll
      for (int r = 0; r < 4; r++){
        int k = kb + 16*t + 4*lg + r;
        w1a[t][r] = W1[k]; w1b[t][r] = W1[HID+k]; w1c[t][r] = W1[2*HID+k];
        b1v[t][r] = b1[k];
      }
    #pragma unroll
    for (int pt = 0; pt < 4; pt++){
      const int p = 16*pt + lr;
      const float xx = sPts[p][0], xy = sPts[p][1], xz = sPts[p][2];
      float gx = 0.f, gy = 0.f, gz = 0.f;
      #pragma unroll
      for (int t = 0; t < 2; t++){
        #pragma unroll
        for (int r = 0; r < 4; r++){
          float pre1 = fmaf(xx, w1a[t][r], fmaf(xy, w1b[t][r], fmaf(xz, w1c[t][r], b1v[t][r])));
          float dp = acc2[pt][t][r] * sg_fast(pre1);
          gx = fmaf(w1a[t][r], dp, gx);
          gy = fmaf(w1b[t][r], dp, gy);
          gz = fmaf(w1c[t][r], dp, gz);
        }
      }
      gx += __shfl_xor(gx, 16); gx += __shfl_xor(gx, 32);
      gy += __shfl_xor(gy, 16); gy += __shfl_xor(gy, 32);
      gz += __shfl_xor(gz, 16); gz += __shfl_xor(gz, 32);
      if (lg == 0){
        sGrad[wv][p][0] = gx; sGrad[wv][p][1] = gy; sGrad[wv][p][2] = gz;
      }
    }
  }
  __syncthreads();
  if (tid < 64){
    #pragma unroll
    for (int c = 0; c < 3; c++)
      grad_out[(q0+tid)*3+c] =
        sGrad[0][tid][c] + sGrad[1][tid][c] + sGrad[2][tid][c] + sGrad[3][tid][c];
  }
}

// ---------------------------------------------------------------- scatters
__global__ void k_scatter_init(const float* __restrict__ sdf_tmp, float* __restrict__ sdf_buf){
  int idx = blockIdx.x*256 + threadIdx.x;
  if (idx >= NRAYS*64) return;
  sdf_buf[(idx >> 6)*128 + (idx & 63)] = sdf_tmp[idx];
}
__global__ void k_scatter_new(const float* __restrict__ sdf_tmp, const int* __restrict__ slots,
                              float* __restrict__ sdf_buf){
  int idx = blockIdx.x*256 + threadIdx.x;
  if (idx >= NRAYS*16) return;
  sdf_buf[(idx >> 4)*128 + slots[idx]] = sdf_tmp[idx];
}

// ---------------------------------------------------------------- upsample (one wave per ray)
__global__ __launch_bounds__(64) void k_upsample(
      const float* __restrict__ rays_o, const float* __restrict__ rays_d,
      float* __restrict__ z_buf, float* __restrict__ sdf_buf,
      float* __restrict__ pts_new, int* __restrict__ slots,
      int S, float inv_s, int last){
  __shared__ float z[128], sd[128], rad[128], cosv[128], alf[128], wv[128], cdf[129], nz[16];
  __shared__ int slt[16];
  const int ray = blockIdx.x;
  const int l   = threadIdx.x;
  const float ox = rays_o[ray*3], oy = rays_o[ray*3+1], oz = rays_o[ray*3+2];
  const float dx = rays_d[ray*3], dy = rays_d[ray*3+1], dz = rays_d[ray*3+2];
  for (int j = l; j < S; j += 64){
    float zz = z_buf[ray*128+j];
    z[j]  = zz;
    sd[j] = sdf_buf[ray*128+j];
    float px = ox+dx*zz, py = oy+dy*zz, pz = oz+dz*zz;
    rad[j] = sqrtf(px*px + py*py + pz*pz);
  }
  __syncthreads();
  for (int j = l; j < S-1; j += 64)
    cosv[j] = (sd[j+1]-sd[j]) / (z[j+1]-z[j] + 1e-5f);
  __syncthreads();
  for (int j = l; j < S-1; j += 64){
    float cv = fminf((j > 0) ? cosv[j-1] : 0.0f, cosv[j]);
    cv = fminf(fmaxf(cv, -1000.0f), 0.0f);
    float inside = (rad[j] < 1.0f || rad[j+1] < 1.0f) ? 1.0f : 0.0f;
    cv *= inside;
    float mid  = 0.5f*(sd[j]+sd[j+1]);
    float dist = z[j+1]-z[j];
    float e = sg_f((mid - cv*dist*0.5f)*inv_s);
    float f = sg_f((mid + cv*dist*0.5f)*inv_s);
    alf[j] = (e - f + 1e-5f) / (e + 1e-5f);
  }
  __syncthreads();
  if (l == 0){
    float T = 1.0f, wsum = 0.0f;
    for (int j = 0; j < S-1; j++){
      float w = alf[j]*T + 1e-5f;   // weights = alpha*trans + 1e-5
      wv[j] = w; wsum += w;
      T *= (1.0f - alf[j] + 1e-7f);
    }
    cdf[0] = 0.0f;
    float c = 0.0f;
    for (int j = 0; j < S-1; j++){ c += wv[j]/wsum; cdf[j+1] = c; }
  }
  __syncthreads();
  if (l < 16){
    float u = 0.03125f + 0.0625f*(float)l;   // linspace(1/32, 31/32, 16)
    int idx = 0;
    while (idx < S && cdf[idx] <= u) idx++;  // searchsorted side='right'
    int below = idx - 1; if (below < 0) below = 0;
    int above = (idx < S-1) ? idx : (S-1);
    float cb = cdf[below], ca = cdf[above];
    float den = ca - cb; if (den < 1e-5f) den = 1.0f;
    float t = (u - cb) / den;
    nz[l] = z[below] + t*(z[above] - z[below]);
  }
  __syncthreads();
  if (l == 0){
    // stable in-place merge from the back (old-before-new on ties)
    int i = S-1, j = 15;
    for (int dst = S+15; dst >= 0; --dst){
      bool takeOld = (j < 0) || (i >= 0 && z[i] > nz[j]);
      if (takeOld){ z[dst] = z[i]; sd[dst] = sd[i]; i--; }
      else        { z[dst] = nz[j]; slt[j] = dst; j--; }
    }
  }
  __syncthreads();
  for (int j = l; j < S+16; j += 64){
    z_buf[ray*128+j]  = z[j];
    sdf_buf[ray*128+j] = sd[j];
  }
  if (!last && l < 16){
    slots[ray*16+l] = slt[l];
    float zz = nz[l];
    pts_new[(ray*16+l)*3+0] = ox + dx*zz;
    pts_new[(ray*16+l)*3+1] = oy + dy*zz;
    pts_new[(ray*16+l)*3+2] = oz + dz*zz;
  }
}

// ---------------------------------------------------------------- final mid-point pts
__global__ void k_prep(const float* __restrict__ rays_o, const float* __restrict__ rays_d,
                       const float* __restrict__ z_buf, float* __restrict__ pts){
  int idx = blockIdx.x*256 + threadIdx.x;
  if (idx >= NRAYS*128) return;
  int ray = idx >> 7, s = idx & 127;
  float z = z_buf[idx];
  float d = (s < 127) ? (z_buf[idx+1] - z) : 0.03125f;   // SAMPLE_DIST = 2/64
  float mid = z + 0.5f*d;
  pts[idx*3+0] = rays_o[ray*3+0] + rays_d[ray*3+0]*mid;
  pts[idx*3+1] = rays_o[ray*3+1] + rays_d[ray*3+1]*mid;
  pts[idx*3+2] = rays_o[ray*3+2] + rays_d[ray*3+2]*mid;
}

// ---------------------------------------------------------------- render (one WAVE per ray)
// Old version: 4096 threads total, 128-step serial loop each -> latency-bound.
// New: lane l handles samples {2l, 2l+1}; alphas in parallel; transmittance
// T via 6-step shfl_up product scan; depth via wave reduce. Exact epsilon
// semantics of the reference preserved (T *= 1-a+1e-7; d=0.03125 at s=127).
__global__ __launch_bounds__(64) void k_render(
    const float* __restrict__ z_buf, const float* __restrict__ sdf_mid,
    const float* __restrict__ rays_d, const float* __restrict__ grad,
    const float* __restrict__ variance, float* __restrict__ depth_out){
  const int ray = blockIdx.x;
  const int l   = threadIdx.x;
  float inv_s = expf(10.0f * variance[0]);
  inv_s = fminf(fmaxf(inv_s, 1e-6f), 1e6f);
  const float dx = rays_d[ray*3], dy = rays_d[ray*3+1], dz = rays_d[ray*3+2];
  const int i0 = ray*128 + 2*l, i1 = i0 + 1;
  const float z0 = z_buf[i0], z1 = z_buf[i1];
  const float zn1 = __shfl_down(z0, 1);              // z[2l+2] from lane l+1
  const float d0 = z1 - z0;
  const float d1 = (l < 63) ? (zn1 - z1) : 0.03125f;
  float a0, a1;
  {
    float sdf = sdf_mid[i0];
    float gx = grad[i0*3], gy = grad[i0*3+1], gz = grad[i0*3+2];
    float tc = dx*gx + dy*gy + dz*gz;
    float ic = -fmaxf(0.5f - 0.5f*tc, 0.0f);
    float e = sg_fast((sdf - ic*d0*0.5f)*inv_s);
    float f = sg_fast((sdf + ic*d0*0.5f)*inv_s);
    a0 = fminf(fmaxf((e - f + 1e-5f) / (e + 1e-5f), 0.0f), 1.0f);
  }
  {
    float sdf = sdf_mid[i1];
    float gx = grad[i1*3], gy = grad[i1*3+1], gz = grad[i1*3+2];
    float tc = dx*gx + dy*gy + dz*gz;
    float ic = -fmaxf(0.5f - 0.5f*tc, 0.0f);
    float e = sg_fast((sdf - ic*d1*0.5f)*inv_s);
    float f = sg_fast((sdf + ic*d1*0.5f)*inv_s);
    a1 = fminf(fmaxf((e - f + 1e-5f) / (e + 1e-5f), 0.0f), 1.0f);
  }
  const float f0 = 1.0f - a0 + 1e-7f;
  const float f1 = 1.0f - a1 + 1e-7f;
  // inclusive product scan of per-lane factor (f0*f1), then exclusive shift
  float incl = f0 * f1;
  #pragma unroll
  for (int off = 1; off < 64; off <<= 1){
    float t = __shfl_up(incl, off);
    if (l >= off) incl *= t;
  }
  float P = __shfl_up(incl, 1);        // T at sample 2l
  if (l == 0) P = 1.0f;
  float part = P * (a0*z0 + f0*a1*z1); // a0*T(2l)*z0 + a1*T(2l+1)*z1
  #pragma unroll
  for (int m = 1; m < 64; m <<= 1) part += __shfl_xor(part, m);
  if (l == 0) depth_out[ray] = part;
}

// ---------------------------------------------------------------- launcher
extern "C" void kernel_launch(void* const* d_in, const int* in_sizes, int n_in,
                              void* d_out, int out_size, void* d_ws, size_t ws_size,
                              hipStream_t stream){
  (void)in_sizes; (void)n_in; (void)out_size; (void)ws_size;
  const float* rays_o = (const float*)d_in[0];
  const float* rays_d = (const float*)d_in[1];
  const float* nearv  = (const float*)d_in[2];
  const float* farv   = (const float*)d_in[3];
  const float* W1 = (const float*)d_in[4];
  const float* b1 = (const float*)d_in[5];
  const float* W2 = (const float*)d_in[6];
  const float* b2 = (const float*)d_in[7];
  const float* W3 = (const float*)d_in[8];
  const float* b3 = (const float*)d_in[9];
  const float* variance = (const float*)d_in[10];

  // Workspace layout: within round-0's proven footprint (6,619,136 B).
  float* ws      = (float*)d_ws;
  float* z_buf   = ws;                    // [0,       524288)
  float* sdf_buf = ws + 524288;           // [524288,  1048576)
  float* sdf_tmp = ws + 1048576;          // [1048576, 1572864)
  int*   slots   = (int*)(ws + 1589248);  // [1589248, 1654784) as ints
  // 2-way fwd + bwd(A-side) fragment tables alias sdf_buf — created AFTER the
  // upsample loop, when sdf_buf is dead (round-4/6/7 validated placement).
  unsigned short* w2fh  = (unsigned short*)(ws + 524288);  // [524288, 532480)
  unsigned short* w2fl  = w2fh + 16384;                    // [532480, 540672)
  unsigned short* w2tfh = w2fh + 32768;                    // [540672, 548864)
  unsigned short* w2tfl = w2fh + 49152;                    // [548864, 557056)
  // 3-way fwd fragments live in the upper (unused) half of sdf_tmp.
  unsigned short* w2h3 = (unsigned short*)(ws + 1310720); // [1310720, 1318912)
  unsigned short* w2m3 = w2h3 + 16384;                    // [1318912, 1327104)
  unsigned short* w2l3 = w2h3 + 32768;                    // [1327104, 1335296)

  float* out       = (float*)d_out;
  float* depth_out = out;
  float* grad_out  = out + NRAYS;         // 524288*3 floats
  float* pts       = grad_out;            // pts staging aliases grad region

  k_make_frags3<<<dim3(8), dim3(256), 0, stream>>>(W2, w2h3, w2m3, w2l3);
  k_init<<<dim3(1024), dim3(256), 0, stream>>>(rays_o, rays_d, nearv, farv, z_buf, pts);
  k_mlp_fwd_t<<<dim3(4096), dim3(256), 0, stream>>>(pts, W1,b1,b2,W3,b3,
                                                    w2h3,w2m3,w2l3, sdf_tmp);
  k_scatter_init<<<dim3(1024), dim3(256), 0, stream>>>(sdf_tmp, sdf_buf);

  for (int i = 0; i < 4; i++){
    int S = 64 + 16*i;
    float inv_s = (float)(64 << i);
    int last = (i == 3) ? 1 : 0;
    k_upsample<<<dim3(4096), dim3(64), 0, stream>>>(rays_o, rays_d, z_buf, sdf_buf,
                                                    pts, slots, S, inv_s, last);
    if (!last){
      k_mlp_fwd_t<<<dim3(1024), dim3(256), 0, stream>>>(pts, W1,b1,b2,W3,b3,
                                                        w2h3,w2m3,w2l3, sdf_tmp);
      k_scatter_new<<<dim3(256), dim3(256), 0, stream>>>(sdf_tmp, slots, sdf_buf);
    }
  }

  // sdf_buf is dead from here on — safe to overwrite with fragments.
  k_make_frags<<<dim3(16), dim3(256), 0, stream>>>(W2, w2fh, w2fl, w2tfh, w2tfl);
  k_prep<<<dim3(2048), dim3(256), 0, stream>>>(rays_o, rays_d, z_buf, pts);
  k_mlp_bwd<<<dim3(8192), dim3(256), 0, stream>>>(pts, W1,b1,b2,W3,b3,
                                                  w2fh,w2fl,w2tfh,w2tfl, sdf_tmp, grad_out);
  k_render<<<dim3(4096), dim3(64), 0, stream>>>(z_buf, sdf_tmp, rays_d, grad_out,
                                                variance, depth_out);
}

// Round 9
// 544.696 us; speedup vs baseline: 2.8342x; 1.0850x over previous
//
#include <hip/hip_runtime.h>
#include <math.h>

#define HID 128
#define NRAYS 4096
#define TP 64   // points per MLP tile (one per lane)

typedef __bf16 bf16x8 __attribute__((ext_vector_type(8)));
typedef float f32x4 __attribute__((ext_vector_type(4)));
typedef unsigned int uint32x4 __attribute__((ext_vector_type(4)));

union frag_u { bf16x8 v; uint32x4 q; };

__device__ __forceinline__ unsigned f2bf(float f){   // fp32 -> bf16 bits, RNE
  unsigned u = __float_as_uint(f);
  u += 0x7FFFu + ((u >> 16) & 1u);
  return u >> 16;
}
__device__ __forceinline__ float bf2f(unsigned h){
  return __uint_as_float(h << 16);
}
__device__ __forceinline__ float sp_fast(float x){   // softplus, v_exp/v_log (~4e-7 abs)
  float e = __expf(-fabsf(x));
  return fmaxf(x, 0.0f) + __logf(1.0f + e);
}
__device__ __forceinline__ float sg_fast(float x){   // sigmoid, fast
  float e = __expf(-fabsf(x));
  float r = __builtin_amdgcn_rcpf(1.0f + e);
  return (x >= 0.0f ? 1.0f : e) * r;
}
__device__ __forceinline__ float sg_f(float x){      // sigmoid, libm-precision
  return 1.0f / (1.0f + expf(-x));
}
__device__ __forceinline__ f32x4 splat4(float x){
  f32x4 v = {x, x, x, x};
  return v;
}

// Swizzled LDS index (ushort units) for a [64][128] bf16 plane.
// byte ^= ((row&7)<<4)  ->  ushort idx ^= ((row&7)<<3). Keeps 16B alignment.
#define SW(p,k) ((((p)*HID) + (k)) ^ (((p)&7)<<3))

// ---------------------------------------------------------------- W2 fragment prep (2-way x 2 layouts)
// frag f = kc*8 + tg; element: contraction a = 32*kc + 8*(lane>>4)+e,
// output b = 16*tg + (lane&15). Stored at [(f*64+lane)*8 + e].
// which=0: v = W2[a*HID+b] -> B-operand for fwd (B[k][n], col=n).
// which=1: v = W2[b*HID+a] -> A-operand for swapped bwd (A[k][n]=W2[k][n], row=k).
__global__ void k_make_frags(const float* __restrict__ W2,
    unsigned short* __restrict__ w2fh,  unsigned short* __restrict__ w2fl,
    unsigned short* __restrict__ w2tfh, unsigned short* __restrict__ w2tfl){
  int idx = blockIdx.x*256 + threadIdx.x;
  if (idx >= 4096) return;
  int which = idx >> 11;
  int f    = (idx >> 6) & 31;
  int lane = idx & 63;
  int kc = f >> 3, tg = f & 7;
  int lg = lane >> 4, lr = lane & 15;
  unsigned short* dh = which ? w2tfh : w2fh;
  unsigned short* dl = which ? w2tfl : w2fl;
  int base = (f*64 + lane)*8;
  #pragma unroll
  for (int e = 0; e < 8; e++){
    int a = 32*kc + 8*lg + e;      // contraction index
    int b = 16*tg + lr;            // output index (fwd: n / bwd: k row)
    float v = which ? W2[b*HID + a] : W2[a*HID + b];
    unsigned hi = f2bf(v);
    dh[base+e] = (unsigned short)hi;
    dl[base+e] = (unsigned short)f2bf(v - bf2f(hi));
  }
}

// ---------------------------------------------------------------- W2 fwd-fragment prep (3-way, precision fwd)
// Triple-bf16 split: v = hi + mid + lo to ~2^-27 relative. Same fragment order.
__global__ void k_make_frags3(const float* __restrict__ W2,
    unsigned short* __restrict__ dh, unsigned short* __restrict__ dm,
    unsigned short* __restrict__ dl){
  int idx = blockIdx.x*256 + threadIdx.x;
  if (idx >= 2048) return;
  int f    = idx >> 6;             // 0..31
  int lane = idx & 63;
  int kc = f >> 3, tg = f & 7;
  int lg = lane >> 4, lr = lane & 15;
  int base = (f*64 + lane)*8;
  #pragma unroll
  for (int e = 0; e < 8; e++){
    int a = 32*kc + 8*lg + e;      // contraction index k
    int b = 16*tg + lr;            // output index n
    float v = W2[a*HID + b];
    unsigned hi = f2bf(v);
    float rm = v - bf2f(hi);
    unsigned md = f2bf(rm);
    dh[base+e] = (unsigned short)hi;
    dm[base+e] = (unsigned short)md;
    dl[base+e] = (unsigned short)f2bf(rm - bf2f(md));
  }
}

// ---------------------------------------------------------------- initial z + pts
__global__ void k_init(const float* __restrict__ rays_o, const float* __restrict__ rays_d,
                       const float* __restrict__ nearv, const float* __restrict__ farv,
                       float* __restrict__ z_buf, float* __restrict__ pts){
  int idx = blockIdx.x*256 + threadIdx.x;
  if (idx >= NRAYS*64) return;
  int ray = idx >> 6, j = idx & 63;
  float nr = nearv[ray];
  float z = nr + (farv[ray] - nr) * ((float)j / 63.0f);
  z_buf[ray*128 + j] = z;
  pts[idx*3+0] = rays_o[ray*3+0] + rays_d[ray*3+0]*z;
  pts[idx*3+1] = rays_o[ray*3+1] + rays_d[ray*3+1]*z;
  pts[idx*3+2] = rays_o[ray*3+2] + rays_d[ray*3+2]*z;
}

// ---------------------------------------------------------------- MLP forward, MFMA 6-term
// PASS-VALIDATED structure (rounds 6-8). Feeds the upsample cdf; triple-bf16
// RNE split keeps pre2 error ~1e-6. This round: fused output scatter —
// mode 0: sdf_out[q0+tid]; mode 1: ray-major sdf_out[ray*128+s] (replaces
// k_scatter_init); mode 2: sdf_out[(p>>4)*128 + slots[p]] (replaces
// k_scatter_new).
__global__ __launch_bounds__(256, 3) void k_mlp_fwd_t(
    const float* __restrict__ pts,
    const float* __restrict__ W1, const float* __restrict__ b1,
    const float* __restrict__ b2,
    const float* __restrict__ W3, const float* __restrict__ b3,
    const unsigned short* __restrict__ w2h, const unsigned short* __restrict__ w2m,
    const unsigned short* __restrict__ w2l,
    float* __restrict__ sdf_out, const int* __restrict__ slots, int mode)
{
  __shared__ unsigned short sHi[64*HID];   // 16 KB each
  __shared__ unsigned short sMi[64*HID];
  __shared__ unsigned short sLo[64*HID];
  __shared__ float sRed[4][64];

  const int tid = threadIdx.x;
  const int l   = tid & 63;
  const int wv  = __builtin_amdgcn_readfirstlane(tid >> 6);
  const int lg  = l >> 4;
  const int lr  = l & 15;
  const int q0  = blockIdx.x * 64;
  const int kb  = 32*wv;

  const float x0 = pts[(q0+l)*3+0];
  const float x1 = pts[(q0+l)*3+1];
  const float x2 = pts[(q0+l)*3+2];

  // ---- layer 1: point l, k in wave's 32-slice; fast softplus, 3-way RNE split
  #pragma unroll
  for (int g = 0; g < 4; g++){
    unsigned hw[4], mw[4], lw[4];
    #pragma unroll
    for (int e2 = 0; e2 < 4; e2++){
      unsigned hpk[2], mpk[2], lpk[2];
      #pragma unroll
      for (int t = 0; t < 2; t++){
        int k = kb + 8*g + 2*e2 + t;
        float pre = b1[k];
        pre = fmaf(x0, W1[k],       pre);
        pre = fmaf(x1, W1[HID+k],   pre);
        pre = fmaf(x2, W1[2*HID+k], pre);
        float h = sp_fast(pre);
        unsigned hi = f2bf(h);
        float rm = h - bf2f(hi);
        unsigned md = f2bf(rm);
        hpk[t] = hi; mpk[t] = md;
        lpk[t] = f2bf(rm - bf2f(md));
      }
      hw[e2] = hpk[0] | (hpk[1] << 16);
      mw[e2] = mpk[0] | (mpk[1] << 16);
      lw[e2] = lpk[0] | (lpk[1] << 16);
    }
    uint32x4 hq = {hw[0], hw[1], hw[2], hw[3]};
    uint32x4 mq = {mw[0], mw[1], mw[2], mw[3]};
    uint32x4 lq = {lw[0], lw[1], lw[2], lw[3]};
    *(uint32x4*)&sHi[SW(l, kb + 8*g)] = hq;
    *(uint32x4*)&sMi[SW(l, kb + 8*g)] = mq;
    *(uint32x4*)&sLo[SW(l, kb + 8*g)] = lq;
  }
  __syncthreads();

  // ---- layer 2: pre2[p][n] via 6-term MFMA, split accumulators
  f32x4 acc[4][2], accC[4][2];
  {
    const float b2a = b2[kb + lr];
    const float b2b = b2[kb + 16 + lr];
    #pragma unroll
    for (int mt = 0; mt < 4; mt++){
      acc[mt][0]  = splat4(b2a);
      acc[mt][1]  = splat4(b2b);
      accC[mt][0] = splat4(0.0f);
      accC[mt][1] = splat4(0.0f);
    }
  }
  #pragma unroll
  for (int kc = 0; kc < 4; kc++){
    frag_u bh0, bm0, bl0, bh1, bm1, bl1;
    const int f0 = ((kc*8 + 2*wv + 0)*64 + l)*8;
    const int f1 = ((kc*8 + 2*wv + 1)*64 + l)*8;
    bh0.q = *(const uint32x4*)(w2h + f0);
    bm0.q = *(const uint32x4*)(w2m + f0);
    bl0.q = *(const uint32x4*)(w2l + f0);
    bh1.q = *(const uint32x4*)(w2h + f1);
    bm1.q = *(const uint32x4*)(w2m + f1);
    bl1.q = *(const uint32x4*)(w2l + f1);
    const int kk = 32*kc + 8*lg;
    #pragma unroll
    for (int mt = 0; mt < 4; mt++){
      frag_u ah, am, al;
      ah.q = *(const uint32x4*)&sHi[SW(16*mt + lr, kk)];
      am.q = *(const uint32x4*)&sMi[SW(16*mt + lr, kk)];
      al.q = *(const uint32x4*)&sLo[SW(16*mt + lr, kk)];
      accC[mt][0] = __builtin_amdgcn_mfma_f32_16x16x32_bf16(ah.v, bl0.v, accC[mt][0], 0,0,0);
      accC[mt][0] = __builtin_amdgcn_mfma_f32_16x16x32_bf16(am.v, bm0.v, accC[mt][0], 0,0,0);
      accC[mt][0] = __builtin_amdgcn_mfma_f32_16x16x32_bf16(al.v, bh0.v, accC[mt][0], 0,0,0);
      accC[mt][0] = __builtin_amdgcn_mfma_f32_16x16x32_bf16(ah.v, bm0.v, accC[mt][0], 0,0,0);
      accC[mt][0] = __builtin_amdgcn_mfma_f32_16x16x32_bf16(am.v, bh0.v, accC[mt][0], 0,0,0);
      acc[mt][0]  = __builtin_amdgcn_mfma_f32_16x16x32_bf16(ah.v, bh0.v, acc[mt][0],  0,0,0);
      accC[mt][1] = __builtin_amdgcn_mfma_f32_16x16x32_bf16(ah.v, bl1.v, accC[mt][1], 0,0,0);
      accC[mt][1] = __builtin_amdgcn_mfma_f32_16x16x32_bf16(am.v, bm1.v, accC[mt][1], 0,0,0);
      accC[mt][1] = __builtin_amdgcn_mfma_f32_16x16x32_bf16(al.v, bh1.v, accC[mt][1], 0,0,0);
      accC[mt][1] = __builtin_amdgcn_mfma_f32_16x16x32_bf16(ah.v, bm1.v, accC[mt][1], 0,0,0);
      accC[mt][1] = __builtin_amdgcn_mfma_f32_16x16x32_bf16(am.v, bh1.v, accC[mt][1], 0,0,0);
      acc[mt][1]  = __builtin_amdgcn_mfma_f32_16x16x32_bf16(ah.v, bh1.v, acc[mt][1],  0,0,0);
    }
  }

  // ---- epilogue: sdf = b3 + sum sp(pre2)*W3 (validated reduce structure)
  {
    const float w3a = W3[kb + lr];
    const float w3b = W3[kb + 16 + lr];
    #pragma unroll
    for (int mt = 0; mt < 4; mt++){
      float svr[4];
      #pragma unroll
      for (int r = 0; r < 4; r++){
        float pa = acc[mt][0][r] + accC[mt][0][r];
        float pb = acc[mt][1][r] + accC[mt][1][r];
        svr[r] = sp_fast(pa)*w3a + sp_fast(pb)*w3b;
      }
      #pragma unroll
      for (int m = 1; m < 16; m <<= 1){
        svr[0] += __shfl_xor(svr[0], m);
        svr[1] += __shfl_xor(svr[1], m);
        svr[2] += __shfl_xor(svr[2], m);
        svr[3] += __shfl_xor(svr[3], m);
      }
      if (lr == 0){
        sRed[wv][16*mt + 4*lg + 0] = svr[0];
        sRed[wv][16*mt + 4*lg + 1] = svr[1];
        sRed[wv][16*mt + 4*lg + 2] = svr[2];
        sRed[wv][16*mt + 4*lg + 3] = svr[3];
      }
    }
  }
  __syncthreads();
  if (tid < 64){
    float sv = b3[0] + sRed[0][tid] + sRed[1][tid] + sRed[2][tid] + sRed[3][tid];
    if (mode == 0){
      sdf_out[q0 + tid] = sv;
    } else if (mode == 1){
      sdf_out[(q0 << 1) + tid] = sv;            // ray=q0/64 -> ray*128 + s
    } else {
      int p = q0 + tid;
      sdf_out[(p >> 4)*128 + slots[p]] = sv;    // ray-major slot scatter
    }
  }
}

// ---------------------------------------------------------------- MLP fwd+bwd, both MFMA
// Fwd half 3-term (pass-validated r4/6/7/8); bwd swapped-operand GEMM
// (pass-validated r7/8), this round reduced to hi-only operands:
//   dh1[k][p] ~= sum_n W2hi[k][n] * g2hi[p][n]   (rel err ~0.3% -> grad ~5e-4)
// Also fused: mid-point pts computed in-kernel from z_buf (k_prep deleted);
// truncation bf16 splits for h1/g2 staging (cheaper than RNE; h>=0).
__global__ __launch_bounds__(256, 4) void k_mlp_bwd(
    const float* __restrict__ z_buf,
    const float* __restrict__ rays_o, const float* __restrict__ rays_d,
    const float* __restrict__ W1, const float* __restrict__ b1,
    const float* __restrict__ b2,
    const float* __restrict__ W3, const float* __restrict__ b3,
    const unsigned short* __restrict__ w2fh,  const unsigned short* __restrict__ w2fl,
    const unsigned short* __restrict__ w2tfh,
    float* __restrict__ sdf_out, float* __restrict__ grad_out)
{
  __shared__ unsigned short sHi[64*HID];   // 16 KB: h1 hi, then g2 hi
  __shared__ unsigned short sLo[64*HID];   // 16 KB: h1 lo (fwd 3-term only)
  __shared__ float sRed[4][64];            // sdf partials per wave
  __shared__ float sPts[64][4];            // x per point (for bwd recompute)
  __shared__ float sGrad[4][64][3];        // grad partials per wave

  const int tid = threadIdx.x;
  const int l   = tid & 63;
  const int wv  = __builtin_amdgcn_readfirstlane(tid >> 6);
  const int lg  = l >> 4;
  const int lr  = l & 15;
  const int q0  = blockIdx.x * 64;
  const int kb  = 32*wv;

  // ---- fused k_prep: mid-point pts from z_buf (ray uniform per block)
  const int ray = q0 >> 7;
  const int s   = (q0 & 127) + l;
  const float z  = z_buf[q0 + l];
  const float zn = z_buf[q0 + l + ((s < 127) ? 1 : 0)];
  const float d  = (s < 127) ? (zn - z) : 0.03125f;    // SAMPLE_DIST = 2/64
  const float midz = z + 0.5f*d;
  const float x0 = rays_o[ray*3+0] + rays_d[ray*3+0]*midz;
  const float x1 = rays_o[ray*3+1] + rays_d[ray*3+1]*midz;
  const float x2 = rays_o[ray*3+2] + rays_d[ray*3+2]*midz;
  if (wv == 0){ sPts[l][0] = x0; sPts[l][1] = x1; sPts[l][2] = x2; }

  // ---- layer 1: point l, k in [32wv, 32wv+32); bf16 hi/lo TRUNC split (h>=0)
  #pragma unroll
  for (int g = 0; g < 4; g++){
    unsigned hw[4], lw[4];
    #pragma unroll
    for (int e2 = 0; e2 < 4; e2++){
      unsigned hpk[2], lpk[2];
      #pragma unroll
      for (int t = 0; t < 2; t++){
        int k = kb + 8*g + 2*e2 + t;
        float pre = b1[k];
        pre = fmaf(x0, W1[k],       pre);
        pre = fmaf(x1, W1[HID+k],   pre);
        pre = fmaf(x2, W1[2*HID+k], pre);
        float h = sp_fast(pre);
        unsigned hi = __float_as_uint(h) >> 16;
        float rm = h - __uint_as_float(hi << 16);
        hpk[t] = hi;
        lpk[t] = __float_as_uint(rm) >> 16;
      }
      hw[e2] = hpk[0] | (hpk[1] << 16);
      lw[e2] = lpk[0] | (lpk[1] << 16);
    }
    uint32x4 hq = {hw[0], hw[1], hw[2], hw[3]};
    uint32x4 lq = {lw[0], lw[1], lw[2], lw[3]};
    *(uint32x4*)&sHi[SW(l, kb + 8*g)] = hq;
    *(uint32x4*)&sLo[SW(l, kb + 8*g)] = lq;
  }
  __syncthreads();

  // ---- layer 2 forward (MFMA, validated): pre2[p][n], n in wave's 32-slice
  f32x4 acc[4][2];
  {
    const float b2a = b2[kb + lr];
    const float b2b = b2[kb + 16 + lr];
    #pragma unroll
    for (int mt = 0; mt < 4; mt++){
      acc[mt][0] = splat4(b2a);
      acc[mt][1] = splat4(b2b);
    }
  }
  #pragma unroll
  for (int kc = 0; kc < 4; kc++){
    frag_u bh0, bl0, bh1, bl1;
    const int f0 = ((kc*8 + 2*wv + 0)*64 + l)*8;
    const int f1 = ((kc*8 + 2*wv + 1)*64 + l)*8;
    bh0.q = *(const uint32x4*)(w2fh + f0);
    bl0.q = *(const uint32x4*)(w2fl + f0);
    bh1.q = *(const uint32x4*)(w2fh + f1);
    bl1.q = *(const uint32x4*)(w2fl + f1);
    const int kk = 32*kc + 8*lg;
    #pragma unroll
    for (int mt = 0; mt < 4; mt++){
      frag_u ah, al;
      ah.q = *(const uint32x4*)&sHi[SW(16*mt + lr, kk)];
      al.q = *(const uint32x4*)&sLo[SW(16*mt + lr, kk)];
      acc[mt][0] = __builtin_amdgcn_mfma_f32_16x16x32_bf16(ah.v, bh0.v, acc[mt][0], 0,0,0);
      acc[mt][0] = __builtin_amdgcn_mfma_f32_16x16x32_bf16(ah.v, bl0.v, acc[mt][0], 0,0,0);
      acc[mt][0] = __builtin_amdgcn_mfma_f32_16x16x32_bf16(al.v, bh0.v, acc[mt][0], 0,0,0);
      acc[mt][1] = __builtin_amdgcn_mfma_f32_16x16x32_bf16(ah.v, bh1.v, acc[mt][1], 0,0,0);
      acc[mt][1] = __builtin_amdgcn_mfma_f32_16x16x32_bf16(ah.v, bl1.v, acc[mt][1], 0,0,0);
      acc[mt][1] = __builtin_amdgcn_mfma_f32_16x16x32_bf16(al.v, bh1.v, acc[mt][1], 0,0,0);
    }
  }
  __syncthreads();   // all waves done reading h planes; g2 may now overwrite sHi

  // ---- fwd epilogue: sdf partials + g2 = sg(pre2)*W3 hi-only (trunc) into sHi
  {
    const float w3a = W3[kb + lr];
    const float w3b = W3[kb + 16 + lr];
    #pragma unroll
    for (int mt = 0; mt < 4; mt++){
      float svr[4];
      #pragma unroll
      for (int r = 0; r < 4; r++){
        float pa = acc[mt][0][r], pb = acc[mt][1][r];
        svr[r] = sp_fast(pa)*w3a + sp_fast(pb)*w3b;
        int pr = 16*mt + 4*lg + r;                    // point (D-row, validated)
        float ga = sg_fast(pa) * w3a;
        float gb = sg_fast(pb) * w3b;
        sHi[SW(pr, kb + lr)]      = (unsigned short)(__float_as_uint(ga) >> 16);
        sHi[SW(pr, kb + 16 + lr)] = (unsigned short)(__float_as_uint(gb) >> 16);
      }
      #pragma unroll
      for (int m = 1; m < 16; m <<= 1){
        svr[0] += __shfl_xor(svr[0], m);
        svr[1] += __shfl_xor(svr[1], m);
        svr[2] += __shfl_xor(svr[2], m);
        svr[3] += __shfl_xor(svr[3], m);
      }
      if (lr == 0){
        sRed[wv][16*mt + 4*lg + 0] = svr[0];
        sRed[wv][16*mt + 4*lg + 1] = svr[1];
        sRed[wv][16*mt + 4*lg + 2] = svr[2];
        sRed[wv][16*mt + 4*lg + 3] = svr[3];
      }
    }
  }
  __syncthreads();   // g2 plane complete before bwd reads it
  if (tid < 64)
    sdf_out[q0+tid] = b3[0] + sRed[0][tid] + sRed[1][tid] + sRed[2][tid] + sRed[3][tid];

  // ---- backward (MFMA, swapped, hi-only): D[k][p] = sum_n W2hi[k][n]*g2hi[p][n]
  f32x4 acc2[4][2];   // [pt][t]: k = kb + 16*t + 4*lg + r, p = 16*pt + lr
  #pragma unroll
  for (int pt = 0; pt < 4; pt++){
    acc2[pt][0] = splat4(0.0f);
    acc2[pt][1] = splat4(0.0f);
  }
  #pragma unroll
  for (int kcn = 0; kcn < 4; kcn++){
    frag_u ah0, ah1;
    const int f0 = ((kcn*8 + 2*wv + 0)*64 + l)*8;
    const int f1 = ((kcn*8 + 2*wv + 1)*64 + l)*8;
    ah0.q = *(const uint32x4*)(w2tfh + f0);
    ah1.q = *(const uint32x4*)(w2tfh + f1);
    const int nn = 32*kcn + 8*lg;
    #pragma unroll
    for (int pt = 0; pt < 4; pt++){
      frag_u bh;
      bh.q = *(const uint32x4*)&sHi[SW(16*pt + lr, nn)];
      acc2[pt][0] = __builtin_amdgcn_mfma_f32_16x16x32_bf16(ah0.v, bh.v, acc2[pt][0], 0,0,0);
      acc2[pt][1] = __builtin_amdgcn_mfma_f32_16x16x32_bf16(ah1.v, bh.v, acc2[pt][1], 0,0,0);
    }
  }

  // ---- bwd epilogue: dp1 = dh1*sg(pre1); grad = W1 @ dp1, reduce over lg
  {
    float w1a[2][4], w1b[2][4], w1c[2][4], b1v[2][4];
    #pragma unroll
    for (int t = 0; t < 2; t++)
      #pragma unroll
      for (int r = 0; r < 4; r++){
        int k = kb + 16*t + 4*lg + r;
        w1a[t][r] = W1[k]; w1b[t][r] = W1[HID+k]; w1c[t][r] = W1[2*HID+k];
        b1v[t][r] = b1[k];
      }
    #pragma unroll
    for (int pt = 0; pt < 4; pt++){
      const int p = 16*pt + lr;
      const float xx = sPts[p][0], xy = sPts[p][1], xz = sPts[p][2];
      float gx = 0.f, gy = 0.f, gz = 0.f;
      #pragma unroll
      for (int t = 0; t < 2; t++){
        #pragma unroll
        for (int r = 0; r < 4; r++){
          float pre1 = fmaf(xx, w1a[t][r], fmaf(xy, w1b[t][r], fmaf(xz, w1c[t][r], b1v[t][r])));
          float dp = acc2[pt][t][r] * sg_fast(pre1);
          gx = fmaf(w1a[t][r], dp, gx);
          gy = fmaf(w1b[t][r], dp, gy);
          gz = fmaf(w1c[t][r], dp, gz);
        }
      }
      gx += __shfl_xor(gx, 16); gx += __shfl_xor(gx, 32);
      gy += __shfl_xor(gy, 16); gy += __shfl_xor(gy, 32);
      gz += __shfl_xor(gz, 16); gz += __shfl_xor(gz, 32);
      if (lg == 0){
        sGrad[wv][p][0] = gx; sGrad[wv][p][1] = gy; sGrad[wv][p][2] = gz;
      }
    }
  }
  __syncthreads();
  if (tid < 64){
    #pragma unroll
    for (int c = 0; c < 3; c++)
      grad_out[(q0+tid)*3+c] =
        sGrad[0][tid][c] + sGrad[1][tid][c] + sGrad[2][tid][c] + sGrad[3][tid][c];
  }
}

// ---------------------------------------------------------------- upsample (one wave per ray)
__global__ __launch_bounds__(64) void k_upsample(
      const float* __restrict__ rays_o, const float* __restrict__ rays_d,
      float* __restrict__ z_buf, float* __restrict__ sdf_buf,
      float* __restrict__ pts_new, int* __restrict__ slots,
      int S, float inv_s, int last){
  __shared__ float z[128], sd[128], rad[128], cosv[128], alf[128], wv[128], cdf[129], nz[16];
  __shared__ int slt[16];
  const int ray = blockIdx.x;
  const int l   = threadIdx.x;
  const float ox = rays_o[ray*3], oy = rays_o[ray*3+1], oz = rays_o[ray*3+2];
  const float dx = rays_d[ray*3], dy = rays_d[ray*3+1], dz = rays_d[ray*3+2];
  for (int j = l; j < S; j += 64){
    float zz = z_buf[ray*128+j];
    z[j]  = zz;
    sd[j] = sdf_buf[ray*128+j];
    float px = ox+dx*zz, py = oy+dy*zz, pz = oz+dz*zz;
    rad[j] = sqrtf(px*px + py*py + pz*pz);
  }
  __syncthreads();
  for (int j = l; j < S-1; j += 64)
    cosv[j] = (sd[j+1]-sd[j]) / (z[j+1]-z[j] + 1e-5f);
  __syncthreads();
  for (int j = l; j < S-1; j += 64){
    float cv = fminf((j > 0) ? cosv[j-1] : 0.0f, cosv[j]);
    cv = fminf(fmaxf(cv, -1000.0f), 0.0f);
    float inside = (rad[j] < 1.0f || rad[j+1] < 1.0f) ? 1.0f : 0.0f;
    cv *= inside;
    float mid  = 0.5f*(sd[j]+sd[j+1]);
    float dist = z[j+1]-z[j];
    float e = sg_f((mid - cv*dist*0.5f)*inv_s);
    float f = sg_f((mid + cv*dist*0.5f)*inv_s);
    alf[j] = (e - f + 1e-5f) / (e + 1e-5f);
  }
  __syncthreads();
  if (l == 0){
    float T = 1.0f, wsum = 0.0f;
    for (int j = 0; j < S-1; j++){
      float w = alf[j]*T + 1e-5f;   // weights = alpha*trans + 1e-5
      wv[j] = w; wsum += w;
      T *= (1.0f - alf[j] + 1e-7f);
    }
    cdf[0] = 0.0f;
    float c = 0.0f;
    for (int j = 0; j < S-1; j++){ c += wv[j]/wsum; cdf[j+1] = c; }
  }
  __syncthreads();
  if (l < 16){
    float u = 0.03125f + 0.0625f*(float)l;   // linspace(1/32, 31/32, 16)
    int idx = 0;
    while (idx < S && cdf[idx] <= u) idx++;  // searchsorted side='right'
    int below = idx - 1; if (below < 0) below = 0;
    int above = (idx < S-1) ? idx : (S-1);
    float cb = cdf[below], ca = cdf[above];
    float den = ca - cb; if (den < 1e-5f) den = 1.0f;
    float t = (u - cb) / den;
    nz[l] = z[below] + t*(z[above] - z[below]);
  }
  __syncthreads();
  if (l == 0){
    // stable in-place merge from the back (old-before-new on ties)
    int i = S-1, j = 15;
    for (int dst = S+15; dst >= 0; --dst){
      bool takeOld = (j < 0) || (i >= 0 && z[i] > nz[j]);
      if (takeOld){ z[dst] = z[i]; sd[dst] = sd[i]; i--; }
      else        { z[dst] = nz[j]; slt[j] = dst; j--; }
    }
  }
  __syncthreads();
  for (int j = l; j < S+16; j += 64){
    z_buf[ray*128+j]  = z[j];
    sdf_buf[ray*128+j] = sd[j];
  }
  if (!last && l < 16){
    slots[ray*16+l] = slt[l];
    float zz = nz[l];
    pts_new[(ray*16+l)*3+0] = ox + dx*zz;
    pts_new[(ray*16+l)*3+1] = oy + dy*zz;
    pts_new[(ray*16+l)*3+2] = oz + dz*zz;
  }
}

// ---------------------------------------------------------------- render (one WAVE per ray)
// PASS-VALIDATED in round 8. Lane l handles samples {2l, 2l+1}; transmittance
// via shfl_up product scan; depth via wave reduce.
__global__ __launch_bounds__(64) void k_render(
    const float* __restrict__ z_buf, const float* __restrict__ sdf_mid,
    const float* __restrict__ rays_d, const float* __restrict__ grad,
    const float* __restrict__ variance, float* __restrict__ depth_out){
  const int ray = blockIdx.x;
  const int l   = threadIdx.x;
  float inv_s = expf(10.0f * variance[0]);
  inv_s = fminf(fmaxf(inv_s, 1e-6f), 1e6f);
  const float dx = rays_d[ray*3], dy = rays_d[ray*3+1], dz = rays_d[ray*3+2];
  const int i0 = ray*128 + 2*l, i1 = i0 + 1;
  const float z0 = z_buf[i0], z1 = z_buf[i1];
  const float zn1 = __shfl_down(z0, 1);              // z[2l+2] from lane l+1
  const float d0 = z1 - z0;
  const float d1 = (l < 63) ? (zn1 - z1) : 0.03125f;
  float a0, a1;
  {
    float sdf = sdf_mid[i0];
    float gx = grad[i0*3], gy = grad[i0*3+1], gz = grad[i0*3+2];
    float tc = dx*gx + dy*gy + dz*gz;
    float ic = -fmaxf(0.5f - 0.5f*tc, 0.0f);
    float e = sg_fast((sdf - ic*d0*0.5f)*inv_s);
    float f = sg_fast((sdf + ic*d0*0.5f)*inv_s);
    a0 = fminf(fmaxf((e - f + 1e-5f) / (e + 1e-5f), 0.0f), 1.0f);
  }
  {
    float sdf = sdf_mid[i1];
    float gx = grad[i1*3], gy = grad[i1*3+1], gz = grad[i1*3+2];
    float tc = dx*gx + dy*gy + dz*gz;
    float ic = -fmaxf(0.5f - 0.5f*tc, 0.0f);
    float e = sg_fast((sdf - ic*d1*0.5f)*inv_s);
    float f = sg_fast((sdf + ic*d1*0.5f)*inv_s);
    a1 = fminf(fmaxf((e - f + 1e-5f) / (e + 1e-5f), 0.0f), 1.0f);
  }
  const float f0 = 1.0f - a0 + 1e-7f;
  const float f1 = 1.0f - a1 + 1e-7f;
  float incl = f0 * f1;
  #pragma unroll
  for (int off = 1; off < 64; off <<= 1){
    float t = __shfl_up(incl, off);
    if (l >= off) incl *= t;
  }
  float P = __shfl_up(incl, 1);        // T at sample 2l
  if (l == 0) P = 1.0f;
  float part = P * (a0*z0 + f0*a1*z1); // a0*T(2l)*z0 + a1*T(2l+1)*z1
  #pragma unroll
  for (int m = 1; m < 64; m <<= 1) part += __shfl_xor(part, m);
  if (l == 0) depth_out[ray] = part;
}

// ---------------------------------------------------------------- launcher
extern "C" void kernel_launch(void* const* d_in, const int* in_sizes, int n_in,
                              void* d_out, int out_size, void* d_ws, size_t ws_size,
                              hipStream_t stream){
  (void)in_sizes; (void)n_in; (void)out_size; (void)ws_size;
  const float* rays_o = (const float*)d_in[0];
  const float* rays_d = (const float*)d_in[1];
  const float* nearv  = (const float*)d_in[2];
  const float* farv   = (const float*)d_in[3];
  const float* W1 = (const float*)d_in[4];
  const float* b1 = (const float*)d_in[5];
  const float* W2 = (const float*)d_in[6];
  const float* b2 = (const float*)d_in[7];
  const float* W3 = (const float*)d_in[8];
  const float* b3 = (const float*)d_in[9];
  const float* variance = (const float*)d_in[10];

  // Workspace layout: within round-0's proven footprint (6,619,136 B).
  float* ws      = (float*)d_ws;
  float* z_buf   = ws;                    // [0,       524288)
  float* sdf_buf = ws + 524288;           // [524288,  1048576)
  float* sdf_tmp = ws + 1048576;          // [1048576, 1572864)
  int*   slots   = (int*)(ws + 1589248);  // [1589248, 1654784) as ints
  // 2-way fwd + bwd(A-side) fragment tables alias sdf_buf — created AFTER the
  // upsample loop, when sdf_buf is dead (round-4/6/7/8 validated placement).
  unsigned short* w2fh  = (unsigned short*)(ws + 524288);  // [524288, 532480)
  unsigned short* w2fl  = w2fh + 16384;                    // [532480, 540672)
  unsigned short* w2tfh = w2fh + 32768;                    // [540672, 548864)
  unsigned short* w2tfl = w2fh + 49152;                    // [548864, 557056)
  // 3-way fwd fragments live in the upper (unused) half of sdf_tmp.
  unsigned short* w2h3 = (unsigned short*)(ws + 1310720); // [1310720, 1318912)
  unsigned short* w2m3 = w2h3 + 16384;                    // [1318912, 1327104)
  unsigned short* w2l3 = w2h3 + 32768;                    // [1327104, 1335296)

  float* out       = (float*)d_out;
  float* depth_out = out;
  float* grad_out  = out + NRAYS;         // 524288*3 floats
  float* pts       = grad_out;            // pts staging aliases grad region

  k_make_frags3<<<dim3(8), dim3(256), 0, stream>>>(W2, w2h3, w2m3, w2l3);
  k_init<<<dim3(1024), dim3(256), 0, stream>>>(rays_o, rays_d, nearv, farv, z_buf, pts);
  // mode 1: write sdf directly into sdf_buf ray-major (replaces k_scatter_init)
  k_mlp_fwd_t<<<dim3(4096), dim3(256), 0, stream>>>(pts, W1,b1,b2,W3,b3,
                                                    w2h3,w2m3,w2l3, sdf_buf, nullptr, 1);

  for (int i = 0; i < 4; i++){
    int S = 64 + 16*i;
    float inv_s = (float)(64 << i);
    int last = (i == 3) ? 1 : 0;
    k_upsample<<<dim3(4096), dim3(64), 0, stream>>>(rays_o, rays_d, z_buf, sdf_buf,
                                                    pts, slots, S, inv_s, last);
    if (!last){
      // mode 2: slot-scatter into sdf_buf (replaces k_scatter_new)
      k_mlp_fwd_t<<<dim3(1024), dim3(256), 0, stream>>>(pts, W1,b1,b2,W3,b3,
                                                        w2h3,w2m3,w2l3, sdf_buf, slots, 2);
    }
  }

  // sdf_buf is dead from here on — safe to overwrite with fragments.
  k_make_frags<<<dim3(16), dim3(256), 0, stream>>>(W2, w2fh, w2fl, w2tfh, w2tfl);
  k_mlp_bwd<<<dim3(8192), dim3(256), 0, stream>>>(z_buf, rays_o, rays_d,
                                                  W1,b1,b2,W3,b3,
                                                  w2fh,w2fl,w2tfh, sdf_tmp, grad_out);
  k_render<<<dim3(4096), dim3(64), 0, stream>>>(z_buf, sdf_tmp, rays_d, grad_out,
                                                variance, depth_out);
}

// Round 10
// 540.783 us; speedup vs baseline: 2.8548x; 1.0072x over previous
//
#include <hip/hip_runtime.h>
#include <math.h>

#define HID 128
#define NRAYS 4096
#define TP 64   // points per MLP tile (one per lane)

typedef __bf16 bf16x8 __attribute__((ext_vector_type(8)));
typedef float f32x4 __attribute__((ext_vector_type(4)));
typedef unsigned int uint32x4 __attribute__((ext_vector_type(4)));

union frag_u { bf16x8 v; uint32x4 q; };

__device__ __forceinline__ unsigned f2bf(float f){   // fp32 -> bf16 bits, RNE (prep kernels)
  unsigned u = __float_as_uint(f);
  u += 0x7FFFu + ((u >> 16) & 1u);
  return u >> 16;
}
__device__ __forceinline__ float bf2f(unsigned h){
  return __uint_as_float(h << 16);
}
__device__ __forceinline__ unsigned short bfc(float f){  // native cast (v_cvt_*bf16, RNE)
  union { __bf16 b; unsigned short u; } c;
  c.b = (__bf16)f;
  return c.u;
}
__device__ __forceinline__ float sp_fast(float x){   // softplus, v_exp/v_log (~4e-7 abs)
  float e = __expf(-fabsf(x));
  return fmaxf(x, 0.0f) + __logf(1.0f + e);
}
__device__ __forceinline__ float sg_fast(float x){   // sigmoid, fast
  float e = __expf(-fabsf(x));
  float r = __builtin_amdgcn_rcpf(1.0f + e);
  return (x >= 0.0f ? 1.0f : e) * r;
}
__device__ __forceinline__ float sg_f(float x){      // sigmoid, libm-precision (upsample)
  return 1.0f / (1.0f + expf(-x));
}
__device__ __forceinline__ f32x4 splat4(float x){
  f32x4 v = {x, x, x, x};
  return v;
}

// Swizzled LDS index (ushort units) for a [64][128] bf16 plane.
// byte ^= ((row&7)<<4)  ->  ushort idx ^= ((row&7)<<3). Keeps 16B alignment.
#define SW(p,k) ((((p)*HID) + (k)) ^ (((p)&7)<<3))

// ---------------------------------------------------------------- W2 fragment prep (2-way x 2 layouts)
// frag f = kc*8 + tg; element: contraction a = 32*kc + 8*(lane>>4)+e,
// output b = 16*tg + (lane&15). Stored at [(f*64+lane)*8 + e].
// which=0: v = W2[a*HID+b] -> B-operand for fwd (B[k][n], col=n).
// which=1: v = W2[b*HID+a] -> A-operand for swapped bwd (A[k][n]=W2[k][n], row=k).
__global__ void k_make_frags(const float* __restrict__ W2,
    unsigned short* __restrict__ w2fh,  unsigned short* __restrict__ w2fl,
    unsigned short* __restrict__ w2tfh, unsigned short* __restrict__ w2tfl){
  int idx = blockIdx.x*256 + threadIdx.x;
  if (idx >= 4096) return;
  int which = idx >> 11;
  int f    = (idx >> 6) & 31;
  int lane = idx & 63;
  int kc = f >> 3, tg = f & 7;
  int lg = lane >> 4, lr = lane & 15;
  unsigned short* dh = which ? w2tfh : w2fh;
  unsigned short* dl = which ? w2tfl : w2fl;
  int base = (f*64 + lane)*8;
  #pragma unroll
  for (int e = 0; e < 8; e++){
    int a = 32*kc + 8*lg + e;      // contraction index
    int b = 16*tg + lr;            // output index (fwd: n / bwd: k row)
    float v = which ? W2[b*HID + a] : W2[a*HID + b];
    unsigned hi = f2bf(v);
    dh[base+e] = (unsigned short)hi;
    dl[base+e] = (unsigned short)f2bf(v - bf2f(hi));
  }
}

// ---------------------------------------------------------------- W2 fwd-fragment prep (3-way, precision fwd)
// Triple-bf16 split: v = hi + mid + lo to ~2^-27 relative. Same fragment order.
__global__ void k_make_frags3(const float* __restrict__ W2,
    unsigned short* __restrict__ dh, unsigned short* __restrict__ dm,
    unsigned short* __restrict__ dl){
  int idx = blockIdx.x*256 + threadIdx.x;
  if (idx >= 2048) return;
  int f    = idx >> 6;             // 0..31
  int lane = idx & 63;
  int kc = f >> 3, tg = f & 7;
  int lg = lane >> 4, lr = lane & 15;
  int base = (f*64 + lane)*8;
  #pragma unroll
  for (int e = 0; e < 8; e++){
    int a = 32*kc + 8*lg + e;      // contraction index k
    int b = 16*tg + lr;            // output index n
    float v = W2[a*HID + b];
    unsigned hi = f2bf(v);
    float rm = v - bf2f(hi);
    unsigned md = f2bf(rm);
    dh[base+e] = (unsigned short)hi;
    dm[base+e] = (unsigned short)md;
    dl[base+e] = (unsigned short)f2bf(rm - bf2f(md));
  }
}

// ---------------------------------------------------------------- MLP forward, MFMA 6-term
// PASS-VALIDATED structure (rounds 6-9). Feeds the upsample cdf; triple-bf16
// RNE split keeps pre2 error ~1e-6. This round: native-cast splits (cvt_pk)
// and mode-1 fused k_init (z from near/far inline; writes z_buf; no pts read).
// mode 0: sdf_out[q0+tid]; mode 1: ray-major sdf_out[ray*128+s]; mode 2:
// sdf_out[(p>>4)*128 + slots[p]].
__global__ __launch_bounds__(256, 3) void k_mlp_fwd_t(
    const float* __restrict__ pts,
    const float* __restrict__ rays_o, const float* __restrict__ rays_d,
    const float* __restrict__ nearv, const float* __restrict__ farv,
    float* __restrict__ z_buf,
    const float* __restrict__ W1, const float* __restrict__ b1,
    const float* __restrict__ b2,
    const float* __restrict__ W3, const float* __restrict__ b3,
    const unsigned short* __restrict__ w2h, const unsigned short* __restrict__ w2m,
    const unsigned short* __restrict__ w2l,
    float* __restrict__ sdf_out, const int* __restrict__ slots, int mode)
{
  __shared__ unsigned short sHi[64*HID];   // 16 KB each
  __shared__ unsigned short sMi[64*HID];
  __shared__ unsigned short sLo[64*HID];
  __shared__ float sRed[4][64];

  const int tid = threadIdx.x;
  const int l   = tid & 63;
  const int wv  = __builtin_amdgcn_readfirstlane(tid >> 6);
  const int lg  = l >> 4;
  const int lr  = l & 15;
  const int q0  = blockIdx.x * 64;
  const int kb  = 32*wv;

  float x0, x1, x2;
  if (mode == 1){
    // fused k_init: ray = blockIdx, sample j = l (64 init samples per ray)
    const int ray = blockIdx.x;
    float nr = nearv[ray];
    float z  = nr + (farv[ray] - nr) * ((float)l / 63.0f);
    x0 = rays_o[ray*3+0] + rays_d[ray*3+0]*z;
    x1 = rays_o[ray*3+1] + rays_d[ray*3+1]*z;
    x2 = rays_o[ray*3+2] + rays_d[ray*3+2]*z;
    if (wv == 0) z_buf[ray*128 + l] = z;
  } else {
    x0 = pts[(q0+l)*3+0];
    x1 = pts[(q0+l)*3+1];
    x2 = pts[(q0+l)*3+2];
  }

  // ---- layer 1: point l, k in wave's 32-slice; fast softplus, 3-way native split
  #pragma unroll
  for (int g = 0; g < 4; g++){
    unsigned hw[4], mw[4], lw[4];
    #pragma unroll
    for (int e2 = 0; e2 < 4; e2++){
      unsigned short hpk[2], mpk[2], lpk[2];
      #pragma unroll
      for (int t = 0; t < 2; t++){
        int k = kb + 8*g + 2*e2 + t;
        float pre = b1[k];
        pre = fmaf(x0, W1[k],       pre);
        pre = fmaf(x1, W1[HID+k],   pre);
        pre = fmaf(x2, W1[2*HID+k], pre);
        float h = sp_fast(pre);
        unsigned short hh = bfc(h);
        float rm = h - bf2f(hh);
        unsigned short mm = bfc(rm);
        hpk[t] = hh; mpk[t] = mm;
        lpk[t] = bfc(rm - bf2f(mm));
      }
      hw[e2] = (unsigned)hpk[0] | ((unsigned)hpk[1] << 16);
      mw[e2] = (unsigned)mpk[0] | ((unsigned)mpk[1] << 16);
      lw[e2] = (unsigned)lpk[0] | ((unsigned)lpk[1] << 16);
    }
    uint32x4 hq = {hw[0], hw[1], hw[2], hw[3]};
    uint32x4 mq = {mw[0], mw[1], mw[2], mw[3]};
    uint32x4 lq = {lw[0], lw[1], lw[2], lw[3]};
    *(uint32x4*)&sHi[SW(l, kb + 8*g)] = hq;
    *(uint32x4*)&sMi[SW(l, kb + 8*g)] = mq;
    *(uint32x4*)&sLo[SW(l, kb + 8*g)] = lq;
  }
  __syncthreads();

  // ---- layer 2: pre2[p][n] via 6-term MFMA, split accumulators
  f32x4 acc[4][2], accC[4][2];
  {
    const float b2a = b2[kb + lr];
    const float b2b = b2[kb + 16 + lr];
    #pragma unroll
    for (int mt = 0; mt < 4; mt++){
      acc[mt][0]  = splat4(b2a);
      acc[mt][1]  = splat4(b2b);
      accC[mt][0] = splat4(0.0f);
      accC[mt][1] = splat4(0.0f);
    }
  }
  #pragma unroll
  for (int kc = 0; kc < 4; kc++){
    frag_u bh0, bm0, bl0, bh1, bm1, bl1;
    const int f0 = ((kc*8 + 2*wv + 0)*64 + l)*8;
    const int f1 = ((kc*8 + 2*wv + 1)*64 + l)*8;
    bh0.q = *(const uint32x4*)(w2h + f0);
    bm0.q = *(const uint32x4*)(w2m + f0);
    bl0.q = *(const uint32x4*)(w2l + f0);
    bh1.q = *(const uint32x4*)(w2h + f1);
    bm1.q = *(const uint32x4*)(w2m + f1);
    bl1.q = *(const uint32x4*)(w2l + f1);
    const int kk = 32*kc + 8*lg;
    #pragma unroll
    for (int mt = 0; mt < 4; mt++){
      frag_u ah, am, al;
      ah.q = *(const uint32x4*)&sHi[SW(16*mt + lr, kk)];
      am.q = *(const uint32x4*)&sMi[SW(16*mt + lr, kk)];
      al.q = *(const uint32x4*)&sLo[SW(16*mt + lr, kk)];
      accC[mt][0] = __builtin_amdgcn_mfma_f32_16x16x32_bf16(ah.v, bl0.v, accC[mt][0], 0,0,0);
      accC[mt][0] = __builtin_amdgcn_mfma_f32_16x16x32_bf16(am.v, bm0.v, accC[mt][0], 0,0,0);
      accC[mt][0] = __builtin_amdgcn_mfma_f32_16x16x32_bf16(al.v, bh0.v, accC[mt][0], 0,0,0);
      accC[mt][0] = __builtin_amdgcn_mfma_f32_16x16x32_bf16(ah.v, bm0.v, accC[mt][0], 0,0,0);
      accC[mt][0] = __builtin_amdgcn_mfma_f32_16x16x32_bf16(am.v, bh0.v, accC[mt][0], 0,0,0);
      acc[mt][0]  = __builtin_amdgcn_mfma_f32_16x16x32_bf16(ah.v, bh0.v, acc[mt][0],  0,0,0);
      accC[mt][1] = __builtin_amdgcn_mfma_f32_16x16x32_bf16(ah.v, bl1.v, accC[mt][1], 0,0,0);
      accC[mt][1] = __builtin_amdgcn_mfma_f32_16x16x32_bf16(am.v, bm1.v, accC[mt][1], 0,0,0);
      accC[mt][1] = __builtin_amdgcn_mfma_f32_16x16x32_bf16(al.v, bh1.v, accC[mt][1], 0,0,0);
      accC[mt][1] = __builtin_amdgcn_mfma_f32_16x16x32_bf16(ah.v, bm1.v, accC[mt][1], 0,0,0);
      accC[mt][1] = __builtin_amdgcn_mfma_f32_16x16x32_bf16(am.v, bh1.v, accC[mt][1], 0,0,0);
      acc[mt][1]  = __builtin_amdgcn_mfma_f32_16x16x32_bf16(ah.v, bh1.v, acc[mt][1],  0,0,0);
    }
  }

  // ---- epilogue: sdf = b3 + sum sp(pre2)*W3 (validated reduce structure)
  {
    const float w3a = W3[kb + lr];
    const float w3b = W3[kb + 16 + lr];
    #pragma unroll
    for (int mt = 0; mt < 4; mt++){
      float svr[4];
      #pragma unroll
      for (int r = 0; r < 4; r++){
        float pa = acc[mt][0][r] + accC[mt][0][r];
        float pb = acc[mt][1][r] + accC[mt][1][r];
        svr[r] = sp_fast(pa)*w3a + sp_fast(pb)*w3b;
      }
      #pragma unroll
      for (int m = 1; m < 16; m <<= 1){
        svr[0] += __shfl_xor(svr[0], m);
        svr[1] += __shfl_xor(svr[1], m);
        svr[2] += __shfl_xor(svr[2], m);
        svr[3] += __shfl_xor(svr[3], m);
      }
      if (lr == 0){
        sRed[wv][16*mt + 4*lg + 0] = svr[0];
        sRed[wv][16*mt + 4*lg + 1] = svr[1];
        sRed[wv][16*mt + 4*lg + 2] = svr[2];
        sRed[wv][16*mt + 4*lg + 3] = svr[3];
      }
    }
  }
  __syncthreads();
  if (tid < 64){
    float sv = b3[0] + sRed[0][tid] + sRed[1][tid] + sRed[2][tid] + sRed[3][tid];
    if (mode == 0){
      sdf_out[q0 + tid] = sv;
    } else if (mode == 1){
      sdf_out[(q0 << 1) + tid] = sv;            // ray=q0/64 -> ray*128 + s
    } else {
      int p = q0 + tid;
      sdf_out[(p >> 4)*128 + slots[p]] = sv;    // ray-major slot scatter
    }
  }
}

// ---------------------------------------------------------------- MLP fwd+bwd, both MFMA
// PASS-VALIDATED in rounds 7-9. This round: native-cast splits (RNE, slightly
// tighter than r9's trunc) + shared exp between softplus/sigmoid in the fwd
// epilogue (saves 32 transcendentals/lane).
__global__ __launch_bounds__(256, 4) void k_mlp_bwd(
    const float* __restrict__ z_buf,
    const float* __restrict__ rays_o, const float* __restrict__ rays_d,
    const float* __restrict__ W1, const float* __restrict__ b1,
    const float* __restrict__ b2,
    const float* __restrict__ W3, const float* __restrict__ b3,
    const unsigned short* __restrict__ w2fh,  const unsigned short* __restrict__ w2fl,
    const unsigned short* __restrict__ w2tfh,
    float* __restrict__ sdf_out, float* __restrict__ grad_out)
{
  __shared__ unsigned short sHi[64*HID];   // 16 KB: h1 hi, then g2 hi
  __shared__ unsigned short sLo[64*HID];   // 16 KB: h1 lo (fwd 3-term only)
  __shared__ float sRed[4][64];            // sdf partials per wave
  __shared__ float sPts[64][4];            // x per point (for bwd recompute)
  __shared__ float sGrad[4][64][3];        // grad partials per wave

  const int tid = threadIdx.x;
  const int l   = tid & 63;
  const int wv  = __builtin_amdgcn_readfirstlane(tid >> 6);
  const int lg  = l >> 4;
  const int lr  = l & 15;
  const int q0  = blockIdx.x * 64;
  const int kb  = 32*wv;

  // ---- fused k_prep: mid-point pts from z_buf (ray uniform per block)
  const int ray = q0 >> 7;
  const int s   = (q0 & 127) + l;
  const float z  = z_buf[q0 + l];
  const float zn = z_buf[q0 + l + ((s < 127) ? 1 : 0)];
  const float d  = (s < 127) ? (zn - z) : 0.03125f;    // SAMPLE_DIST = 2/64
  const float midz = z + 0.5f*d;
  const float x0 = rays_o[ray*3+0] + rays_d[ray*3+0]*midz;
  const float x1 = rays_o[ray*3+1] + rays_d[ray*3+1]*midz;
  const float x2 = rays_o[ray*3+2] + rays_d[ray*3+2]*midz;
  if (wv == 0){ sPts[l][0] = x0; sPts[l][1] = x1; sPts[l][2] = x2; }

  // ---- layer 1: point l, k in [32wv, 32wv+32); bf16 hi/lo native split
  #pragma unroll
  for (int g = 0; g < 4; g++){
    unsigned hw[4], lw[4];
    #pragma unroll
    for (int e2 = 0; e2 < 4; e2++){
      unsigned short hpk[2], lpk[2];
      #pragma unroll
      for (int t = 0; t < 2; t++){
        int k = kb + 8*g + 2*e2 + t;
        float pre = b1[k];
        pre = fmaf(x0, W1[k],       pre);
        pre = fmaf(x1, W1[HID+k],   pre);
        pre = fmaf(x2, W1[2*HID+k], pre);
        float h = sp_fast(pre);
        unsigned short hh = bfc(h);
        hpk[t] = hh;
        lpk[t] = bfc(h - bf2f(hh));
      }
      hw[e2] = (unsigned)hpk[0] | ((unsigned)hpk[1] << 16);
      lw[e2] = (unsigned)lpk[0] | ((unsigned)lpk[1] << 16);
    }
    uint32x4 hq = {hw[0], hw[1], hw[2], hw[3]};
    uint32x4 lq = {lw[0], lw[1], lw[2], lw[3]};
    *(uint32x4*)&sHi[SW(l, kb + 8*g)] = hq;
    *(uint32x4*)&sLo[SW(l, kb + 8*g)] = lq;
  }
  __syncthreads();

  // ---- layer 2 forward (MFMA, validated): pre2[p][n], n in wave's 32-slice
  f32x4 acc[4][2];
  {
    const float b2a = b2[kb + lr];
    const float b2b = b2[kb + 16 + lr];
    #pragma unroll
    for (int mt = 0; mt < 4; mt++){
      acc[mt][0] = splat4(b2a);
      acc[mt][1] = splat4(b2b);
    }
  }
  #pragma unroll
  for (int kc = 0; kc < 4; kc++){
    frag_u bh0, bl0, bh1, bl1;
    const int f0 = ((kc*8 + 2*wv + 0)*64 + l)*8;
    const int f1 = ((kc*8 + 2*wv + 1)*64 + l)*8;
    bh0.q = *(const uint32x4*)(w2fh + f0);
    bl0.q = *(const uint32x4*)(w2fl + f0);
    bh1.q = *(const uint32x4*)(w2fh + f1);
    bl1.q = *(const uint32x4*)(w2fl + f1);
    const int kk = 32*kc + 8*lg;
    #pragma unroll
    for (int mt = 0; mt < 4; mt++){
      frag_u ah, al;
      ah.q = *(const uint32x4*)&sHi[SW(16*mt + lr, kk)];
      al.q = *(const uint32x4*)&sLo[SW(16*mt + lr, kk)];
      acc[mt][0] = __builtin_amdgcn_mfma_f32_16x16x32_bf16(ah.v, bh0.v, acc[mt][0], 0,0,0);
      acc[mt][0] = __builtin_amdgcn_mfma_f32_16x16x32_bf16(ah.v, bl0.v, acc[mt][0], 0,0,0);
      acc[mt][0] = __builtin_amdgcn_mfma_f32_16x16x32_bf16(al.v, bh0.v, acc[mt][0], 0,0,0);
      acc[mt][1] = __builtin_amdgcn_mfma_f32_16x16x32_bf16(ah.v, bh1.v, acc[mt][1], 0,0,0);
      acc[mt][1] = __builtin_amdgcn_mfma_f32_16x16x32_bf16(ah.v, bl1.v, acc[mt][1], 0,0,0);
      acc[mt][1] = __builtin_amdgcn_mfma_f32_16x16x32_bf16(al.v, bh1.v, acc[mt][1], 0,0,0);
    }
  }
  __syncthreads();   // all waves done reading h planes; g2 may now overwrite sHi

  // ---- fwd epilogue: sdf partials + g2 hi-only into sHi (shared exp for sp/sg)
  {
    const float w3a = W3[kb + lr];
    const float w3b = W3[kb + 16 + lr];
    #pragma unroll
    for (int mt = 0; mt < 4; mt++){
      float svr[4];
      #pragma unroll
      for (int r = 0; r < 4; r++){
        float pa = acc[mt][0][r], pb = acc[mt][1][r];
        float ea = __expf(-fabsf(pa)), eb = __expf(-fabsf(pb));
        float ta = 1.0f + ea,          tb = 1.0f + eb;
        float spa = fmaxf(pa, 0.0f) + __logf(ta);
        float spb = fmaxf(pb, 0.0f) + __logf(tb);
        svr[r] = spa*w3a + spb*w3b;
        float sga = (pa >= 0.0f ? 1.0f : ea) * __builtin_amdgcn_rcpf(ta);
        float sgb = (pb >= 0.0f ? 1.0f : eb) * __builtin_amdgcn_rcpf(tb);
        int pr = 16*mt + 4*lg + r;                    // point (D-row, validated)
        sHi[SW(pr, kb + lr)]      = bfc(sga * w3a);
        sHi[SW(pr, kb + 16 + lr)] = bfc(sgb * w3b);
      }
      #pragma unroll
      for (int m = 1; m < 16; m <<= 1){
        svr[0] += __shfl_xor(svr[0], m);
        svr[1] += __shfl_xor(svr[1], m);
        svr[2] += __shfl_xor(svr[2], m);
        svr[3] += __shfl_xor(svr[3], m);
      }
      if (lr == 0){
        sRed[wv][16*mt + 4*lg + 0] = svr[0];
        sRed[wv][16*mt + 4*lg + 1] = svr[1];
        sRed[wv][16*mt + 4*lg + 2] = svr[2];
        sRed[wv][16*mt + 4*lg + 3] = svr[3];
      }
    }
  }
  __syncthreads();   // g2 plane complete before bwd reads it
  if (tid < 64)
    sdf_out[q0+tid] = b3[0] + sRed[0][tid] + sRed[1][tid] + sRed[2][tid] + sRed[3][tid];

  // ---- backward (MFMA, swapped, hi-only): D[k][p] = sum_n W2hi[k][n]*g2hi[p][n]
  f32x4 acc2[4][2];   // [pt][t]: k = kb + 16*t + 4*lg + r, p = 16*pt + lr
  #pragma unroll
  for (int pt = 0; pt < 4; pt++){
    acc2[pt][0] = splat4(0.0f);
    acc2[pt][1] = splat4(0.0f);
  }
  #pragma unroll
  for (int kcn = 0; kcn < 4; kcn++){
    frag_u ah0, ah1;
    const int f0 = ((kcn*8 + 2*wv + 0)*64 + l)*8;
    const int f1 = ((kcn*8 + 2*wv + 1)*64 + l)*8;
    ah0.q = *(const uint32x4*)(w2tfh + f0);
    ah1.q = *(const uint32x4*)(w2tfh + f1);
    const int nn = 32*kcn + 8*lg;
    #pragma unroll
    for (int pt = 0; pt < 4; pt++){
      frag_u bh;
      bh.q = *(const uint32x4*)&sHi[SW(16*pt + lr, nn)];
      acc2[pt][0] = __builtin_amdgcn_mfma_f32_16x16x32_bf16(ah0.v, bh.v, acc2[pt][0], 0,0,0);
      acc2[pt][1] = __builtin_amdgcn_mfma_f32_16x16x32_bf16(ah1.v, bh.v, acc2[pt][1], 0,0,0);
    }
  }

  // ---- bwd epilogue: dp1 = dh1*sg(pre1); grad = W1 @ dp1, reduce over lg
  {
    float w1a[2][4], w1b[2][4], w1c[2][4], b1v[2][4];
    #pragma unroll
    for (int t = 0; t < 2; t++)
      #pragma unroll
      for (int r = 0; r < 4; r++){
        int k = kb + 16*t + 4*lg + r;
        w1a[t][r] = W1[k]; w1b[t][r] = W1[HID+k]; w1c[t][r] = W1[2*HID+k];
        b1v[t][r] = b1[k];
      }
    #pragma unroll
    for (int pt = 0; pt < 4; pt++){
      const int p = 16*pt + lr;
      const float xx = sPts[p][0], xy = sPts[p][1], xz = sPts[p][2];
      float gx = 0.f, gy = 0.f, gz = 0.f;
      #pragma unroll
      for (int t = 0; t < 2; t++){
        #pragma unroll
        for (int r = 0; r < 4; r++){
          float pre1 = fmaf(xx, w1a[t][r], fmaf(xy, w1b[t][r], fmaf(xz, w1c[t][r], b1v[t][r])));
          float dp = acc2[pt][t][r] * sg_fast(pre1);
          gx = fmaf(w1a[t][r], dp, gx);
          gy = fmaf(w1b[t][r], dp, gy);
          gz = fmaf(w1c[t][r], dp, gz);
        }
      }
      gx += __shfl_xor(gx, 16); gx += __shfl_xor(gx, 32);
      gy += __shfl_xor(gy, 16); gy += __shfl_xor(gy, 32);
      gz += __shfl_xor(gz, 16); gz += __shfl_xor(gz, 32);
      if (lg == 0){
        sGrad[wv][p][0] = gx; sGrad[wv][p][1] = gy; sGrad[wv][p][2] = gz;
      }
    }
  }
  __syncthreads();
  if (tid < 64){
    #pragma unroll
    for (int c = 0; c < 3; c++)
      grad_out[(q0+tid)*3+c] =
        sGrad[0][tid][c] + sGrad[1][tid][c] + sGrad[2][tid][c] + sGrad[3][tid][c];
  }
}

// ---------------------------------------------------------------- upsample (one wave per ray)
__global__ __launch_bounds__(64) void k_upsample(
      const float* __restrict__ rays_o, const float* __restrict__ rays_d,
      float* __restrict__ z_buf, float* __restrict__ sdf_buf,
      float* __restrict__ pts_new, int* __restrict__ slots,
      int S, float inv_s, int last){
  __shared__ float z[128], sd[128], rad[128], cosv[128], alf[128], wv[128], cdf[129], nz[16];
  __shared__ int slt[16];
  const int ray = blockIdx.x;
  const int l   = threadIdx.x;
  const float ox = rays_o[ray*3], oy = rays_o[ray*3+1], oz = rays_o[ray*3+2];
  const float dx = rays_d[ray*3], dy = rays_d[ray*3+1], dz = rays_d[ray*3+2];
  for (int j = l; j < S; j += 64){
    float zz = z_buf[ray*128+j];
    z[j]  = zz;
    sd[j] = sdf_buf[ray*128+j];
    float px = ox+dx*zz, py = oy+dy*zz, pz = oz+dz*zz;
    rad[j] = sqrtf(px*px + py*py + pz*pz);
  }
  __syncthreads();
  for (int j = l; j < S-1; j += 64)
    cosv[j] = (sd[j+1]-sd[j]) / (z[j+1]-z[j] + 1e-5f);
  __syncthreads();
  for (int j = l; j < S-1; j += 64){
    float cv = fminf((j > 0) ? cosv[j-1] : 0.0f, cosv[j]);
    cv = fminf(fmaxf(cv, -1000.0f), 0.0f);
    float inside = (rad[j] < 1.0f || rad[j+1] < 1.0f) ? 1.0f : 0.0f;
    cv *= inside;
    float mid  = 0.5f*(sd[j]+sd[j+1]);
    float dist = z[j+1]-z[j];
    float e = sg_f((mid - cv*dist*0.5f)*inv_s);
    float f = sg_f((mid + cv*dist*0.5f)*inv_s);
    alf[j] = (e - f + 1e-5f) / (e + 1e-5f);
  }
  __syncthreads();
  if (l == 0){
    float T = 1.0f, wsum = 0.0f;
    for (int j = 0; j < S-1; j++){
      float w = alf[j]*T + 1e-5f;   // weights = alpha*trans + 1e-5
      wv[j] = w; wsum += w;
      T *= (1.0f - alf[j] + 1e-7f);
    }
    cdf[0] = 0.0f;
    float c = 0.0f;
    for (int j = 0; j < S-1; j++){ c += wv[j]/wsum; cdf[j+1] = c; }
  }
  __syncthreads();
  if (l < 16){
    float u = 0.03125f + 0.0625f*(float)l;   // linspace(1/32, 31/32, 16)
    int idx = 0;
    while (idx < S && cdf[idx] <= u) idx++;  // searchsorted side='right'
    int below = idx - 1; if (below < 0) below = 0;
    int above = (idx < S-1) ? idx : (S-1);
    float cb = cdf[below], ca = cdf[above];
    float den = ca - cb; if (den < 1e-5f) den = 1.0f;
    float t = (u - cb) / den;
    nz[l] = z[below] + t*(z[above] - z[below]);
  }
  __syncthreads();
  if (l == 0){
    // stable in-place merge from the back (old-before-new on ties)
    int i = S-1, j = 15;
    for (int dst = S+15; dst >= 0; --dst){
      bool takeOld = (j < 0) || (i >= 0 && z[i] > nz[j]);
      if (takeOld){ z[dst] = z[i]; sd[dst] = sd[i]; i--; }
      else        { z[dst] = nz[j]; slt[j] = dst; j--; }
    }
  }
  __syncthreads();
  for (int j = l; j < S+16; j += 64){
    z_buf[ray*128+j]  = z[j];
    sdf_buf[ray*128+j] = sd[j];
  }
  if (!last && l < 16){
    slots[ray*16+l] = slt[l];
    float zz = nz[l];
    pts_new[(ray*16+l)*3+0] = ox + dx*zz;
    pts_new[(ray*16+l)*3+1] = oy + dy*zz;
    pts_new[(ray*16+l)*3+2] = oz + dz*zz;
  }
}

// ---------------------------------------------------------------- render (one WAVE per ray)
// PASS-VALIDATED in rounds 8-9.
__global__ __launch_bounds__(64) void k_render(
    const float* __restrict__ z_buf, const float* __restrict__ sdf_mid,
    const float* __restrict__ rays_d, const float* __restrict__ grad,
    const float* __restrict__ variance, float* __restrict__ depth_out){
  const int ray = blockIdx.x;
  const int l   = threadIdx.x;
  float inv_s = expf(10.0f * variance[0]);
  inv_s = fminf(fmaxf(inv_s, 1e-6f), 1e6f);
  const float dx = rays_d[ray*3], dy = rays_d[ray*3+1], dz = rays_d[ray*3+2];
  const int i0 = ray*128 + 2*l, i1 = i0 + 1;
  const float z0 = z_buf[i0], z1 = z_buf[i1];
  const float zn1 = __shfl_down(z0, 1);              // z[2l+2] from lane l+1
  const float d0 = z1 - z0;
  const float d1 = (l < 63) ? (zn1 - z1) : 0.03125f;
  float a0, a1;
  {
    float sdf = sdf_mid[i0];
    float gx = grad[i0*3], gy = grad[i0*3+1], gz = grad[i0*3+2];
    float tc = dx*gx + dy*gy + dz*gz;
    float ic = -fmaxf(0.5f - 0.5f*tc, 0.0f);
    float e = sg_fast((sdf - ic*d0*0.5f)*inv_s);
    float f = sg_fast((sdf + ic*d0*0.5f)*inv_s);
    a0 = fminf(fmaxf((e - f + 1e-5f) / (e + 1e-5f), 0.0f), 1.0f);
  }
  {
    float sdf = sdf_mid[i1];
    float gx = grad[i1*3], gy = grad[i1*3+1], gz = grad[i1*3+2];
    float tc = dx*gx + dy*gy + dz*gz;
    float ic = -fmaxf(0.5f - 0.5f*tc, 0.0f);
    float e = sg_fast((sdf - ic*d1*0.5f)*inv_s);
    float f = sg_fast((sdf + ic*d1*0.5f)*inv_s);
    a1 = fminf(fmaxf((e - f + 1e-5f) / (e + 1e-5f), 0.0f), 1.0f);
  }
  const float f0 = 1.0f - a0 + 1e-7f;
  const float f1 = 1.0f - a1 + 1e-7f;
  float incl = f0 * f1;
  #pragma unroll
  for (int off = 1; off < 64; off <<= 1){
    float t = __shfl_up(incl, off);
    if (l >= off) incl *= t;
  }
  float P = __shfl_up(incl, 1);        // T at sample 2l
  if (l == 0) P = 1.0f;
  float part = P * (a0*z0 + f0*a1*z1); // a0*T(2l)*z0 + a1*T(2l+1)*z1
  #pragma unroll
  for (int m = 1; m < 64; m <<= 1) part += __shfl_xor(part, m);
  if (l == 0) depth_out[ray] = part;
}

// ---------------------------------------------------------------- launcher
extern "C" void kernel_launch(void* const* d_in, const int* in_sizes, int n_in,
                              void* d_out, int out_size, void* d_ws, size_t ws_size,
                              hipStream_t stream){
  (void)in_sizes; (void)n_in; (void)out_size; (void)ws_size;
  const float* rays_o = (const float*)d_in[0];
  const float* rays_d = (const float*)d_in[1];
  const float* nearv  = (const float*)d_in[2];
  const float* farv   = (const float*)d_in[3];
  const float* W1 = (const float*)d_in[4];
  const float* b1 = (const float*)d_in[5];
  const float* W2 = (const float*)d_in[6];
  const float* b2 = (const float*)d_in[7];
  const float* W3 = (const float*)d_in[8];
  const float* b3 = (const float*)d_in[9];
  const float* variance = (const float*)d_in[10];

  // Workspace layout: within round-0's proven footprint (6,619,136 B).
  float* ws      = (float*)d_ws;
  float* z_buf   = ws;                    // [0,       524288)
  float* sdf_buf = ws + 524288;           // [524288,  1048576)
  float* sdf_tmp = ws + 1048576;          // [1048576, 1572864)
  int*   slots   = (int*)(ws + 1589248);  // [1589248, 1654784) as ints
  // 2-way fwd + bwd(A-side) fragment tables alias sdf_buf — created AFTER the
  // upsample loop, when sdf_buf is dead (rounds 4-9 validated placement).
  unsigned short* w2fh  = (unsigned short*)(ws + 524288);  // [524288, 532480)
  unsigned short* w2fl  = w2fh + 16384;                    // [532480, 540672)
  unsigned short* w2tfh = w2fh + 32768;                    // [540672, 548864)
  unsigned short* w2tfl = w2fh + 49152;                    // [548864, 557056)
  // 3-way fwd fragments live in the upper (unused) half of sdf_tmp.
  unsigned short* w2h3 = (unsigned short*)(ws + 1310720); // [1310720, 1318912)
  unsigned short* w2m3 = w2h3 + 16384;                    // [1318912, 1327104)
  unsigned short* w2l3 = w2h3 + 32768;                    // [1327104, 1335296)

  float* out       = (float*)d_out;
  float* depth_out = out;
  float* grad_out  = out + NRAYS;         // 524288*3 floats
  float* pts       = grad_out;            // pts staging aliases grad region

  k_make_frags3<<<dim3(8), dim3(256), 0, stream>>>(W2, w2h3, w2m3, w2l3);
  // mode 1: fused k_init (z inline, z_buf written) + sdf ray-major into sdf_buf
  k_mlp_fwd_t<<<dim3(4096), dim3(256), 0, stream>>>(pts, rays_o, rays_d, nearv, farv,
                                                    z_buf, W1,b1,b2,W3,b3,
                                                    w2h3,w2m3,w2l3, sdf_buf, nullptr, 1);

  for (int i = 0; i < 4; i++){
    int S = 64 + 16*i;
    float inv_s = (float)(64 << i);
    int last = (i == 3) ? 1 : 0;
    k_upsample<<<dim3(4096), dim3(64), 0, stream>>>(rays_o, rays_d, z_buf, sdf_buf,
                                                    pts, slots, S, inv_s, last);
    if (!last){
      // mode 2: slot-scatter into sdf_buf (fused k_scatter_new)
      k_mlp_fwd_t<<<dim3(1024), dim3(256), 0, stream>>>(pts, rays_o, rays_d, nearv, farv,
                                                        z_buf, W1,b1,b2,W3,b3,
                                                        w2h3,w2m3,w2l3, sdf_buf, slots, 2);
    }
  }

  // sdf_buf is dead from here on — safe to overwrite with fragments.
  k_make_frags<<<dim3(16), dim3(256), 0, stream>>>(W2, w2fh, w2fl, w2tfh, w2tfl);
  k_mlp_bwd<<<dim3(8192), dim3(256), 0, stream>>>(z_buf, rays_o, rays_d,
                                                  W1,b1,b2,W3,b3,
                                                  w2fh,w2fl,w2tfh, sdf_tmp, grad_out);
  k_render<<<dim3(4096), dim3(64), 0, stream>>>(z_buf, sdf_tmp, rays_d, grad_out,
                                                variance, depth_out);
}

// Round 11
// 534.262 us; speedup vs baseline: 2.8896x; 1.0122x over previous
//
#include <hip/hip_runtime.h>
#include <math.h>

#define HID 128
#define NRAYS 4096
#define TP 64   // points per MLP tile (one per lane)

typedef __bf16 bf16x8 __attribute__((ext_vector_type(8)));
typedef float f32x4 __attribute__((ext_vector_type(4)));
typedef unsigned int uint32x4 __attribute__((ext_vector_type(4)));

union frag_u { bf16x8 v; uint32x4 q; };

__device__ __forceinline__ unsigned f2bf(float f){   // fp32 -> bf16 bits, RNE (prep kernels)
  unsigned u = __float_as_uint(f);
  u += 0x7FFFu + ((u >> 16) & 1u);
  return u >> 16;
}
__device__ __forceinline__ float bf2f(unsigned h){
  return __uint_as_float(h << 16);
}
__device__ __forceinline__ unsigned short bfc(float f){  // native cast (v_cvt_*bf16, RNE)
  union { __bf16 b; unsigned short u; } c;
  c.b = (__bf16)f;
  return c.u;
}
__device__ __forceinline__ float sp_fast(float x){   // softplus, v_exp/v_log (~4e-7 abs)
  float e = __expf(-fabsf(x));
  return fmaxf(x, 0.0f) + __logf(1.0f + e);
}
__device__ __forceinline__ float sg_fast(float x){   // sigmoid, fast
  float e = __expf(-fabsf(x));
  float r = __builtin_amdgcn_rcpf(1.0f + e);
  return (x >= 0.0f ? 1.0f : e) * r;
}
__device__ __forceinline__ float sg_f(float x){      // sigmoid, libm-precision (upsample)
  return 1.0f / (1.0f + expf(-x));
}
__device__ __forceinline__ f32x4 splat4(float x){
  f32x4 v = {x, x, x, x};
  return v;
}

// Swizzled LDS index (ushort units) for a [64][128] bf16 plane.
// byte ^= ((row&7)<<4)  ->  ushort idx ^= ((row&7)<<3). Keeps 16B alignment.
#define SW(p,k) ((((p)*HID) + (k)) ^ (((p)&7)<<3))

// ---------------------------------------------------------------- W2 fragment prep (2-way x 2 layouts)
// frag f = kc*8 + tg; element: contraction a = 32*kc + 8*(lane>>4)+e,
// output b = 16*tg + (lane&15). Stored at [(f*64+lane)*8 + e].
// which=0: v = W2[a*HID+b] -> B-operand for fwd (B[k][n], col=n).
// which=1: v = W2[b*HID+a] -> A-operand for swapped bwd (A[k][n]=W2[k][n], row=k).
__global__ void k_make_frags(const float* __restrict__ W2,
    unsigned short* __restrict__ w2fh,  unsigned short* __restrict__ w2fl,
    unsigned short* __restrict__ w2tfh, unsigned short* __restrict__ w2tfl){
  int idx = blockIdx.x*256 + threadIdx.x;
  if (idx >= 4096) return;
  int which = idx >> 11;
  int f    = (idx >> 6) & 31;
  int lane = idx & 63;
  int kc = f >> 3, tg = f & 7;
  int lg = lane >> 4, lr = lane & 15;
  unsigned short* dh = which ? w2tfh : w2fh;
  unsigned short* dl = which ? w2tfl : w2fl;
  int base = (f*64 + lane)*8;
  #pragma unroll
  for (int e = 0; e < 8; e++){
    int a = 32*kc + 8*lg + e;      // contraction index
    int b = 16*tg + lr;            // output index (fwd: n / bwd: k row)
    float v = which ? W2[b*HID + a] : W2[a*HID + b];
    unsigned hi = f2bf(v);
    dh[base+e] = (unsigned short)hi;
    dl[base+e] = (unsigned short)f2bf(v - bf2f(hi));
  }
}

// ---------------------------------------------------------------- W2 fwd-fragment prep (3-way, precision fwd)
// Triple-bf16 split: v = hi + mid + lo to ~2^-27 relative. Same fragment order.
__global__ void k_make_frags3(const float* __restrict__ W2,
    unsigned short* __restrict__ dh, unsigned short* __restrict__ dm,
    unsigned short* __restrict__ dl){
  int idx = blockIdx.x*256 + threadIdx.x;
  if (idx >= 2048) return;
  int f    = idx >> 6;             // 0..31
  int lane = idx & 63;
  int kc = f >> 3, tg = f & 7;
  int lg = lane >> 4, lr = lane & 15;
  int base = (f*64 + lane)*8;
  #pragma unroll
  for (int e = 0; e < 8; e++){
    int a = 32*kc + 8*lg + e;      // contraction index k
    int b = 16*tg + lr;            // output index n
    float v = W2[a*HID + b];
    unsigned hi = f2bf(v);
    float rm = v - bf2f(hi);
    unsigned md = f2bf(rm);
    dh[base+e] = (unsigned short)hi;
    dm[base+e] = (unsigned short)md;
    dl[base+e] = (unsigned short)f2bf(rm - bf2f(md));
  }
}

// ---------------------------------------------------------------- MLP forward, MFMA 6-term
// PASS-VALIDATED structure (rounds 6-10). Feeds the upsample cdf; triple-bf16
// RNE split keeps pre2 error ~1e-6. Round-10 form kept (native-cast splits +
// mode-1 fused k_init) — that half of round 10 gained ~21 us.
// mode 0: sdf_out[q0+tid]; mode 1: ray-major sdf_out[ray*128+s]; mode 2:
// sdf_out[(p>>4)*128 + slots[p]].
__global__ __launch_bounds__(256, 3) void k_mlp_fwd_t(
    const float* __restrict__ pts,
    const float* __restrict__ rays_o, const float* __restrict__ rays_d,
    const float* __restrict__ nearv, const float* __restrict__ farv,
    float* __restrict__ z_buf,
    const float* __restrict__ W1, const float* __restrict__ b1,
    const float* __restrict__ b2,
    const float* __restrict__ W3, const float* __restrict__ b3,
    const unsigned short* __restrict__ w2h, const unsigned short* __restrict__ w2m,
    const unsigned short* __restrict__ w2l,
    float* __restrict__ sdf_out, const int* __restrict__ slots, int mode)
{
  __shared__ unsigned short sHi[64*HID];   // 16 KB each
  __shared__ unsigned short sMi[64*HID];
  __shared__ unsigned short sLo[64*HID];
  __shared__ float sRed[4][64];

  const int tid = threadIdx.x;
  const int l   = tid & 63;
  const int wv  = __builtin_amdgcn_readfirstlane(tid >> 6);
  const int lg  = l >> 4;
  const int lr  = l & 15;
  const int q0  = blockIdx.x * 64;
  const int kb  = 32*wv;

  float x0, x1, x2;
  if (mode == 1){
    // fused k_init: ray = blockIdx, sample j = l (64 init samples per ray)
    const int ray = blockIdx.x;
    float nr = nearv[ray];
    float z  = nr + (farv[ray] - nr) * ((float)l / 63.0f);
    x0 = rays_o[ray*3+0] + rays_d[ray*3+0]*z;
    x1 = rays_o[ray*3+1] + rays_d[ray*3+1]*z;
    x2 = rays_o[ray*3+2] + rays_d[ray*3+2]*z;
    if (wv == 0) z_buf[ray*128 + l] = z;
  } else {
    x0 = pts[(q0+l)*3+0];
    x1 = pts[(q0+l)*3+1];
    x2 = pts[(q0+l)*3+2];
  }

  // ---- layer 1: point l, k in wave's 32-slice; fast softplus, 3-way native split
  #pragma unroll
  for (int g = 0; g < 4; g++){
    unsigned hw[4], mw[4], lw[4];
    #pragma unroll
    for (int e2 = 0; e2 < 4; e2++){
      unsigned short hpk[2], mpk[2], lpk[2];
      #pragma unroll
      for (int t = 0; t < 2; t++){
        int k = kb + 8*g + 2*e2 + t;
        float pre = b1[k];
        pre = fmaf(x0, W1[k],       pre);
        pre = fmaf(x1, W1[HID+k],   pre);
        pre = fmaf(x2, W1[2*HID+k], pre);
        float h = sp_fast(pre);
        unsigned short hh = bfc(h);
        float rm = h - bf2f(hh);
        unsigned short mm = bfc(rm);
        hpk[t] = hh; mpk[t] = mm;
        lpk[t] = bfc(rm - bf2f(mm));
      }
      hw[e2] = (unsigned)hpk[0] | ((unsigned)hpk[1] << 16);
      mw[e2] = (unsigned)mpk[0] | ((unsigned)mpk[1] << 16);
      lw[e2] = (unsigned)lpk[0] | ((unsigned)lpk[1] << 16);
    }
    uint32x4 hq = {hw[0], hw[1], hw[2], hw[3]};
    uint32x4 mq = {mw[0], mw[1], mw[2], mw[3]};
    uint32x4 lq = {lw[0], lw[1], lw[2], lw[3]};
    *(uint32x4*)&sHi[SW(l, kb + 8*g)] = hq;
    *(uint32x4*)&sMi[SW(l, kb + 8*g)] = mq;
    *(uint32x4*)&sLo[SW(l, kb + 8*g)] = lq;
  }
  __syncthreads();

  // ---- layer 2: pre2[p][n] via 6-term MFMA, split accumulators
  f32x4 acc[4][2], accC[4][2];
  {
    const float b2a = b2[kb + lr];
    const float b2b = b2[kb + 16 + lr];
    #pragma unroll
    for (int mt = 0; mt < 4; mt++){
      acc[mt][0]  = splat4(b2a);
      acc[mt][1]  = splat4(b2b);
      accC[mt][0] = splat4(0.0f);
      accC[mt][1] = splat4(0.0f);
    }
  }
  #pragma unroll
  for (int kc = 0; kc < 4; kc++){
    frag_u bh0, bm0, bl0, bh1, bm1, bl1;
    const int f0 = ((kc*8 + 2*wv + 0)*64 + l)*8;
    const int f1 = ((kc*8 + 2*wv + 1)*64 + l)*8;
    bh0.q = *(const uint32x4*)(w2h + f0);
    bm0.q = *(const uint32x4*)(w2m + f0);
    bl0.q = *(const uint32x4*)(w2l + f0);
    bh1.q = *(const uint32x4*)(w2h + f1);
    bm1.q = *(const uint32x4*)(w2m + f1);
    bl1.q = *(const uint32x4*)(w2l + f1);
    const int kk = 32*kc + 8*lg;
    #pragma unroll
    for (int mt = 0; mt < 4; mt++){
      frag_u ah, am, al;
      ah.q = *(const uint32x4*)&sHi[SW(16*mt + lr, kk)];
      am.q = *(const uint32x4*)&sMi[SW(16*mt + lr, kk)];
      al.q = *(const uint32x4*)&sLo[SW(16*mt + lr, kk)];
      accC[mt][0] = __builtin_amdgcn_mfma_f32_16x16x32_bf16(ah.v, bl0.v, accC[mt][0], 0,0,0);
      accC[mt][0] = __builtin_amdgcn_mfma_f32_16x16x32_bf16(am.v, bm0.v, accC[mt][0], 0,0,0);
      accC[mt][0] = __builtin_amdgcn_mfma_f32_16x16x32_bf16(al.v, bh0.v, accC[mt][0], 0,0,0);
      accC[mt][0] = __builtin_amdgcn_mfma_f32_16x16x32_bf16(ah.v, bm0.v, accC[mt][0], 0,0,0);
      accC[mt][0] = __builtin_amdgcn_mfma_f32_16x16x32_bf16(am.v, bh0.v, accC[mt][0], 0,0,0);
      acc[mt][0]  = __builtin_amdgcn_mfma_f32_16x16x32_bf16(ah.v, bh0.v, acc[mt][0],  0,0,0);
      accC[mt][1] = __builtin_amdgcn_mfma_f32_16x16x32_bf16(ah.v, bl1.v, accC[mt][1], 0,0,0);
      accC[mt][1] = __builtin_amdgcn_mfma_f32_16x16x32_bf16(am.v, bm1.v, accC[mt][1], 0,0,0);
      accC[mt][1] = __builtin_amdgcn_mfma_f32_16x16x32_bf16(al.v, bh1.v, accC[mt][1], 0,0,0);
      accC[mt][1] = __builtin_amdgcn_mfma_f32_16x16x32_bf16(ah.v, bm1.v, accC[mt][1], 0,0,0);
      accC[mt][1] = __builtin_amdgcn_mfma_f32_16x16x32_bf16(am.v, bh1.v, accC[mt][1], 0,0,0);
      acc[mt][1]  = __builtin_amdgcn_mfma_f32_16x16x32_bf16(ah.v, bh1.v, acc[mt][1],  0,0,0);
    }
  }

  // ---- epilogue: sdf = b3 + sum sp(pre2)*W3 (validated reduce structure)
  {
    const float w3a = W3[kb + lr];
    const float w3b = W3[kb + 16 + lr];
    #pragma unroll
    for (int mt = 0; mt < 4; mt++){
      float svr[4];
      #pragma unroll
      for (int r = 0; r < 4; r++){
        float pa = acc[mt][0][r] + accC[mt][0][r];
        float pb = acc[mt][1][r] + accC[mt][1][r];
        svr[r] = sp_fast(pa)*w3a + sp_fast(pb)*w3b;
      }
      #pragma unroll
      for (int m = 1; m < 16; m <<= 1){
        svr[0] += __shfl_xor(svr[0], m);
        svr[1] += __shfl_xor(svr[1], m);
        svr[2] += __shfl_xor(svr[2], m);
        svr[3] += __shfl_xor(svr[3], m);
      }
      if (lr == 0){
        sRed[wv][16*mt + 4*lg + 0] = svr[0];
        sRed[wv][16*mt + 4*lg + 1] = svr[1];
        sRed[wv][16*mt + 4*lg + 2] = svr[2];
        sRed[wv][16*mt + 4*lg + 3] = svr[3];
      }
    }
  }
  __syncthreads();
  if (tid < 64){
    float sv = b3[0] + sRed[0][tid] + sRed[1][tid] + sRed[2][tid] + sRed[3][tid];
    if (mode == 0){
      sdf_out[q0 + tid] = sv;
    } else if (mode == 1){
      sdf_out[(q0 << 1) + tid] = sv;            // ray=q0/64 -> ray*128 + s
    } else {
      int p = q0 + tid;
      sdf_out[(p >> 4)*128 + slots[p]] = sv;    // ray-major slot scatter
    }
  }
}

// ---------------------------------------------------------------- MLP fwd+bwd, both MFMA
// REVERTED to the round-9 version (measured 168 us, passing): trunc splits,
// separate sp_fast/sg_fast in the fwd epilogue. Round 10's shared-exp +
// native-cast variant regressed this kernel to 185 us (VALUBusy 88.5->81.5:
// serialized sp/sg dependency chains + cvt scheduling).
__global__ __launch_bounds__(256, 4) void k_mlp_bwd(
    const float* __restrict__ z_buf,
    const float* __restrict__ rays_o, const float* __restrict__ rays_d,
    const float* __restrict__ W1, const float* __restrict__ b1,
    const float* __restrict__ b2,
    const float* __restrict__ W3, const float* __restrict__ b3,
    const unsigned short* __restrict__ w2fh,  const unsigned short* __restrict__ w2fl,
    const unsigned short* __restrict__ w2tfh,
    float* __restrict__ sdf_out, float* __restrict__ grad_out)
{
  __shared__ unsigned short sHi[64*HID];   // 16 KB: h1 hi, then g2 hi
  __shared__ unsigned short sLo[64*HID];   // 16 KB: h1 lo (fwd 3-term only)
  __shared__ float sRed[4][64];            // sdf partials per wave
  __shared__ float sPts[64][4];            // x per point (for bwd recompute)
  __shared__ float sGrad[4][64][3];        // grad partials per wave

  const int tid = threadIdx.x;
  const int l   = tid & 63;
  const int wv  = __builtin_amdgcn_readfirstlane(tid >> 6);
  const int lg  = l >> 4;
  const int lr  = l & 15;
  const int q0  = blockIdx.x * 64;
  const int kb  = 32*wv;

  // ---- fused k_prep: mid-point pts from z_buf (ray uniform per block)
  const int ray = q0 >> 7;
  const int s   = (q0 & 127) + l;
  const float z  = z_buf[q0 + l];
  const float zn = z_buf[q0 + l + ((s < 127) ? 1 : 0)];
  const float d  = (s < 127) ? (zn - z) : 0.03125f;    // SAMPLE_DIST = 2/64
  const float midz = z + 0.5f*d;
  const float x0 = rays_o[ray*3+0] + rays_d[ray*3+0]*midz;
  const float x1 = rays_o[ray*3+1] + rays_d[ray*3+1]*midz;
  const float x2 = rays_o[ray*3+2] + rays_d[ray*3+2]*midz;
  if (wv == 0){ sPts[l][0] = x0; sPts[l][1] = x1; sPts[l][2] = x2; }

  // ---- layer 1: point l, k in [32wv, 32wv+32); bf16 hi/lo TRUNC split (h>=0)
  #pragma unroll
  for (int g = 0; g < 4; g++){
    unsigned hw[4], lw[4];
    #pragma unroll
    for (int e2 = 0; e2 < 4; e2++){
      unsigned hpk[2], lpk[2];
      #pragma unroll
      for (int t = 0; t < 2; t++){
        int k = kb + 8*g + 2*e2 + t;
        float pre = b1[k];
        pre = fmaf(x0, W1[k],       pre);
        pre = fmaf(x1, W1[HID+k],   pre);
        pre = fmaf(x2, W1[2*HID+k], pre);
        float h = sp_fast(pre);
        unsigned hi = __float_as_uint(h) >> 16;
        float rm = h - __uint_as_float(hi << 16);
        hpk[t] = hi;
        lpk[t] = __float_as_uint(rm) >> 16;
      }
      hw[e2] = hpk[0] | (hpk[1] << 16);
      lw[e2] = lpk[0] | (lpk[1] << 16);
    }
    uint32x4 hq = {hw[0], hw[1], hw[2], hw[3]};
    uint32x4 lq = {lw[0], lw[1], lw[2], lw[3]};
    *(uint32x4*)&sHi[SW(l, kb + 8*g)] = hq;
    *(uint32x4*)&sLo[SW(l, kb + 8*g)] = lq;
  }
  __syncthreads();

  // ---- layer 2 forward (MFMA, validated): pre2[p][n], n in wave's 32-slice
  f32x4 acc[4][2];
  {
    const float b2a = b2[kb + lr];
    const float b2b = b2[kb + 16 + lr];
    #pragma unroll
    for (int mt = 0; mt < 4; mt++){
      acc[mt][0] = splat4(b2a);
      acc[mt][1] = splat4(b2b);
    }
  }
  #pragma unroll
  for (int kc = 0; kc < 4; kc++){
    frag_u bh0, bl0, bh1, bl1;
    const int f0 = ((kc*8 + 2*wv + 0)*64 + l)*8;
    const int f1 = ((kc*8 + 2*wv + 1)*64 + l)*8;
    bh0.q = *(const uint32x4*)(w2fh + f0);
    bl0.q = *(const uint32x4*)(w2fl + f0);
    bh1.q = *(const uint32x4*)(w2fh + f1);
    bl1.q = *(const uint32x4*)(w2fl + f1);
    const int kk = 32*kc + 8*lg;
    #pragma unroll
    for (int mt = 0; mt < 4; mt++){
      frag_u ah, al;
      ah.q = *(const uint32x4*)&sHi[SW(16*mt + lr, kk)];
      al.q = *(const uint32x4*)&sLo[SW(16*mt + lr, kk)];
      acc[mt][0] = __builtin_amdgcn_mfma_f32_16x16x32_bf16(ah.v, bh0.v, acc[mt][0], 0,0,0);
      acc[mt][0] = __builtin_amdgcn_mfma_f32_16x16x32_bf16(ah.v, bl0.v, acc[mt][0], 0,0,0);
      acc[mt][0] = __builtin_amdgcn_mfma_f32_16x16x32_bf16(al.v, bh0.v, acc[mt][0], 0,0,0);
      acc[mt][1] = __builtin_amdgcn_mfma_f32_16x16x32_bf16(ah.v, bh1.v, acc[mt][1], 0,0,0);
      acc[mt][1] = __builtin_amdgcn_mfma_f32_16x16x32_bf16(ah.v, bl1.v, acc[mt][1], 0,0,0);
      acc[mt][1] = __builtin_amdgcn_mfma_f32_16x16x32_bf16(al.v, bh1.v, acc[mt][1], 0,0,0);
    }
  }
  __syncthreads();   // all waves done reading h planes; g2 may now overwrite sHi

  // ---- fwd epilogue: sdf partials + g2 = sg(pre2)*W3 hi-only (trunc) into sHi
  {
    const float w3a = W3[kb + lr];
    const float w3b = W3[kb + 16 + lr];
    #pragma unroll
    for (int mt = 0; mt < 4; mt++){
      float svr[4];
      #pragma unroll
      for (int r = 0; r < 4; r++){
        float pa = acc[mt][0][r], pb = acc[mt][1][r];
        svr[r] = sp_fast(pa)*w3a + sp_fast(pb)*w3b;
        int pr = 16*mt + 4*lg + r;                    // point (D-row, validated)
        float ga = sg_fast(pa) * w3a;
        float gb = sg_fast(pb) * w3b;
        sHi[SW(pr, kb + lr)]      = (unsigned short)(__float_as_uint(ga) >> 16);
        sHi[SW(pr, kb + 16 + lr)] = (unsigned short)(__float_as_uint(gb) >> 16);
      }
      #pragma unroll
      for (int m = 1; m < 16; m <<= 1){
        svr[0] += __shfl_xor(svr[0], m);
        svr[1] += __shfl_xor(svr[1], m);
        svr[2] += __shfl_xor(svr[2], m);
        svr[3] += __shfl_xor(svr[3], m);
      }
      if (lr == 0){
        sRed[wv][16*mt + 4*lg + 0] = svr[0];
        sRed[wv][16*mt + 4*lg + 1] = svr[1];
        sRed[wv][16*mt + 4*lg + 2] = svr[2];
        sRed[wv][16*mt + 4*lg + 3] = svr[3];
      }
    }
  }
  __syncthreads();   // g2 plane complete before bwd reads it
  if (tid < 64)
    sdf_out[q0+tid] = b3[0] + sRed[0][tid] + sRed[1][tid] + sRed[2][tid] + sRed[3][tid];

  // ---- backward (MFMA, swapped, hi-only): D[k][p] = sum_n W2hi[k][n]*g2hi[p][n]
  f32x4 acc2[4][2];   // [pt][t]: k = kb + 16*t + 4*lg + r, p = 16*pt + lr
  #pragma unroll
  for (int pt = 0; pt < 4; pt++){
    acc2[pt][0] = splat4(0.0f);
    acc2[pt][1] = splat4(0.0f);
  }
  #pragma unroll
  for (int kcn = 0; kcn < 4; kcn++){
    frag_u ah0, ah1;
    const int f0 = ((kcn*8 + 2*wv + 0)*64 + l)*8;
    const int f1 = ((kcn*8 + 2*wv + 1)*64 + l)*8;
    ah0.q = *(const uint32x4*)(w2tfh + f0);
    ah1.q = *(const uint32x4*)(w2tfh + f1);
    const int nn = 32*kcn + 8*lg;
    #pragma unroll
    for (int pt = 0; pt < 4; pt++){
      frag_u bh;
      bh.q = *(const uint32x4*)&sHi[SW(16*pt + lr, nn)];
      acc2[pt][0] = __builtin_amdgcn_mfma_f32_16x16x32_bf16(ah0.v, bh.v, acc2[pt][0], 0,0,0);
      acc2[pt][1] = __builtin_amdgcn_mfma_f32_16x16x32_bf16(ah1.v, bh.v, acc2[pt][1], 0,0,0);
    }
  }

  // ---- bwd epilogue: dp1 = dh1*sg(pre1); grad = W1 @ dp1, reduce over lg
  {
    float w1a[2][4], w1b[2][4], w1c[2][4], b1v[2][4];
    #pragma unroll
    for (int t = 0; t < 2; t++)
      #pragma unroll
      for (int r = 0; r < 4; r++){
        int k = kb + 16*t + 4*lg + r;
        w1a[t][r] = W1[k]; w1b[t][r] = W1[HID+k]; w1c[t][r] = W1[2*HID+k];
        b1v[t][r] = b1[k];
      }
    #pragma unroll
    for (int pt = 0; pt < 4; pt++){
      const int p = 16*pt + lr;
      const float xx = sPts[p][0], xy = sPts[p][1], xz = sPts[p][2];
      float gx = 0.f, gy = 0.f, gz = 0.f;
      #pragma unroll
      for (int t = 0; t < 2; t++){
        #pragma unroll
        for (int r = 0; r < 4; r++){
          float pre1 = fmaf(xx, w1a[t][r], fmaf(xy, w1b[t][r], fmaf(xz, w1c[t][r], b1v[t][r])));
          float dp = acc2[pt][t][r] * sg_fast(pre1);
          gx = fmaf(w1a[t][r], dp, gx);
          gy = fmaf(w1b[t][r], dp, gy);
          gz = fmaf(w1c[t][r], dp, gz);
        }
      }
      gx += __shfl_xor(gx, 16); gx += __shfl_xor(gx, 32);
      gy += __shfl_xor(gy, 16); gy += __shfl_xor(gy, 32);
      gz += __shfl_xor(gz, 16); gz += __shfl_xor(gz, 32);
      if (lg == 0){
        sGrad[wv][p][0] = gx; sGrad[wv][p][1] = gy; sGrad[wv][p][2] = gz;
      }
    }
  }
  __syncthreads();
  if (tid < 64){
    #pragma unroll
    for (int c = 0; c < 3; c++)
      grad_out[(q0+tid)*3+c] =
        sGrad[0][tid][c] + sGrad[1][tid][c] + sGrad[2][tid][c] + sGrad[3][tid][c];
  }
}

// ---------------------------------------------------------------- upsample (one wave per ray)
__global__ __launch_bounds__(64) void k_upsample(
      const float* __restrict__ rays_o, const float* __restrict__ rays_d,
      float* __restrict__ z_buf, float* __restrict__ sdf_buf,
      float* __restrict__ pts_new, int* __restrict__ slots,
      int S, float inv_s, int last){
  __shared__ float z[128], sd[128], rad[128], cosv[128], alf[128], wv[128], cdf[129], nz[16];
  __shared__ int slt[16];
  const int ray = blockIdx.x;
  const int l   = threadIdx.x;
  const float ox = rays_o[ray*3], oy = rays_o[ray*3+1], oz = rays_o[ray*3+2];
  const float dx = rays_d[ray*3], dy = rays_d[ray*3+1], dz = rays_d[ray*3+2];
  for (int j = l; j < S; j += 64){
    float zz = z_buf[ray*128+j];
    z[j]  = zz;
    sd[j] = sdf_buf[ray*128+j];
    float px = ox+dx*zz, py = oy+dy*zz, pz = oz+dz*zz;
    rad[j] = sqrtf(px*px + py*py + pz*pz);
  }
  __syncthreads();
  for (int j = l; j < S-1; j += 64)
    cosv[j] = (sd[j+1]-sd[j]) / (z[j+1]-z[j] + 1e-5f);
  __syncthreads();
  for (int j = l; j < S-1; j += 64){
    float cv = fminf((j > 0) ? cosv[j-1] : 0.0f, cosv[j]);
    cv = fminf(fmaxf(cv, -1000.0f), 0.0f);
    float inside = (rad[j] < 1.0f || rad[j+1] < 1.0f) ? 1.0f : 0.0f;
    cv *= inside;
    float mid  = 0.5f*(sd[j]+sd[j+1]);
    float dist = z[j+1]-z[j];
    float e = sg_f((mid - cv*dist*0.5f)*inv_s);
    float f = sg_f((mid + cv*dist*0.5f)*inv_s);
    alf[j] = (e - f + 1e-5f) / (e + 1e-5f);
  }
  __syncthreads();
  if (l == 0){
    float T = 1.0f, wsum = 0.0f;
    for (int j = 0; j < S-1; j++){
      float w = alf[j]*T + 1e-5f;   // weights = alpha*trans + 1e-5
      wv[j] = w; wsum += w;
      T *= (1.0f - alf[j] + 1e-7f);
    }
    cdf[0] = 0.0f;
    float c = 0.0f;
    for (int j = 0; j < S-1; j++){ c += wv[j]/wsum; cdf[j+1] = c; }
  }
  __syncthreads();
  if (l < 16){
    float u = 0.03125f + 0.0625f*(float)l;   // linspace(1/32, 31/32, 16)
    int idx = 0;
    while (idx < S && cdf[idx] <= u) idx++;  // searchsorted side='right'
    int below = idx - 1; if (below < 0) below = 0;
    int above = (idx < S-1) ? idx : (S-1);
    float cb = cdf[below], ca = cdf[above];
    float den = ca - cb; if (den < 1e-5f) den = 1.0f;
    float t = (u - cb) / den;
    nz[l] = z[below] + t*(z[above] - z[below]);
  }
  __syncthreads();
  if (l == 0){
    // stable in-place merge from the back (old-before-new on ties)
    int i = S-1, j = 15;
    for (int dst = S+15; dst >= 0; --dst){
      bool takeOld = (j < 0) || (i >= 0 && z[i] > nz[j]);
      if (takeOld){ z[dst] = z[i]; sd[dst] = sd[i]; i--; }
      else        { z[dst] = nz[j]; slt[j] = dst; j--; }
    }
  }
  __syncthreads();
  for (int j = l; j < S+16; j += 64){
    z_buf[ray*128+j]  = z[j];
    sdf_buf[ray*128+j] = sd[j];
  }
  if (!last && l < 16){
    slots[ray*16+l] = slt[l];
    float zz = nz[l];
    pts_new[(ray*16+l)*3+0] = ox + dx*zz;
    pts_new[(ray*16+l)*3+1] = oy + dy*zz;
    pts_new[(ray*16+l)*3+2] = oz + dz*zz;
  }
}

// ---------------------------------------------------------------- render (one WAVE per ray)
// PASS-VALIDATED in rounds 8-10.
__global__ __launch_bounds__(64) void k_render(
    const float* __restrict__ z_buf, const float* __restrict__ sdf_mid,
    const float* __restrict__ rays_d, const float* __restrict__ grad,
    const float* __restrict__ variance, float* __restrict__ depth_out){
  const int ray = blockIdx.x;
  const int l   = threadIdx.x;
  float inv_s = expf(10.0f * variance[0]);
  inv_s = fminf(fmaxf(inv_s, 1e-6f), 1e6f);
  const float dx = rays_d[ray*3], dy = rays_d[ray*3+1], dz = rays_d[ray*3+2];
  const int i0 = ray*128 + 2*l, i1 = i0 + 1;
  const float z0 = z_buf[i0], z1 = z_buf[i1];
  const float zn1 = __shfl_down(z0, 1);              // z[2l+2] from lane l+1
  const float d0 = z1 - z0;
  const float d1 = (l < 63) ? (zn1 - z1) : 0.03125f;
  float a0, a1;
  {
    float sdf = sdf_mid[i0];
    float gx = grad[i0*3], gy = grad[i0*3+1], gz = grad[i0*3+2];
    float tc = dx*gx + dy*gy + dz*gz;
    float ic = -fmaxf(0.5f - 0.5f*tc, 0.0f);
    float e = sg_fast((sdf - ic*d0*0.5f)*inv_s);
    float f = sg_fast((sdf + ic*d0*0.5f)*inv_s);
    a0 = fminf(fmaxf((e - f + 1e-5f) / (e + 1e-5f), 0.0f), 1.0f);
  }
  {
    float sdf = sdf_mid[i1];
    float gx = grad[i1*3], gy = grad[i1*3+1], gz = grad[i1*3+2];
    float tc = dx*gx + dy*gy + dz*gz;
    float ic = -fmaxf(0.5f - 0.5f*tc, 0.0f);
    float e = sg_fast((sdf - ic*d1*0.5f)*inv_s);
    float f = sg_fast((sdf + ic*d1*0.5f)*inv_s);
    a1 = fminf(fmaxf((e - f + 1e-5f) / (e + 1e-5f), 0.0f), 1.0f);
  }
  const float f0 = 1.0f - a0 + 1e-7f;
  const float f1 = 1.0f - a1 + 1e-7f;
  float incl = f0 * f1;
  #pragma unroll
  for (int off = 1; off < 64; off <<= 1){
    float t = __shfl_up(incl, off);
    if (l >= off) incl *= t;
  }
  float P = __shfl_up(incl, 1);        // T at sample 2l
  if (l == 0) P = 1.0f;
  float part = P * (a0*z0 + f0*a1*z1); // a0*T(2l)*z0 + a1*T(2l+1)*z1
  #pragma unroll
  for (int m = 1; m < 64; m <<= 1) part += __shfl_xor(part, m);
  if (l == 0) depth_out[ray] = part;
}

// ---------------------------------------------------------------- launcher
extern "C" void kernel_launch(void* const* d_in, const int* in_sizes, int n_in,
                              void* d_out, int out_size, void* d_ws, size_t ws_size,
                              hipStream_t stream){
  (void)in_sizes; (void)n_in; (void)out_size; (void)ws_size;
  const float* rays_o = (const float*)d_in[0];
  const float* rays_d = (const float*)d_in[1];
  const float* nearv  = (const float*)d_in[2];
  const float* farv   = (const float*)d_in[3];
  const float* W1 = (const float*)d_in[4];
  const float* b1 = (const float*)d_in[5];
  const float* W2 = (const float*)d_in[6];
  const float* b2 = (const float*)d_in[7];
  const float* W3 = (const float*)d_in[8];
  const float* b3 = (const float*)d_in[9];
  const float* variance = (const float*)d_in[10];

  // Workspace layout: within round-0's proven footprint (6,619,136 B).
  float* ws      = (float*)d_ws;
  float* z_buf   = ws;                    // [0,       524288)
  float* sdf_buf = ws + 524288;           // [524288,  1048576)
  float* sdf_tmp = ws + 1048576;          // [1048576, 1572864)
  int*   slots   = (int*)(ws + 1589248);  // [1589248, 1654784) as ints
  // 2-way fwd + bwd(A-side) fragment tables alias sdf_buf — created AFTER the
  // upsample loop, when sdf_buf is dead (rounds 4-10 validated placement).
  unsigned short* w2fh  = (unsigned short*)(ws + 524288);  // [524288, 532480)
  unsigned short* w2fl  = w2fh + 16384;                    // [532480, 540672)
  unsigned short* w2tfh = w2fh + 32768;                    // [540672, 548864)
  unsigned short* w2tfl = w2fh + 49152;                    // [548864, 557056)
  // 3-way fwd fragments live in the upper (unused) half of sdf_tmp.
  unsigned short* w2h3 = (unsigned short*)(ws + 1310720); // [1310720, 1318912)
  unsigned short* w2m3 = w2h3 + 16384;                    // [1318912, 1327104)
  unsigned short* w2l3 = w2h3 + 32768;                    // [1327104, 1335296)

  float* out       = (float*)d_out;
  float* depth_out = out;
  float* grad_out  = out + NRAYS;         // 524288*3 floats
  float* pts       = grad_out;            // pts staging aliases grad region

  k_make_frags3<<<dim3(8), dim3(256), 0, stream>>>(W2, w2h3, w2m3, w2l3);
  // mode 1: fused k_init (z inline, z_buf written) + sdf ray-major into sdf_buf
  k_mlp_fwd_t<<<dim3(4096), dim3(256), 0, stream>>>(pts, rays_o, rays_d, nearv, farv,
                                                    z_buf, W1,b1,b2,W3,b3,
                                                    w2h3,w2m3,w2l3, sdf_buf, nullptr, 1);

  for (int i = 0; i < 4; i++){
    int S = 64 + 16*i;
    float inv_s = (float)(64 << i);
    int last = (i == 3) ? 1 : 0;
    k_upsample<<<dim3(4096), dim3(64), 0, stream>>>(rays_o, rays_d, z_buf, sdf_buf,
                                                    pts, slots, S, inv_s, last);
    if (!last){
      // mode 2: slot-scatter into sdf_buf (fused k_scatter_new)
      k_mlp_fwd_t<<<dim3(1024), dim3(256), 0, stream>>>(pts, rays_o, rays_d, nearv, farv,
                                                        z_buf, W1,b1,b2,W3,b3,
                                                        w2h3,w2m3,w2l3, sdf_buf, slots, 2);
    }
  }

  // sdf_buf is dead from here on — safe to overwrite with fragments.
  k_make_frags<<<dim3(16), dim3(256), 0, stream>>>(W2, w2fh, w2fl, w2tfh, w2tfl);
  k_mlp_bwd<<<dim3(8192), dim3(256), 0, stream>>>(z_buf, rays_o, rays_d,
                                                  W1,b1,b2,W3,b3,
                                                  w2fh,w2fl,w2tfh, sdf_tmp, grad_out);
  k_render<<<dim3(4096), dim3(64), 0, stream>>>(z_buf, sdf_tmp, rays_d, grad_out,
                                                variance, depth_out);
}